// Round 7
// baseline (246.290 us; speedup 1.0000x reference)
//
#include <hip/hip_runtime.h>
#include <cstdint>
#include <cmath>

#define EMBED 768
#define HID 384
#define NHEAD 12
#define HDIM 64
#define BATCH 8
#define NTOK 1024
#define MINKEEP 102

using f32x4  = __attribute__((ext_vector_type(4))) float;
using short8 = __attribute__((ext_vector_type(8))) short;
using short4v = __attribute__((ext_vector_type(4))) short;

__device__ inline short f2bf(float f) {
  unsigned u = __float_as_uint(f);
  u += 0x7fffu + ((u >> 16) & 1u);
  return (short)(u >> 16);
}
__device__ inline float bf2f(short s) {
  return __uint_as_float(((unsigned)(unsigned short)s) << 16);
}
__device__ inline unsigned pack_bf2(float lo, float hi) {
  unsigned ul = __float_as_uint(lo);
  ul += 0x7fffu + ((ul >> 16) & 1u);
  unsigned uh = __float_as_uint(hi);
  uh += 0x7fffu + ((uh >> 16) & 1u);
  return (ul >> 16) | (uh & 0xffff0000u);
}
// exact 3-way split: v = h + m + l + O(2^-27 v).
__device__ inline void split3(float v, short& h, short& m, short& l) {
  h = f2bf(v);
  float r1 = v - bf2f(h);
  m = f2bf(r1);
  float r2 = r1 - bf2f(m);
  l = f2bf(r2);
}

// ---------------------------------------------------------------------------
// K1a: addvec[b][c] = 2*emb[idx][c]   (init for atomic accumulation)
// ---------------------------------------------------------------------------
__global__ __launch_bounds__(768) void addvec_init_kernel(
    const float* __restrict__ layer_emb, const int* __restrict__ lidx,
    float* __restrict__ addvec) {
  int b = blockIdx.x, c = threadIdx.x;
  addvec[b * EMBED + c] = 2.0f * layer_emb[lidx[0] * EMBED + c];
}

// ---------------------------------------------------------------------------
// K1b: addvec[b][c] += (1/NTOK) * sum_{n in chunk} tokens[b,n,c]
// ---------------------------------------------------------------------------
__global__ __launch_bounds__(768) void colmean_kernel(
    const float* __restrict__ tokens, float* __restrict__ addvec) {
  int b = blockIdx.x, chunk = blockIdx.y, c = threadIdx.x;
  const float* tb = tokens + ((size_t)b * NTOK + chunk * 64) * EMBED + c;
  float s = 0.f;
#pragma unroll 8
  for (int n = 0; n < 64; ++n) s += tb[(size_t)n * EMBED];
  atomicAdd(&addvec[b * EMBED + c], s * (1.0f / NTOK));
}

// ---------------------------------------------------------------------------
// K2: layernorm per row (768) -> 3 bf16 planes (xh, xm, xl)
// ---------------------------------------------------------------------------
__global__ __launch_bounds__(256) void ln_split_kernel(
    const float* __restrict__ tokens, const float* __restrict__ addvec,
    const float* __restrict__ gamma, const float* __restrict__ beta,
    short* __restrict__ xh, short* __restrict__ xm, short* __restrict__ xl) {
  int row = blockIdx.x;
  int b = row >> 10;
  __shared__ float s_row[EMBED];
  __shared__ float s_red[4];
  const float* tr = tokens + (size_t)row * EMBED;
  const float* av = addvec + b * EMBED;
  float lsum = 0.f;
  for (int c = threadIdx.x; c < EMBED; c += 256) {
    float v = tr[c] + av[c];
    s_row[c] = v;
    lsum += v;
  }
  for (int o = 32; o; o >>= 1) lsum += __shfl_down(lsum, o, 64);
  int wid = threadIdx.x >> 6;
  if ((threadIdx.x & 63) == 0) s_red[wid] = lsum;
  __syncthreads();
  float mu = (s_red[0] + s_red[1] + s_red[2] + s_red[3]) * (1.f / EMBED);
  float lss = 0.f;
  for (int c = threadIdx.x; c < EMBED; c += 256) {
    float d = s_row[c] - mu;
    lss += d * d;
  }
  for (int o = 32; o; o >>= 1) lss += __shfl_down(lss, o, 64);
  __syncthreads();
  if ((threadIdx.x & 63) == 0) s_red[wid] = lss;
  __syncthreads();
  float var = (s_red[0] + s_red[1] + s_red[2] + s_red[3]) * (1.f / EMBED);
  float rinv = 1.0f / sqrtf(var + 1e-5f);
  for (int c = threadIdx.x; c < EMBED; c += 256) {
    float v = (s_row[c] - mu) * rinv * gamma[c] + beta[c];
    short h, m, l;
    split3(v, h, m, l);
    size_t idx = (size_t)row * EMBED + c;
    xh[idx] = h; xm[idx] = m; xl[idx] = l;
  }
}

// ---------------------------------------------------------------------------
// f32 -> 3 bf16 planes bulk convert (4 elems/thread)
// ---------------------------------------------------------------------------
__global__ __launch_bounds__(256) void cvt_split3_kernel(
    const float* __restrict__ in, short* __restrict__ oh,
    short* __restrict__ om, short* __restrict__ ol, int n4) {
  int i = blockIdx.x * 256 + threadIdx.x;
  if (i >= n4) return;
  float4 f = ((const float4*)in)[i];
  short4v h, m, l;
  short th, tm, tl;
  split3(f.x, th, tm, tl); h[0] = th; m[0] = tm; l[0] = tl;
  split3(f.y, th, tm, tl); h[1] = th; m[1] = tm; l[1] = tl;
  split3(f.z, th, tm, tl); h[2] = th; m[2] = tm; l[2] = tl;
  split3(f.w, th, tm, tl); h[3] = th; m[3] = tm; l[3] = tl;
  ((short4v*)oh)[i] = h;
  ((short4v*)om)[i] = m;
  ((short4v*)ol)[i] = l;
}

// ---------------------------------------------------------------------------
// Split-bf16 MFMA GEMM (fp32-exact to ~2^-27): C = A@W^T + bias, gelu.
// v7 = R1/R4 proven structure (64x64 tile, BK=32, quad-per-row A staging,
// [64][40] LDS) with W NOT staged through LDS: B-fragments are read
// directly from global. W is <=1.7MB (all planes) -> L2/L3-resident; the
// direct fragment load (16 rows x 64B segments per instruction) has the
// same segment structure as the staging reads. Effects: LDS traffic/K-step
// halves (A only), LDS 30KB->15KB (more resident blocks -> barrier hiding,
// the decisive factor per R6), W-side conflicts gone. Numerics identical
// to R4 (same chain, same order).
// ---------------------------------------------------------------------------
__device__ inline float gelu_exact(float x) {
  return 0.5f * x * (1.0f + erff(x * 0.70710678118654752f));
}

template <int OUT>
__global__ __launch_bounds__(256) void gemm_split_kernel(
    const short* __restrict__ Ah, const short* __restrict__ Am,
    const short* __restrict__ Al, const short* __restrict__ Wh,
    const short* __restrict__ Wm, const short* __restrict__ Wl,
    const float* __restrict__ bias, short* __restrict__ Ch,
    short* __restrict__ Cm, short* __restrict__ Cl, float* __restrict__ Cf,
    int M, int N, int K) {
  __shared__ short sA[3][64][40];
  int tid = threadIdx.x;
  int w = tid >> 6, l = tid & 63, lg = l >> 4, lb = l & 15;
  int wr = (w >> 1) * 32, wc = (w & 1) * 32;
  int row0 = blockIdx.x * 64, col0 = blockIdx.y * 64;
  int srow = tid >> 2;
  int skk = (tid & 3) * 8;
  f32x4 acc0[2][2] = {}, acc1[2][2] = {};
  short8 ra0, ra1, ra2;
  // W fragment row bases (per-lane): rows col0+wc+j*16+lb, j=0,1
  size_t wb0 = (size_t)(col0 + wc + lb) * K + lg * 8;
  size_t wb1 = (size_t)(col0 + wc + 16 + lb) * K + lg * 8;
  {
    size_t aoff = (size_t)(row0 + srow) * K + skk;
    ra0 = *(const short8*)(Ah + aoff);
    ra1 = *(const short8*)(Am + aoff);
    ra2 = *(const short8*)(Al + aoff);
  }
  for (int k0 = 0; k0 < K; k0 += 32) {
    __syncthreads();
    *(short8*)&sA[0][srow][skk] = ra0;
    *(short8*)&sA[1][srow][skk] = ra1;
    *(short8*)&sA[2][srow][skk] = ra2;
    __syncthreads();
    // W fragments straight from global (L2-resident)
    short8 bh[2], bm[2], bl[2];
    bh[0] = *(const short8*)(Wh + wb0 + k0);
    bh[1] = *(const short8*)(Wh + wb1 + k0);
    bm[0] = *(const short8*)(Wm + wb0 + k0);
    bm[1] = *(const short8*)(Wm + wb1 + k0);
    bl[0] = *(const short8*)(Wl + wb0 + k0);
    bl[1] = *(const short8*)(Wl + wb1 + k0);
    if (k0 + 32 < K) {
      size_t aoff = (size_t)(row0 + srow) * K + k0 + 32 + skk;
      ra0 = *(const short8*)(Ah + aoff);
      ra1 = *(const short8*)(Am + aoff);
      ra2 = *(const short8*)(Al + aoff);
    }
    short8 ah[2], am[2], al[2];
#pragma unroll
    for (int i = 0; i < 2; ++i) {
      ah[i] = *(short8*)&sA[0][wr + i * 16 + lb][lg * 8];
      am[i] = *(short8*)&sA[1][wr + i * 16 + lb][lg * 8];
      al[i] = *(short8*)&sA[2][wr + i * 16 + lb][lg * 8];
    }
#pragma unroll
    for (int i = 0; i < 2; ++i)
#pragma unroll
      for (int j = 0; j < 2; ++j) {
        f32x4 c0 = acc0[i][j];
        f32x4 c1 = acc1[i][j];
        c0 = __builtin_amdgcn_mfma_f32_16x16x32_bf16(ah[i], bh[j], c0, 0, 0, 0);
        c1 = __builtin_amdgcn_mfma_f32_16x16x32_bf16(ah[i], bm[j], c1, 0, 0, 0);
        c0 = __builtin_amdgcn_mfma_f32_16x16x32_bf16(am[i], bh[j], c0, 0, 0, 0);
        c1 = __builtin_amdgcn_mfma_f32_16x16x32_bf16(ah[i], bl[j], c1, 0, 0, 0);
        c0 = __builtin_amdgcn_mfma_f32_16x16x32_bf16(al[i], bh[j], c0, 0, 0, 0);
        c1 = __builtin_amdgcn_mfma_f32_16x16x32_bf16(am[i], bm[j], c1, 0, 0, 0);
        acc0[i][j] = c0;
        acc1[i][j] = c1;
      }
  }
#pragma unroll
  for (int i = 0; i < 2; ++i) {
#pragma unroll
    for (int j = 0; j < 2; ++j) {
#pragma unroll
      for (int r = 0; r < 4; ++r) {
        int grow = row0 + wr + i * 16 + lg * 4 + r;
        int gcol = col0 + wc + j * 16 + lb;
        float g = gelu_exact(acc0[i][j][r] + acc1[i][j][r] + bias[gcol]);
        size_t idx = (size_t)grow * N + gcol;
        if (OUT == 0) {
          short h, m, lo;
          split3(g, h, m, lo);
          Ch[idx] = h; Cm[idx] = m; Cl[idx] = lo;
        } else {
          Cf[idx] = g;
        }
      }
    }
  }
}

// ---------------------------------------------------------------------------
// logits + sigmoid -> probs
// ---------------------------------------------------------------------------
__global__ __launch_bounds__(256) void logits_kernel(
    const float* __restrict__ h2, const float* __restrict__ w3,
    const float* __restrict__ b3, float* __restrict__ probs) {
  int row = blockIdx.x * 4 + (threadIdx.x >> 6);
  int lane = threadIdx.x & 63;
  const float* hr = h2 + (size_t)row * HID;
  float s = 0.f;
  for (int c = lane; c < HID; c += 64) s += hr[c] * w3[c];
  for (int o = 32; o; o >>= 1) s += __shfl_down(s, o, 64);
  if (lane == 0) probs[row] = 1.0f / (1.0f + expf(-(s + b3[0])));
}

// ---------------------------------------------------------------------------
// mask v3: threshold (+ gated bitonic top-102 correction), then per-batch
// COMPACTION: kidx[b][j] = ascending kept-token indices, kc[b] = count,
// biasc[b][j] = 0 for j<kc else -3e38 (softmax bias in compacted space).
// ---------------------------------------------------------------------------
__global__ __launch_bounds__(1024) void mask_kernel(
    const float* __restrict__ probs, int* __restrict__ kidx,
    int* __restrict__ kc, float* __restrict__ biasc) {
  int b = blockIdx.x, tid = threadIdx.x;
  __shared__ unsigned long long keys[1024];
  __shared__ int flag[1024];
  __shared__ int wsum[16];
  float p = probs[b * NTOK + tid];
  bool bin = (p >= 0.5f);
  int wid = tid >> 6, lane = tid & 63;
  unsigned long long bal = __ballot(bin);
  if (lane == 0) wsum[wid] = __popcll(bal);
  __syncthreads();
  int total = 0;
  for (int q = 0; q < 16; ++q) total += wsum[q];
  int mv;
  if (total >= MINKEEP) {
    mv = bin ? 1 : 0;
  } else {
    flag[tid] = 0;
    unsigned u = __float_as_uint(p);
    keys[tid] = ((unsigned long long)u << 32) | (unsigned)(1023 - tid);
    __syncthreads();
    for (int k2 = 2; k2 <= 1024; k2 <<= 1) {
      for (int j = k2 >> 1; j > 0; j >>= 1) {
        int ixj = tid ^ j;
        if (ixj > tid) {
          unsigned long long a = keys[tid], c = keys[ixj];
          bool desc = ((tid & k2) == 0);
          if (desc ? (a < c) : (a > c)) {
            keys[tid] = c;
            keys[ixj] = a;
          }
        }
        __syncthreads();
      }
    }
    if (tid < MINKEEP) {
      int idx = 1023 - (int)(keys[tid] & 0xFFFFFFFFu);
      flag[idx] = 1;
    }
    __syncthreads();
    mv = flag[tid];
  }
  if (tid == 0) mv = 1;
  __syncthreads();  // wsum reuse
  unsigned long long fb = __ballot(mv != 0);
  if (lane == 0) wsum[wid] = __popcll(fb);
  __syncthreads();
  int base = 0, tot = 0;
  for (int q = 0; q < 16; ++q) {
    int v = wsum[q];
    if (q < wid) base += v;
    tot += v;
  }
  int pre = base + __popcll(fb & ((1ull << lane) - 1ull));
  if (mv) {
    kidx[b * NTOK + pre] = tid;
    biasc[b * NTOK + pre] = 0.f;
  }
  if (tid >= tot) {
    kidx[b * NTOK + tid] = 0;
    biasc[b * NTOK + tid] = -3.0e38f;
  }
  if (tid == 0) kc[b] = tot;
}

// ---------------------------------------------------------------------------
// f32 -> bf16 bulk convert (4 elems/thread)
// ---------------------------------------------------------------------------
__global__ __launch_bounds__(256) void cvt_bf16_kernel(
    const float* __restrict__ in, short* __restrict__ out, int n4) {
  int i = blockIdx.x * 256 + threadIdx.x;
  if (i >= n4) return;
  float4 f = ((const float4*)in)[i];
  short4v s;
  s[0] = f2bf(f.x); s[1] = f2bf(f.y); s[2] = f2bf(f.z); s[3] = f2bf(f.w);
  ((short4v*)out)[i] = s;
}

// ---------------------------------------------------------------------------
// QKV gather-GEMM (compacted rows). 128x128 tile, BK=64, reg prefetch.
// b = bx&7 so wgid%8 == batch -> all 8 XCDs active.
// ---------------------------------------------------------------------------
__global__ __launch_bounds__(256) void qkv_gather_kernel(
    const short* __restrict__ tok_bf, const short* __restrict__ W,
    const float* __restrict__ bias, const int* __restrict__ kidx,
    const int* __restrict__ kc, short* __restrict__ qq,
    short* __restrict__ kk_, short* __restrict__ vv) {
  __shared__ short sA[128][72];
  __shared__ short sW[128][72];
  __shared__ int s_idx[128];
  int bx = blockIdx.x;
  int b = bx & 7, bt = bx >> 3;
  int kcb = kc[b];
  if (bt * 128 >= kcb) return;
  int tid = threadIdx.x;
  if (tid < 128) s_idx[tid] = kidx[b * NTOK + bt * 128 + tid];
  int w = tid >> 6, l = tid & 63, lg = l >> 4, lb = l & 15;
  int wr = (w >> 1) * 64, wc = (w & 1) * 64;
  int col0 = blockIdx.y * 128;
  int r_ = tid >> 3, kq = (tid & 7) * 8;
  __syncthreads();  // s_idx ready
  const short* Ab = tok_bf + (size_t)b * NTOK * EMBED;
  f32x4 acc[4][4] = {};
  short8 pa[4], pw[4];
#pragma unroll
  for (int t = 0; t < 4; ++t) {
    pa[t] = *(const short8*)(Ab + (size_t)s_idx[t * 32 + r_] * EMBED + kq);
    pw[t] = *(const short8*)(W + (size_t)(col0 + t * 32 + r_) * EMBED + kq);
  }
  for (int k0 = 0; k0 < EMBED; k0 += 64) {
    __syncthreads();
#pragma unroll
    for (int t = 0; t < 4; ++t) {
      *(short8*)&sA[t * 32 + r_][kq] = pa[t];
      *(short8*)&sW[t * 32 + r_][kq] = pw[t];
    }
    __syncthreads();
    if (k0 + 64 < EMBED) {
#pragma unroll
      for (int t = 0; t < 4; ++t) {
        pa[t] = *(const short8*)(Ab + (size_t)s_idx[t * 32 + r_] * EMBED +
                                 k0 + 64 + kq);
        pw[t] = *(const short8*)(W + (size_t)(col0 + t * 32 + r_) * EMBED +
                                 k0 + 64 + kq);
      }
    }
#pragma unroll
    for (int half = 0; half < 2; ++half) {
      short8 af[4], bfr[4];
#pragma unroll
      for (int i = 0; i < 4; ++i)
        af[i] = *(short8*)&sA[wr + i * 16 + lb][half * 32 + lg * 8];
#pragma unroll
      for (int j = 0; j < 4; ++j)
        bfr[j] = *(short8*)&sW[wc + j * 16 + lb][half * 32 + lg * 8];
#pragma unroll
      for (int i = 0; i < 4; ++i)
#pragma unroll
        for (int j = 0; j < 4; ++j)
          acc[i][j] = __builtin_amdgcn_mfma_f32_16x16x32_bf16(af[i], bfr[j],
                                                              acc[i][j], 0, 0, 0);
    }
  }
#pragma unroll
  for (int i = 0; i < 4; ++i) {
#pragma unroll
    for (int j = 0; j < 4; ++j) {
#pragma unroll
      for (int r = 0; r < 4; ++r) {
        int jrow = bt * 128 + wr + i * 16 + lg * 4 + r;  // compacted position
        int gcol = col0 + wc + j * 16 + lb;
        float val = acc[i][j][r] + bias[gcol];
        int which = gcol / EMBED;
        int rem = gcol - which * EMBED;
        int h = rem >> 6, d = rem & 63;
        size_t dst = ((size_t)(b * NHEAD + h) * NTOK + jrow) * HDIM + d;
        if (which == 0)
          qq[dst] = f2bf(val * 0.125f);
        else if (which == 1)
          kk_[dst] = f2bf(val);
        else
          vv[dst] = f2bf(val);
      }
    }
  }
}

// ---------------------------------------------------------------------------
// V transpose: Vc[bh][j][d] -> VTc[bh][d][j]
// ---------------------------------------------------------------------------
__global__ __launch_bounds__(256) void vtrans_kernel(
    const short* __restrict__ Vb, short* __restrict__ VT) {
  int bh = blockIdx.y;
  int n0 = blockIdx.x * 64;
  __shared__ short st[64][72];
  int tid = threadIdx.x;
#pragma unroll
  for (int t = 0; t < 2; ++t) {
    int c = tid + t * 256;
    int n = c >> 3, ds = c & 7;
    *(short8*)&st[n][ds * 8] =
        *(const short8*)(Vb + ((size_t)bh * NTOK + n0 + n) * HDIM + ds * 8);
  }
  __syncthreads();
#pragma unroll
  for (int t = 0; t < 2; ++t) {
    int c = tid + t * 256;
    int d = c >> 3, ns = c & 7;
    short8 tmp;
#pragma unroll
    for (int jj = 0; jj < 8; ++jj) tmp[jj] = st[ns * 8 + jj][d];
    *(short8*)(VT + ((size_t)bh * HDIM + d) * NTOK + n0 + ns * 8) = tmp;
  }
}

// ---------------------------------------------------------------------------
// MFMA flash attention v3 — compacted token space. Loop count nt =
// ceil(kc[b]/64) read from device. Pad slots carry bias -3e38 -> P = 0.
// ---------------------------------------------------------------------------
#define ATTN_SWZ(row, colbyte) (((row)*128) + ((colbyte) ^ (((row)&7) << 4)))

__global__ __launch_bounds__(256) void attn_mfma3_kernel(
    const short* __restrict__ Qc, const short* __restrict__ Kc,
    const short* __restrict__ VTc, const float* __restrict__ biasc,
    const int* __restrict__ kc, short* __restrict__ ao) {
  __shared__ __align__(16) short sK[64 * 64];
  __shared__ __align__(16) short sVT[64 * 64];
  int bid = blockIdx.x;
  int xcd = bid & 7, slot = bid >> 3;
  int bh = xcd * 12 + (slot >> 3);
  int qt = slot & 7;
  int b = bh / NHEAD;
  int kcb = kc[b];
  if (qt * 128 >= kcb) return;
  int nt = (kcb + 63) >> 6;
  int tid = threadIdx.x;
  int w = tid >> 6, l = tid & 63, lg = l >> 4, lb = l & 15;
  int n0 = qt * 128 + w * 32;
  const short* Qp = Qc + ((size_t)bh * NTOK + n0) * HDIM;
  const short* Kp = Kc + (size_t)bh * NTOK * HDIM;
  const short* Vp = VTc + (size_t)bh * HDIM * NTOK;
  const float* bp = biasc + b * NTOK;

  short8 qf[2][2];
#pragma unroll
  for (int i = 0; i < 2; ++i)
#pragma unroll
    for (int hh = 0; hh < 2; ++hh)
      qf[i][hh] = *(const short8*)(Qp + (i * 16 + lb) * HDIM + hh * 32 + lg * 8);

  f32x4 acc[2][4] = {};
  float lr[2] = {0.f, 0.f};

  int srow = tid >> 3;
  int scol = (tid & 7) * 8;
  int scolb = scol * 2;
  short8 rk0, rk1, rv0, rv1;

#define ATTN_LOADT(m0_)                                                        \
  {                                                                            \
    rk0 = *(const short8*)(Kp + (size_t)((m0_) + srow) * HDIM + scol);         \
    rk1 = *(const short8*)(Kp + (size_t)((m0_) + srow + 32) * HDIM + scol);    \
    rv0 = *(const short8*)(Vp + (size_t)srow * NTOK + (m0_) + scol);           \
    rv1 = *(const short8*)(Vp + (size_t)(srow + 32) * NTOK + (m0_) + scol);    \
  }

  ATTN_LOADT(0);
  for (int t = 0; t < nt; ++t) {
    int m0 = t * 64;
    *(short8*)((char*)sK + ATTN_SWZ(srow, scolb)) = rk0;
    *(short8*)((char*)sK + ATTN_SWZ(srow + 32, scolb)) = rk1;
    *(short8*)((char*)sVT + ATTN_SWZ(srow, scolb)) = rv0;
    *(short8*)((char*)sVT + ATTN_SWZ(srow + 32, scolb)) = rv1;
    __syncthreads();
    if (t + 1 < nt) ATTN_LOADT(m0 + 64);

    f32x4 bias4[4];
#pragma unroll
    for (int s = 0; s < 4; ++s)
      bias4[s] = *(const f32x4*)(bp + m0 + s * 16 + lg * 4);

    f32x4 S[2][4];
#pragma unroll
    for (int s = 0; s < 4; ++s) {
      short8 kf0 = *(const short8*)((const char*)sK +
                                    ATTN_SWZ(s * 16 + lb, lg * 16));
      short8 kf1 = *(const short8*)((const char*)sK +
                                    ATTN_SWZ(s * 16 + lb, 64 + lg * 16));
#pragma unroll
      for (int i = 0; i < 2; ++i) {
        f32x4 c = bias4[s];
        c = __builtin_amdgcn_mfma_f32_16x16x32_bf16(kf0, qf[i][0], c, 0, 0, 0);
        c = __builtin_amdgcn_mfma_f32_16x16x32_bf16(kf1, qf[i][1], c, 0, 0, 0);
        S[i][s] = c;
      }
    }

    unsigned pk[2][4][2];
#pragma unroll
    for (int i = 0; i < 2; ++i) {
      float rs = 0.f;
#pragma unroll
      for (int s = 0; s < 4; ++s) {
        float p0 = __expf(S[i][s][0]);
        float p1 = __expf(S[i][s][1]);
        float p2 = __expf(S[i][s][2]);
        float p3 = __expf(S[i][s][3]);
        rs += (p0 + p1) + (p2 + p3);
        pk[i][s][0] = pack_bf2(p0, p1);
        pk[i][s][1] = pack_bf2(p2, p3);
      }
      rs += __shfl_xor(rs, 16);
      rs += __shfl_xor(rs, 32);
      lr[i] += rs;
    }

    bool hi = (lg & 2) != 0;
    int srcl = ((lg & 1) * 2) * 16 + lb;
#pragma unroll
    for (int t2 = 0; t2 < 2; ++t2) {
      short8 vf[4];
#pragma unroll
      for (int u = 0; u < 4; ++u)
        vf[u] = *(const short8*)((const char*)sVT +
                                 ATTN_SWZ(u * 16 + lb, t2 * 64 + lg * 16));
#pragma unroll
      for (int i = 0; i < 2; ++i) {
        int a0 = __shfl((int)pk[i][2 * t2][0], srcl);
        int b0 = __shfl((int)pk[i][2 * t2 + 1][0], srcl);
        int a1 = __shfl((int)pk[i][2 * t2][1], srcl);
        int b1 = __shfl((int)pk[i][2 * t2 + 1][1], srcl);
        int a2 = __shfl((int)pk[i][2 * t2][0], srcl + 16);
        int b2 = __shfl((int)pk[i][2 * t2 + 1][0], srcl + 16);
        int a3 = __shfl((int)pk[i][2 * t2][1], srcl + 16);
        int b3 = __shfl((int)pk[i][2 * t2 + 1][1], srcl + 16);
        union { short8 s8; int u[4]; } pa;
        pa.u[0] = hi ? b0 : a0;
        pa.u[1] = hi ? b1 : a1;
        pa.u[2] = hi ? b2 : a2;
        pa.u[3] = hi ? b3 : a3;
#pragma unroll
        for (int u = 0; u < 4; ++u)
          acc[i][u] = __builtin_amdgcn_mfma_f32_16x16x32_bf16(pa.s8, vf[u],
                                                              acc[i][u], 0, 0, 0);
      }
    }
    __syncthreads();
  }

  int h = bh - b * NHEAD;
#pragma unroll
  for (int i = 0; i < 2; ++i) {
#pragma unroll
    for (int r = 0; r < 4; ++r) {
      float inv = 1.0f / __shfl(lr[i], lg * 4 + r);
      int j = n0 + i * 16 + lg * 4 + r;  // compacted row
#pragma unroll
      for (int u = 0; u < 4; ++u) {
        ao[((size_t)b * NTOK + j) * EMBED + h * HDIM + u * 16 + lb] =
            f2bf(acc[i][u][r] * inv);
      }
    }
  }
}

// ---------------------------------------------------------------------------
// Proj gather-GEMM: A = aoc (compacted rows, dense), W = proj weights.
// ---------------------------------------------------------------------------
__global__ __launch_bounds__(256) void proj_gather_kernel(
    const short* __restrict__ A, const short* __restrict__ W,
    const float* __restrict__ bias, const int* __restrict__ kidx,
    const int* __restrict__ kc, float* __restrict__ out) {
  __shared__ short sA[128][72];
  __shared__ short sW[128][72];
  __shared__ int s_idx[128];
  int bx = blockIdx.x;
  int b = bx & 7, bt = bx >> 3;
  int kcb = kc[b];
  if (bt * 128 >= kcb) return;
  int tid = threadIdx.x;
  if (tid < 128) s_idx[tid] = kidx[b * NTOK + bt * 128 + tid];
  int w = tid >> 6, l = tid & 63, lg = l >> 4, lb = l & 15;
  int wr = (w >> 1) * 64, wc = (w & 1) * 64;
  int col0 = blockIdx.y * 128;
  int r_ = tid >> 3, kq = (tid & 7) * 8;
  const short* Ab = A + ((size_t)b * NTOK + bt * 128) * EMBED;
  f32x4 acc[4][4] = {};
  short8 pa[4], pw[4];
#pragma unroll
  for (int t = 0; t < 4; ++t) {
    pa[t] = *(const short8*)(Ab + (size_t)(t * 32 + r_) * EMBED + kq);
    pw[t] = *(const short8*)(W + (size_t)(col0 + t * 32 + r_) * EMBED + kq);
  }
  for (int k0 = 0; k0 < EMBED; k0 += 64) {
    __syncthreads();
#pragma unroll
    for (int t = 0; t < 4; ++t) {
      *(short8*)&sA[t * 32 + r_][kq] = pa[t];
      *(short8*)&sW[t * 32 + r_][kq] = pw[t];
    }
    __syncthreads();
    if (k0 + 64 < EMBED) {
#pragma unroll
      for (int t = 0; t < 4; ++t) {
        pa[t] = *(const short8*)(Ab + (size_t)(t * 32 + r_) * EMBED + k0 + 64 + kq);
        pw[t] = *(const short8*)(W + (size_t)(col0 + t * 32 + r_) * EMBED + k0 + 64 + kq);
      }
    }
#pragma unroll
    for (int half = 0; half < 2; ++half) {
      short8 af[4], bfr[4];
#pragma unroll
      for (int i = 0; i < 4; ++i)
        af[i] = *(short8*)&sA[wr + i * 16 + lb][half * 32 + lg * 8];
#pragma unroll
      for (int j = 0; j < 4; ++j)
        bfr[j] = *(short8*)&sW[wc + j * 16 + lb][half * 32 + lg * 8];
#pragma unroll
      for (int i = 0; i < 4; ++i)
#pragma unroll
        for (int j = 0; j < 4; ++j)
          acc[i][j] = __builtin_amdgcn_mfma_f32_16x16x32_bf16(af[i], bfr[j],
                                                              acc[i][j], 0, 0, 0);
    }
  }
#pragma unroll
  for (int i = 0; i < 4; ++i) {
#pragma unroll
    for (int j = 0; j < 4; ++j) {
#pragma unroll
      for (int r = 0; r < 4; ++r) {
        int jloc = wr + i * 16 + lg * 4 + r;
        int jrow = bt * 128 + jloc;
        int gcol = col0 + wc + j * 16 + lb;
        if (jrow < kcb) {
          int n = s_idx[jloc];
          out[((size_t)b * NTOK + n) * EMBED + gcol] = acc[i][j][r] + bias[gcol];
        }
      }
    }
  }
}

// ---------------------------------------------------------------------------
extern "C" void kernel_launch(void* const* d_in, const int* in_sizes, int n_in,
                              void* d_out, int out_size, void* d_ws, size_t ws_size,
                              hipStream_t stream) {
  const float* tokens   = (const float*)d_in[0];
  const int*   lidx     = (const int*)d_in[1];
  const float* layer_emb= (const float*)d_in[2];
  const float* ln_g     = (const float*)d_in[3];
  const float* ln_b     = (const float*)d_in[4];
  const float* w1       = (const float*)d_in[5];
  const float* b1       = (const float*)d_in[6];
  const float* w2       = (const float*)d_in[7];
  const float* b2       = (const float*)d_in[8];
  const float* w3       = (const float*)d_in[9];
  const float* b3       = (const float*)d_in[10];
  const float* qkv_w    = (const float*)d_in[11];
  const float* qkv_b    = (const float*)d_in[12];
  const float* proj_w   = (const float*)d_in[13];
  const float* proj_b   = (const float*)d_in[14];
  float* out = (float*)d_out;
  float* ws = (float*)d_ws;

  float* addvec = ws;
  float* probs  = ws + 6144;
  int*   kidx   = (int*)(ws + 14336);
  float* biasc  = ws + 22528;
  int*   kc     = (int*)(ws + 30720);
  short* tok_bf = (short*)(ws + 30736);
  short* wq_bf  = (short*)(ws + 3176464);
  short* wp_bf  = (short*)(ws + 4061200);
  short* w1h = (short*)(ws + 4356112);
  short* w1m = (short*)(ws + 4503568);
  short* w1l = (short*)(ws + 4651024);
  short* w2h = (short*)(ws + 4798480);
  short* w2m = (short*)(ws + 4872208);
  short* w2l = (short*)(ws + 4945936);
  const size_t X0 = 5019664;
  short* xh  = (short*)(ws + X0);
  short* xm  = (short*)(ws + X0 + 3145728);
  short* xl  = (short*)(ws + X0 + 6291456);
  short* h1h = (short*)(ws + X0 + 9437184);
  short* h1m = (short*)(ws + X0 + 11010048);
  short* h1l = (short*)(ws + X0 + 12582912);
  float* h2  = ws + X0 + 14155776;
  short* Qc   = (short*)(ws + X0);
  short* Kc   = (short*)(ws + X0 + 3145728);
  short* Vc   = (short*)(ws + X0 + 6291456);
  short* VTc  = (short*)(ws + X0 + 9437184);
  short* aoc  = (short*)(ws + X0 + 12582912);

  // masked output rows are exactly 0 in the reference -> pre-zero d_out
  hipMemsetAsync(d_out, 0, (size_t)out_size * sizeof(float), stream);

  // bf16 conversions
  cvt_bf16_kernel<<<dim3(6144), dim3(256), 0, stream>>>(tokens, tok_bf, 1572864);
  cvt_bf16_kernel<<<dim3(1728), dim3(256), 0, stream>>>(qkv_w, wq_bf, 442368);
  cvt_bf16_kernel<<<dim3(576),  dim3(256), 0, stream>>>(proj_w, wp_bf, 147456);
  cvt_split3_kernel<<<dim3(288), dim3(256), 0, stream>>>(w1, w1h, w1m, w1l, 73728);
  cvt_split3_kernel<<<dim3(144), dim3(256), 0, stream>>>(w2, w2h, w2m, w2l, 36864);

  // mask path (fp32-exact to ~2^-27 via 3-plane split MFMA)
  addvec_init_kernel<<<dim3(BATCH), dim3(768), 0, stream>>>(layer_emb, lidx, addvec);
  colmean_kernel<<<dim3(BATCH, 16), dim3(768), 0, stream>>>(tokens, addvec);
  ln_split_kernel<<<dim3(BATCH * NTOK), dim3(256), 0, stream>>>(
      tokens, addvec, ln_g, ln_b, xh, xm, xl);
  gemm_split_kernel<0><<<dim3(128, 6), dim3(256), 0, stream>>>(
      xh, xm, xl, w1h, w1m, w1l, b1, h1h, h1m, h1l, nullptr,
      BATCH * NTOK, HID, EMBED);
  gemm_split_kernel<1><<<dim3(128, 6), dim3(256), 0, stream>>>(
      h1h, h1m, h1l, w2h, w2m, w2l, b2, nullptr, nullptr, nullptr, h2,
      BATCH * NTOK, HID, HID);
  logits_kernel<<<dim3(2048), dim3(256), 0, stream>>>(h2, w3, b3, probs);
  mask_kernel<<<dim3(BATCH), dim3(1024), 0, stream>>>(probs, kidx, kc, biasc);

  // attention path, compacted token space (~kc of 1024 tokens per batch)
  qkv_gather_kernel<<<dim3(64, 18), dim3(256), 0, stream>>>(
      tok_bf, wq_bf, qkv_b, kidx, kc, Qc, Kc, Vc);
  vtrans_kernel<<<dim3(16, BATCH * NHEAD), dim3(256), 0, stream>>>(Vc, VTc);
  attn_mfma3_kernel<<<dim3(768), dim3(256), 0, stream>>>(
      Qc, Kc, VTc, biasc, kc, aoc);
  proj_gather_kernel<<<dim3(64, 6), dim3(256), 0, stream>>>(
      aoc, wp_bf, proj_b, kidx, kc, out);
}

// Round 8
// 180.848 us; speedup vs baseline: 1.3619x; 1.3619x over previous
//
#include <hip/hip_runtime.h>
#include <cstdint>
#include <cmath>

#define EMBED 768
#define HID 384
#define NHEAD 12
#define HDIM 64
#define BATCH 8
#define NTOK 1024
#define MINKEEP 102

using f32x4  = __attribute__((ext_vector_type(4))) float;
using short8 = __attribute__((ext_vector_type(8))) short;
using short4v = __attribute__((ext_vector_type(4))) short;
using half8  = __attribute__((ext_vector_type(8))) _Float16;

__device__ inline short f2bf(float f) {
  unsigned u = __float_as_uint(f);
  u += 0x7fffu + ((u >> 16) & 1u);
  return (short)(u >> 16);
}
__device__ inline float bf2f(short s) {
  return __uint_as_float(((unsigned)(unsigned short)s) << 16);
}
__device__ inline unsigned pack_bf2(float lo, float hi) {
  unsigned ul = __float_as_uint(lo);
  ul += 0x7fffu + ((ul >> 16) & 1u);
  unsigned uh = __float_as_uint(hi);
  uh += 0x7fffu + ((uh >> 16) & 1u);
  return (ul >> 16) | (uh & 0xffff0000u);
}
// fp16 2-way split: v = h + m + O(2^-22 v). fp16 has 11 mantissa bits;
// r = v - (float)h is exact in fp32, m captures the next 11 bits.
__device__ inline void split2h(float v, short& h, short& m) {
  _Float16 h0 = (_Float16)v;
  float r = v - (float)h0;
  _Float16 m0 = (_Float16)r;
  h = __builtin_bit_cast(short, h0);
  m = __builtin_bit_cast(short, m0);
}

// ---------------------------------------------------------------------------
// K1a: addvec[b][c] = 2*emb[idx][c]   (init for atomic accumulation)
// ---------------------------------------------------------------------------
__global__ __launch_bounds__(768) void addvec_init_kernel(
    const float* __restrict__ layer_emb, const int* __restrict__ lidx,
    float* __restrict__ addvec) {
  int b = blockIdx.x, c = threadIdx.x;
  addvec[b * EMBED + c] = 2.0f * layer_emb[lidx[0] * EMBED + c];
}

// ---------------------------------------------------------------------------
// K1b: addvec[b][c] += (1/NTOK) * sum_{n in chunk} tokens[b,n,c]
// ---------------------------------------------------------------------------
__global__ __launch_bounds__(768) void colmean_kernel(
    const float* __restrict__ tokens, float* __restrict__ addvec) {
  int b = blockIdx.x, chunk = blockIdx.y, c = threadIdx.x;
  const float* tb = tokens + ((size_t)b * NTOK + chunk * 64) * EMBED + c;
  float s = 0.f;
#pragma unroll 8
  for (int n = 0; n < 64; ++n) s += tb[(size_t)n * EMBED];
  atomicAdd(&addvec[b * EMBED + c], s * (1.0f / NTOK));
}

// ---------------------------------------------------------------------------
// K2: layernorm per row (768) -> 2 fp16 planes (xh, xm)
// ---------------------------------------------------------------------------
__global__ __launch_bounds__(256) void ln_split_kernel(
    const float* __restrict__ tokens, const float* __restrict__ addvec,
    const float* __restrict__ gamma, const float* __restrict__ beta,
    short* __restrict__ xh, short* __restrict__ xm) {
  int row = blockIdx.x;
  int b = row >> 10;
  __shared__ float s_row[EMBED];
  __shared__ float s_red[4];
  const float* tr = tokens + (size_t)row * EMBED;
  const float* av = addvec + b * EMBED;
  float lsum = 0.f;
  for (int c = threadIdx.x; c < EMBED; c += 256) {
    float v = tr[c] + av[c];
    s_row[c] = v;
    lsum += v;
  }
  for (int o = 32; o; o >>= 1) lsum += __shfl_down(lsum, o, 64);
  int wid = threadIdx.x >> 6;
  if ((threadIdx.x & 63) == 0) s_red[wid] = lsum;
  __syncthreads();
  float mu = (s_red[0] + s_red[1] + s_red[2] + s_red[3]) * (1.f / EMBED);
  float lss = 0.f;
  for (int c = threadIdx.x; c < EMBED; c += 256) {
    float d = s_row[c] - mu;
    lss += d * d;
  }
  for (int o = 32; o; o >>= 1) lss += __shfl_down(lss, o, 64);
  __syncthreads();
  if ((threadIdx.x & 63) == 0) s_red[wid] = lss;
  __syncthreads();
  float var = (s_red[0] + s_red[1] + s_red[2] + s_red[3]) * (1.f / EMBED);
  float rinv = 1.0f / sqrtf(var + 1e-5f);
  for (int c = threadIdx.x; c < EMBED; c += 256) {
    float v = (s_row[c] - mu) * rinv * gamma[c] + beta[c];
    short h, m;
    split2h(v, h, m);
    size_t idx = (size_t)row * EMBED + c;
    xh[idx] = h; xm[idx] = m;
  }
}

// ---------------------------------------------------------------------------
// f32 -> 2 fp16 planes bulk convert (4 elems/thread)
// ---------------------------------------------------------------------------
__global__ __launch_bounds__(256) void cvt_split2_kernel(
    const float* __restrict__ in, short* __restrict__ oh,
    short* __restrict__ om, int n4) {
  int i = blockIdx.x * 256 + threadIdx.x;
  if (i >= n4) return;
  float4 f = ((const float4*)in)[i];
  short4v h, m;
  short th, tm;
  split2h(f.x, th, tm); h[0] = th; m[0] = tm;
  split2h(f.y, th, tm); h[1] = th; m[1] = tm;
  split2h(f.z, th, tm); h[2] = th; m[2] = tm;
  split2h(f.w, th, tm); h[3] = th; m[3] = tm;
  ((short4v*)oh)[i] = h;
  ((short4v*)om)[i] = m;
}

// ---------------------------------------------------------------------------
// Split-fp16 MFMA GEMM (~2^-22 exact): C = A@W^T + bias, gelu.
// v8 = R1/R4's proven schedule (64x64 tile, BK=32, quad-per-row coalesced
// staging, [64][40] LDS, reg prefetch) — every schedule experiment
// (R5 write-balance, R6 bigger tile, R7 W-from-L2) regressed, so the
// schedule is kept bit-identical and the WORK is reduced instead:
// fp16 2-plane split (11 mantissa bits) with 3 MFMA products replaces
// bf16 3-plane with 6 products. LDS traffic -33%, MFMA -50%, A-plane
// HBM -33%, LDS 30KB->20KB. Residual ~3*2^-22 relative on logits (mask
// threshold comparisons still ~1e-6-safe; final absmax dominated by the
// bf16 attention path).
// ---------------------------------------------------------------------------
__device__ inline float gelu_exact(float x) {
  return 0.5f * x * (1.0f + erff(x * 0.70710678118654752f));
}

template <int OUT>
__global__ __launch_bounds__(256) void gemm_split_kernel(
    const short* __restrict__ Ah, const short* __restrict__ Am,
    const short* __restrict__ Wh, const short* __restrict__ Wm,
    const float* __restrict__ bias, short* __restrict__ Ch,
    short* __restrict__ Cm, float* __restrict__ Cf,
    int M, int N, int K) {
  __shared__ short sA[2][64][40];
  __shared__ short sW[2][64][40];
  int tid = threadIdx.x;
  int w = tid >> 6, l = tid & 63, lg = l >> 4, lb = l & 15;
  int wr = (w >> 1) * 32, wc = (w & 1) * 32;
  int row0 = blockIdx.x * 64, col0 = blockIdx.y * 64;
  int srow = tid >> 2;
  int skk = (tid & 3) * 8;
  f32x4 acc0[2][2] = {}, acc1[2][2] = {};
  short8 ra0, ra1, rw0, rw1;
  {
    size_t aoff = (size_t)(row0 + srow) * K + skk;
    size_t woff = (size_t)(col0 + srow) * K + skk;
    ra0 = *(const short8*)(Ah + aoff);
    ra1 = *(const short8*)(Am + aoff);
    rw0 = *(const short8*)(Wh + woff);
    rw1 = *(const short8*)(Wm + woff);
  }
  for (int k0 = 0; k0 < K; k0 += 32) {
    __syncthreads();
    *(short8*)&sA[0][srow][skk] = ra0;
    *(short8*)&sA[1][srow][skk] = ra1;
    *(short8*)&sW[0][srow][skk] = rw0;
    *(short8*)&sW[1][srow][skk] = rw1;
    __syncthreads();
    if (k0 + 32 < K) {
      size_t aoff = (size_t)(row0 + srow) * K + k0 + 32 + skk;
      size_t woff = (size_t)(col0 + srow) * K + k0 + 32 + skk;
      ra0 = *(const short8*)(Ah + aoff);
      ra1 = *(const short8*)(Am + aoff);
      rw0 = *(const short8*)(Wh + woff);
      rw1 = *(const short8*)(Wm + woff);
    }
    half8 ah[2], am[2], bh[2], bm[2];
#pragma unroll
    for (int i = 0; i < 2; ++i) {
      ah[i] = *(half8*)&sA[0][wr + i * 16 + lb][lg * 8];
      am[i] = *(half8*)&sA[1][wr + i * 16 + lb][lg * 8];
      bh[i] = *(half8*)&sW[0][wc + i * 16 + lb][lg * 8];
      bm[i] = *(half8*)&sW[1][wc + i * 16 + lb][lg * 8];
    }
#pragma unroll
    for (int i = 0; i < 2; ++i)
#pragma unroll
      for (int j = 0; j < 2; ++j) {
        f32x4 c0 = acc0[i][j];
        f32x4 c1 = acc1[i][j];
        c0 = __builtin_amdgcn_mfma_f32_16x16x32_f16(ah[i], bh[j], c0, 0, 0, 0);
        c1 = __builtin_amdgcn_mfma_f32_16x16x32_f16(ah[i], bm[j], c1, 0, 0, 0);
        c0 = __builtin_amdgcn_mfma_f32_16x16x32_f16(am[i], bh[j], c0, 0, 0, 0);
        acc0[i][j] = c0;
        acc1[i][j] = c1;
      }
  }
#pragma unroll
  for (int i = 0; i < 2; ++i) {
#pragma unroll
    for (int j = 0; j < 2; ++j) {
#pragma unroll
      for (int r = 0; r < 4; ++r) {
        int grow = row0 + wr + i * 16 + lg * 4 + r;
        int gcol = col0 + wc + j * 16 + lb;
        float g = gelu_exact(acc0[i][j][r] + acc1[i][j][r] + bias[gcol]);
        size_t idx = (size_t)grow * N + gcol;
        if (OUT == 0) {
          short h, m;
          split2h(g, h, m);
          Ch[idx] = h; Cm[idx] = m;
        } else {
          Cf[idx] = g;
        }
      }
    }
  }
}

// ---------------------------------------------------------------------------
// logits + sigmoid -> probs
// ---------------------------------------------------------------------------
__global__ __launch_bounds__(256) void logits_kernel(
    const float* __restrict__ h2, const float* __restrict__ w3,
    const float* __restrict__ b3, float* __restrict__ probs) {
  int row = blockIdx.x * 4 + (threadIdx.x >> 6);
  int lane = threadIdx.x & 63;
  const float* hr = h2 + (size_t)row * HID;
  float s = 0.f;
  for (int c = lane; c < HID; c += 64) s += hr[c] * w3[c];
  for (int o = 32; o; o >>= 1) s += __shfl_down(s, o, 64);
  if (lane == 0) probs[row] = 1.0f / (1.0f + expf(-(s + b3[0])));
}

// ---------------------------------------------------------------------------
// mask v3: threshold (+ gated bitonic top-102 correction), then per-batch
// COMPACTION: kidx[b][j] = ascending kept-token indices, kc[b] = count,
// biasc[b][j] = 0 for j<kc else -3e38 (softmax bias in compacted space).
// ---------------------------------------------------------------------------
__global__ __launch_bounds__(1024) void mask_kernel(
    const float* __restrict__ probs, int* __restrict__ kidx,
    int* __restrict__ kc, float* __restrict__ biasc) {
  int b = blockIdx.x, tid = threadIdx.x;
  __shared__ unsigned long long keys[1024];
  __shared__ int flag[1024];
  __shared__ int wsum[16];
  float p = probs[b * NTOK + tid];
  bool bin = (p >= 0.5f);
  int wid = tid >> 6, lane = tid & 63;
  unsigned long long bal = __ballot(bin);
  if (lane == 0) wsum[wid] = __popcll(bal);
  __syncthreads();
  int total = 0;
  for (int q = 0; q < 16; ++q) total += wsum[q];
  int mv;
  if (total >= MINKEEP) {
    mv = bin ? 1 : 0;
  } else {
    flag[tid] = 0;
    unsigned u = __float_as_uint(p);
    keys[tid] = ((unsigned long long)u << 32) | (unsigned)(1023 - tid);
    __syncthreads();
    for (int k2 = 2; k2 <= 1024; k2 <<= 1) {
      for (int j = k2 >> 1; j > 0; j >>= 1) {
        int ixj = tid ^ j;
        if (ixj > tid) {
          unsigned long long a = keys[tid], c = keys[ixj];
          bool desc = ((tid & k2) == 0);
          if (desc ? (a < c) : (a > c)) {
            keys[tid] = c;
            keys[ixj] = a;
          }
        }
        __syncthreads();
      }
    }
    if (tid < MINKEEP) {
      int idx = 1023 - (int)(keys[tid] & 0xFFFFFFFFu);
      flag[idx] = 1;
    }
    __syncthreads();
    mv = flag[tid];
  }
  if (tid == 0) mv = 1;
  __syncthreads();  // wsum reuse
  unsigned long long fb = __ballot(mv != 0);
  if (lane == 0) wsum[wid] = __popcll(fb);
  __syncthreads();
  int base = 0, tot = 0;
  for (int q = 0; q < 16; ++q) {
    int v = wsum[q];
    if (q < wid) base += v;
    tot += v;
  }
  int pre = base + __popcll(fb & ((1ull << lane) - 1ull));
  if (mv) {
    kidx[b * NTOK + pre] = tid;
    biasc[b * NTOK + pre] = 0.f;
  }
  if (tid >= tot) {
    kidx[b * NTOK + tid] = 0;
    biasc[b * NTOK + tid] = -3.0e38f;
  }
  if (tid == 0) kc[b] = tot;
}

// ---------------------------------------------------------------------------
// f32 -> bf16 bulk convert (4 elems/thread)
// ---------------------------------------------------------------------------
__global__ __launch_bounds__(256) void cvt_bf16_kernel(
    const float* __restrict__ in, short* __restrict__ out, int n4) {
  int i = blockIdx.x * 256 + threadIdx.x;
  if (i >= n4) return;
  float4 f = ((const float4*)in)[i];
  short4v s;
  s[0] = f2bf(f.x); s[1] = f2bf(f.y); s[2] = f2bf(f.z); s[3] = f2bf(f.w);
  ((short4v*)out)[i] = s;
}

// ---------------------------------------------------------------------------
// QKV gather-GEMM (compacted rows). 128x128 tile, BK=64, reg prefetch.
// b = bx&7 so wgid%8 == batch -> all 8 XCDs active.
// ---------------------------------------------------------------------------
__global__ __launch_bounds__(256) void qkv_gather_kernel(
    const short* __restrict__ tok_bf, const short* __restrict__ W,
    const float* __restrict__ bias, const int* __restrict__ kidx,
    const int* __restrict__ kc, short* __restrict__ qq,
    short* __restrict__ kk_, short* __restrict__ vv) {
  __shared__ short sA[128][72];
  __shared__ short sW[128][72];
  __shared__ int s_idx[128];
  int bx = blockIdx.x;
  int b = bx & 7, bt = bx >> 3;
  int kcb = kc[b];
  if (bt * 128 >= kcb) return;
  int tid = threadIdx.x;
  if (tid < 128) s_idx[tid] = kidx[b * NTOK + bt * 128 + tid];
  int w = tid >> 6, l = tid & 63, lg = l >> 4, lb = l & 15;
  int wr = (w >> 1) * 64, wc = (w & 1) * 64;
  int col0 = blockIdx.y * 128;
  int r_ = tid >> 3, kq = (tid & 7) * 8;
  __syncthreads();  // s_idx ready
  const short* Ab = tok_bf + (size_t)b * NTOK * EMBED;
  f32x4 acc[4][4] = {};
  short8 pa[4], pw[4];
#pragma unroll
  for (int t = 0; t < 4; ++t) {
    pa[t] = *(const short8*)(Ab + (size_t)s_idx[t * 32 + r_] * EMBED + kq);
    pw[t] = *(const short8*)(W + (size_t)(col0 + t * 32 + r_) * EMBED + kq);
  }
  for (int k0 = 0; k0 < EMBED; k0 += 64) {
    __syncthreads();
#pragma unroll
    for (int t = 0; t < 4; ++t) {
      *(short8*)&sA[t * 32 + r_][kq] = pa[t];
      *(short8*)&sW[t * 32 + r_][kq] = pw[t];
    }
    __syncthreads();
    if (k0 + 64 < EMBED) {
#pragma unroll
      for (int t = 0; t < 4; ++t) {
        pa[t] = *(const short8*)(Ab + (size_t)s_idx[t * 32 + r_] * EMBED +
                                 k0 + 64 + kq);
        pw[t] = *(const short8*)(W + (size_t)(col0 + t * 32 + r_) * EMBED +
                                 k0 + 64 + kq);
      }
    }
#pragma unroll
    for (int half = 0; half < 2; ++half) {
      short8 af[4], bfr[4];
#pragma unroll
      for (int i = 0; i < 4; ++i)
        af[i] = *(short8*)&sA[wr + i * 16 + lb][half * 32 + lg * 8];
#pragma unroll
      for (int j = 0; j < 4; ++j)
        bfr[j] = *(short8*)&sW[wc + j * 16 + lb][half * 32 + lg * 8];
#pragma unroll
      for (int i = 0; i < 4; ++i)
#pragma unroll
        for (int j = 0; j < 4; ++j)
          acc[i][j] = __builtin_amdgcn_mfma_f32_16x16x32_bf16(af[i], bfr[j],
                                                              acc[i][j], 0, 0, 0);
    }
  }
#pragma unroll
  for (int i = 0; i < 4; ++i) {
#pragma unroll
    for (int j = 0; j < 4; ++j) {
#pragma unroll
      for (int r = 0; r < 4; ++r) {
        int jrow = bt * 128 + wr + i * 16 + lg * 4 + r;  // compacted position
        int gcol = col0 + wc + j * 16 + lb;
        float val = acc[i][j][r] + bias[gcol];
        int which = gcol / EMBED;
        int rem = gcol - which * EMBED;
        int h = rem >> 6, d = rem & 63;
        size_t dst = ((size_t)(b * NHEAD + h) * NTOK + jrow) * HDIM + d;
        if (which == 0)
          qq[dst] = f2bf(val * 0.125f);
        else if (which == 1)
          kk_[dst] = f2bf(val);
        else
          vv[dst] = f2bf(val);
      }
    }
  }
}

// ---------------------------------------------------------------------------
// V transpose: Vc[bh][j][d] -> VTc[bh][d][j]
// ---------------------------------------------------------------------------
__global__ __launch_bounds__(256) void vtrans_kernel(
    const short* __restrict__ Vb, short* __restrict__ VT) {
  int bh = blockIdx.y;
  int n0 = blockIdx.x * 64;
  __shared__ short st[64][72];
  int tid = threadIdx.x;
#pragma unroll
  for (int t = 0; t < 2; ++t) {
    int c = tid + t * 256;
    int n = c >> 3, ds = c & 7;
    *(short8*)&st[n][ds * 8] =
        *(const short8*)(Vb + ((size_t)bh * NTOK + n0 + n) * HDIM + ds * 8);
  }
  __syncthreads();
#pragma unroll
  for (int t = 0; t < 2; ++t) {
    int c = tid + t * 256;
    int d = c >> 3, ns = c & 7;
    short8 tmp;
#pragma unroll
    for (int jj = 0; jj < 8; ++jj) tmp[jj] = st[ns * 8 + jj][d];
    *(short8*)(VT + ((size_t)bh * HDIM + d) * NTOK + n0 + ns * 8) = tmp;
  }
}

// ---------------------------------------------------------------------------
// MFMA flash attention v3 — compacted token space. Loop count nt =
// ceil(kc[b]/64) read from device. Pad slots carry bias -3e38 -> P = 0.
// ---------------------------------------------------------------------------
#define ATTN_SWZ(row, colbyte) (((row)*128) + ((colbyte) ^ (((row)&7) << 4)))

__global__ __launch_bounds__(256) void attn_mfma3_kernel(
    const short* __restrict__ Qc, const short* __restrict__ Kc,
    const short* __restrict__ VTc, const float* __restrict__ biasc,
    const int* __restrict__ kc, short* __restrict__ ao) {
  __shared__ __align__(16) short sK[64 * 64];
  __shared__ __align__(16) short sVT[64 * 64];
  int bid = blockIdx.x;
  int xcd = bid & 7, slot = bid >> 3;
  int bh = xcd * 12 + (slot >> 3);
  int qt = slot & 7;
  int b = bh / NHEAD;
  int kcb = kc[b];
  if (qt * 128 >= kcb) return;
  int nt = (kcb + 63) >> 6;
  int tid = threadIdx.x;
  int w = tid >> 6, l = tid & 63, lg = l >> 4, lb = l & 15;
  int n0 = qt * 128 + w * 32;
  const short* Qp = Qc + ((size_t)bh * NTOK + n0) * HDIM;
  const short* Kp = Kc + (size_t)bh * NTOK * HDIM;
  const short* Vp = VTc + (size_t)bh * HDIM * NTOK;
  const float* bp = biasc + b * NTOK;

  short8 qf[2][2];
#pragma unroll
  for (int i = 0; i < 2; ++i)
#pragma unroll
    for (int hh = 0; hh < 2; ++hh)
      qf[i][hh] = *(const short8*)(Qp + (i * 16 + lb) * HDIM + hh * 32 + lg * 8);

  f32x4 acc[2][4] = {};
  float lr[2] = {0.f, 0.f};

  int srow = tid >> 3;
  int scol = (tid & 7) * 8;
  int scolb = scol * 2;
  short8 rk0, rk1, rv0, rv1;

#define ATTN_LOADT(m0_)                                                        \
  {                                                                            \
    rk0 = *(const short8*)(Kp + (size_t)((m0_) + srow) * HDIM + scol);         \
    rk1 = *(const short8*)(Kp + (size_t)((m0_) + srow + 32) * HDIM + scol);    \
    rv0 = *(const short8*)(Vp + (size_t)srow * NTOK + (m0_) + scol);           \
    rv1 = *(const short8*)(Vp + (size_t)(srow + 32) * NTOK + (m0_) + scol);    \
  }

  ATTN_LOADT(0);
  for (int t = 0; t < nt; ++t) {
    int m0 = t * 64;
    *(short8*)((char*)sK + ATTN_SWZ(srow, scolb)) = rk0;
    *(short8*)((char*)sK + ATTN_SWZ(srow + 32, scolb)) = rk1;
    *(short8*)((char*)sVT + ATTN_SWZ(srow, scolb)) = rv0;
    *(short8*)((char*)sVT + ATTN_SWZ(srow + 32, scolb)) = rv1;
    __syncthreads();
    if (t + 1 < nt) ATTN_LOADT(m0 + 64);

    f32x4 bias4[4];
#pragma unroll
    for (int s = 0; s < 4; ++s)
      bias4[s] = *(const f32x4*)(bp + m0 + s * 16 + lg * 4);

    f32x4 S[2][4];
#pragma unroll
    for (int s = 0; s < 4; ++s) {
      short8 kf0 = *(const short8*)((const char*)sK +
                                    ATTN_SWZ(s * 16 + lb, lg * 16));
      short8 kf1 = *(const short8*)((const char*)sK +
                                    ATTN_SWZ(s * 16 + lb, 64 + lg * 16));
#pragma unroll
      for (int i = 0; i < 2; ++i) {
        f32x4 c = bias4[s];
        c = __builtin_amdgcn_mfma_f32_16x16x32_bf16(kf0, qf[i][0], c, 0, 0, 0);
        c = __builtin_amdgcn_mfma_f32_16x16x32_bf16(kf1, qf[i][1], c, 0, 0, 0);
        S[i][s] = c;
      }
    }

    unsigned pk[2][4][2];
#pragma unroll
    for (int i = 0; i < 2; ++i) {
      float rs = 0.f;
#pragma unroll
      for (int s = 0; s < 4; ++s) {
        float p0 = __expf(S[i][s][0]);
        float p1 = __expf(S[i][s][1]);
        float p2 = __expf(S[i][s][2]);
        float p3 = __expf(S[i][s][3]);
        rs += (p0 + p1) + (p2 + p3);
        pk[i][s][0] = pack_bf2(p0, p1);
        pk[i][s][1] = pack_bf2(p2, p3);
      }
      rs += __shfl_xor(rs, 16);
      rs += __shfl_xor(rs, 32);
      lr[i] += rs;
    }

    bool hi = (lg & 2) != 0;
    int srcl = ((lg & 1) * 2) * 16 + lb;
#pragma unroll
    for (int t2 = 0; t2 < 2; ++t2) {
      short8 vf[4];
#pragma unroll
      for (int u = 0; u < 4; ++u)
        vf[u] = *(const short8*)((const char*)sVT +
                                 ATTN_SWZ(u * 16 + lb, t2 * 64 + lg * 16));
#pragma unroll
      for (int i = 0; i < 2; ++i) {
        int a0 = __shfl((int)pk[i][2 * t2][0], srcl);
        int b0 = __shfl((int)pk[i][2 * t2 + 1][0], srcl);
        int a1 = __shfl((int)pk[i][2 * t2][1], srcl);
        int b1 = __shfl((int)pk[i][2 * t2 + 1][1], srcl);
        int a2 = __shfl((int)pk[i][2 * t2][0], srcl + 16);
        int b2 = __shfl((int)pk[i][2 * t2 + 1][0], srcl + 16);
        int a3 = __shfl((int)pk[i][2 * t2][1], srcl + 16);
        int b3 = __shfl((int)pk[i][2 * t2 + 1][1], srcl + 16);
        union { short8 s8; int u[4]; } pa;
        pa.u[0] = hi ? b0 : a0;
        pa.u[1] = hi ? b1 : a1;
        pa.u[2] = hi ? b2 : a2;
        pa.u[3] = hi ? b3 : a3;
#pragma unroll
        for (int u = 0; u < 4; ++u)
          acc[i][u] = __builtin_amdgcn_mfma_f32_16x16x32_bf16(pa.s8, vf[u],
                                                              acc[i][u], 0, 0, 0);
      }
    }
    __syncthreads();
  }

  int h = bh - b * NHEAD;
#pragma unroll
  for (int i = 0; i < 2; ++i) {
#pragma unroll
    for (int r = 0; r < 4; ++r) {
      float inv = 1.0f / __shfl(lr[i], lg * 4 + r);
      int j = n0 + i * 16 + lg * 4 + r;  // compacted row
#pragma unroll
      for (int u = 0; u < 4; ++u) {
        ao[((size_t)b * NTOK + j) * EMBED + h * HDIM + u * 16 + lb] =
            f2bf(acc[i][u][r] * inv);
      }
    }
  }
}

// ---------------------------------------------------------------------------
// Proj gather-GEMM: A = aoc (compacted rows, dense), W = proj weights.
// ---------------------------------------------------------------------------
__global__ __launch_bounds__(256) void proj_gather_kernel(
    const short* __restrict__ A, const short* __restrict__ W,
    const float* __restrict__ bias, const int* __restrict__ kidx,
    const int* __restrict__ kc, float* __restrict__ out) {
  __shared__ short sA[128][72];
  __shared__ short sW[128][72];
  __shared__ int s_idx[128];
  int bx = blockIdx.x;
  int b = bx & 7, bt = bx >> 3;
  int kcb = kc[b];
  if (bt * 128 >= kcb) return;
  int tid = threadIdx.x;
  if (tid < 128) s_idx[tid] = kidx[b * NTOK + bt * 128 + tid];
  int w = tid >> 6, l = tid & 63, lg = l >> 4, lb = l & 15;
  int wr = (w >> 1) * 64, wc = (w & 1) * 64;
  int col0 = blockIdx.y * 128;
  int r_ = tid >> 3, kq = (tid & 7) * 8;
  const short* Ab = A + ((size_t)b * NTOK + bt * 128) * EMBED;
  f32x4 acc[4][4] = {};
  short8 pa[4], pw[4];
#pragma unroll
  for (int t = 0; t < 4; ++t) {
    pa[t] = *(const short8*)(Ab + (size_t)(t * 32 + r_) * EMBED + kq);
    pw[t] = *(const short8*)(W + (size_t)(col0 + t * 32 + r_) * EMBED + kq);
  }
  for (int k0 = 0; k0 < EMBED; k0 += 64) {
    __syncthreads();
#pragma unroll
    for (int t = 0; t < 4; ++t) {
      *(short8*)&sA[t * 32 + r_][kq] = pa[t];
      *(short8*)&sW[t * 32 + r_][kq] = pw[t];
    }
    __syncthreads();
    if (k0 + 64 < EMBED) {
#pragma unroll
      for (int t = 0; t < 4; ++t) {
        pa[t] = *(const short8*)(Ab + (size_t)(t * 32 + r_) * EMBED + k0 + 64 + kq);
        pw[t] = *(const short8*)(W + (size_t)(col0 + t * 32 + r_) * EMBED + k0 + 64 + kq);
      }
    }
#pragma unroll
    for (int half = 0; half < 2; ++half) {
      short8 af[4], bfr[4];
#pragma unroll
      for (int i = 0; i < 4; ++i)
        af[i] = *(short8*)&sA[wr + i * 16 + lb][half * 32 + lg * 8];
#pragma unroll
      for (int j = 0; j < 4; ++j)
        bfr[j] = *(short8*)&sW[wc + j * 16 + lb][half * 32 + lg * 8];
#pragma unroll
      for (int i = 0; i < 4; ++i)
#pragma unroll
        for (int j = 0; j < 4; ++j)
          acc[i][j] = __builtin_amdgcn_mfma_f32_16x16x32_bf16(af[i], bfr[j],
                                                              acc[i][j], 0, 0, 0);
    }
  }
#pragma unroll
  for (int i = 0; i < 4; ++i) {
#pragma unroll
    for (int j = 0; j < 4; ++j) {
#pragma unroll
      for (int r = 0; r < 4; ++r) {
        int jloc = wr + i * 16 + lg * 4 + r;
        int jrow = bt * 128 + jloc;
        int gcol = col0 + wc + j * 16 + lb;
        if (jrow < kcb) {
          int n = s_idx[jloc];
          out[((size_t)b * NTOK + n) * EMBED + gcol] = acc[i][j][r] + bias[gcol];
        }
      }
    }
  }
}

// ---------------------------------------------------------------------------
extern "C" void kernel_launch(void* const* d_in, const int* in_sizes, int n_in,
                              void* d_out, int out_size, void* d_ws, size_t ws_size,
                              hipStream_t stream) {
  const float* tokens   = (const float*)d_in[0];
  const int*   lidx     = (const int*)d_in[1];
  const float* layer_emb= (const float*)d_in[2];
  const float* ln_g     = (const float*)d_in[3];
  const float* ln_b     = (const float*)d_in[4];
  const float* w1       = (const float*)d_in[5];
  const float* b1       = (const float*)d_in[6];
  const float* w2       = (const float*)d_in[7];
  const float* b2       = (const float*)d_in[8];
  const float* w3       = (const float*)d_in[9];
  const float* b3       = (const float*)d_in[10];
  const float* qkv_w    = (const float*)d_in[11];
  const float* qkv_b    = (const float*)d_in[12];
  const float* proj_w   = (const float*)d_in[13];
  const float* proj_b   = (const float*)d_in[14];
  float* out = (float*)d_out;
  float* ws = (float*)d_ws;

  float* addvec = ws;
  float* probs  = ws + 6144;
  int*   kidx   = (int*)(ws + 14336);
  float* biasc  = ws + 22528;
  int*   kc     = (int*)(ws + 30720);
  short* tok_bf = (short*)(ws + 30736);
  short* wq_bf  = (short*)(ws + 3176464);
  short* wp_bf  = (short*)(ws + 4061200);
  short* w1h = (short*)(ws + 4356112);
  short* w1m = (short*)(ws + 4503568);
  short* w2h = (short*)(ws + 4798480);
  short* w2m = (short*)(ws + 4872208);
  const size_t X0 = 5019664;
  short* xh  = (short*)(ws + X0);
  short* xm  = (short*)(ws + X0 + 3145728);
  short* h1h = (short*)(ws + X0 + 9437184);
  short* h1m = (short*)(ws + X0 + 11010048);
  float* h2  = ws + X0 + 14155776;
  short* Qc   = (short*)(ws + X0);
  short* Kc   = (short*)(ws + X0 + 3145728);
  short* Vc   = (short*)(ws + X0 + 6291456);
  short* VTc  = (short*)(ws + X0 + 9437184);
  short* aoc  = (short*)(ws + X0 + 12582912);

  // masked output rows are exactly 0 in the reference -> pre-zero d_out
  hipMemsetAsync(d_out, 0, (size_t)out_size * sizeof(float), stream);

  // bf16 / fp16-split conversions
  cvt_bf16_kernel<<<dim3(6144), dim3(256), 0, stream>>>(tokens, tok_bf, 1572864);
  cvt_bf16_kernel<<<dim3(1728), dim3(256), 0, stream>>>(qkv_w, wq_bf, 442368);
  cvt_bf16_kernel<<<dim3(576),  dim3(256), 0, stream>>>(proj_w, wp_bf, 147456);
  cvt_split2_kernel<<<dim3(288), dim3(256), 0, stream>>>(w1, w1h, w1m, 73728);
  cvt_split2_kernel<<<dim3(144), dim3(256), 0, stream>>>(w2, w2h, w2m, 36864);

  // mask path (~2^-22-exact via 2-plane fp16 split MFMA)
  addvec_init_kernel<<<dim3(BATCH), dim3(768), 0, stream>>>(layer_emb, lidx, addvec);
  colmean_kernel<<<dim3(BATCH, 16), dim3(768), 0, stream>>>(tokens, addvec);
  ln_split_kernel<<<dim3(BATCH * NTOK), dim3(256), 0, stream>>>(
      tokens, addvec, ln_g, ln_b, xh, xm);
  gemm_split_kernel<0><<<dim3(128, 6), dim3(256), 0, stream>>>(
      xh, xm, w1h, w1m, b1, h1h, h1m, nullptr,
      BATCH * NTOK, HID, EMBED);
  gemm_split_kernel<1><<<dim3(128, 6), dim3(256), 0, stream>>>(
      h1h, h1m, w2h, w2m, b2, nullptr, nullptr, h2,
      BATCH * NTOK, HID, HID);
  logits_kernel<<<dim3(2048), dim3(256), 0, stream>>>(h2, w3, b3, probs);
  mask_kernel<<<dim3(BATCH), dim3(1024), 0, stream>>>(probs, kidx, kc, biasc);

  // attention path, compacted token space (~kc of 1024 tokens per batch)
  qkv_gather_kernel<<<dim3(64, 18), dim3(256), 0, stream>>>(
      tok_bf, wq_bf, qkv_b, kidx, kc, Qc, Kc, Vc);
  vtrans_kernel<<<dim3(16, BATCH * NHEAD), dim3(256), 0, stream>>>(Vc, VTc);
  attn_mfma3_kernel<<<dim3(768), dim3(256), 0, stream>>>(
      Qc, Kc, VTc, biasc, kc, aoc);
  proj_gather_kernel<<<dim3(64, 6), dim3(256), 0, stream>>>(
      aoc, wp_bf, proj_b, kidx, kc, out);
}

// Round 9
// 166.434 us; speedup vs baseline: 1.4798x; 1.0866x over previous
//
#include <hip/hip_runtime.h>
#include <cstdint>
#include <cmath>

#define EMBED 768
#define HID 384
#define NHEAD 12
#define HDIM 64
#define BATCH 8
#define NTOK 1024
#define MINKEEP 102

using f32x4  = __attribute__((ext_vector_type(4))) float;
using short8 = __attribute__((ext_vector_type(8))) short;
using short4v = __attribute__((ext_vector_type(4))) short;
using half8  = __attribute__((ext_vector_type(8))) _Float16;

__device__ inline short f2bf(float f) {
  unsigned u = __float_as_uint(f);
  u += 0x7fffu + ((u >> 16) & 1u);
  return (short)(u >> 16);
}
__device__ inline float bf2f(short s) {
  return __uint_as_float(((unsigned)(unsigned short)s) << 16);
}
__device__ inline unsigned pack_bf2(float lo, float hi) {
  unsigned ul = __float_as_uint(lo);
  ul += 0x7fffu + ((ul >> 16) & 1u);
  unsigned uh = __float_as_uint(hi);
  uh += 0x7fffu + ((uh >> 16) & 1u);
  return (ul >> 16) | (uh & 0xffff0000u);
}
// fp16 2-way split: v = h + m + O(2^-22 v).
__device__ inline void split2h(float v, short& h, short& m) {
  _Float16 h0 = (_Float16)v;
  float r = v - (float)h0;
  _Float16 m0 = (_Float16)r;
  h = __builtin_bit_cast(short, h0);
  m = __builtin_bit_cast(short, m0);
}

// ---------------------------------------------------------------------------
// prep: all weight conversions + addvec init in ONE dispatch (block ranges).
//  [0,1728)      qkv_w  -> bf16          (442368 thr x float4)
//  [1728,2304)   proj_w -> bf16          (147456 thr)
//  [2304,2592)   w1     -> fp16 h/m      (73728 thr)
//  [2592,2736)   w2     -> fp16 h/m      (36864 thr)
//  [2736,2760)   addvec[b][c] = 2*emb[idx][c]  (6144 thr)
// ---------------------------------------------------------------------------
__global__ __launch_bounds__(256) void prep_kernel(
    const float* __restrict__ qkv_w, short* __restrict__ wq_bf,
    const float* __restrict__ proj_w, short* __restrict__ wp_bf,
    const float* __restrict__ w1, short* __restrict__ w1h, short* __restrict__ w1m,
    const float* __restrict__ w2, short* __restrict__ w2h, short* __restrict__ w2m,
    const float* __restrict__ layer_emb, const int* __restrict__ lidx,
    float* __restrict__ addvec) {
  int blk = blockIdx.x, tid = threadIdx.x;
  if (blk < 2304) {
    const float* in = (blk < 1728) ? qkv_w : proj_w;
    short* out = (blk < 1728) ? wq_bf : wp_bf;
    int i = (blk < 1728 ? blk : blk - 1728) * 256 + tid;
    float4 f = ((const float4*)in)[i];
    short4v s;
    s[0] = f2bf(f.x); s[1] = f2bf(f.y); s[2] = f2bf(f.z); s[3] = f2bf(f.w);
    ((short4v*)out)[i] = s;
  } else if (blk < 2736) {
    const float* in = (blk < 2592) ? w1 : w2;
    short* oh = (blk < 2592) ? w1h : w2h;
    short* om = (blk < 2592) ? w1m : w2m;
    int i = (blk < 2592 ? blk - 2304 : blk - 2592) * 256 + tid;
    float4 f = ((const float4*)in)[i];
    short4v h, m;
    short th, tm;
    split2h(f.x, th, tm); h[0] = th; m[0] = tm;
    split2h(f.y, th, tm); h[1] = th; m[1] = tm;
    split2h(f.z, th, tm); h[2] = th; m[2] = tm;
    split2h(f.w, th, tm); h[3] = th; m[3] = tm;
    ((short4v*)oh)[i] = h;
    ((short4v*)om)[i] = m;
  } else {
    int i = (blk - 2736) * 256 + tid;  // 0..6143
    int c = i & (EMBED - 1);           // EMBED=768 not pow2 -> compute properly
    c = i % EMBED;
    addvec[i] = 2.0f * layer_emb[lidx[0] * EMBED + c];
  }
}

// ---------------------------------------------------------------------------
// colmean: addvec[b][c] += (1/NTOK) * sum_{n in chunk} tokens[b,n,c]
// ---------------------------------------------------------------------------
__global__ __launch_bounds__(768) void colmean_kernel(
    const float* __restrict__ tokens, float* __restrict__ addvec) {
  int b = blockIdx.x, chunk = blockIdx.y, c = threadIdx.x;
  const float* tb = tokens + ((size_t)b * NTOK + chunk * 64) * EMBED + c;
  float s = 0.f;
#pragma unroll 8
  for (int n = 0; n < 64; ++n) s += tb[(size_t)n * EMBED];
  atomicAdd(&addvec[b * EMBED + c], s * (1.0f / NTOK));
}

// ---------------------------------------------------------------------------
// K2: layernorm per row (768) -> 2 fp16 planes (xh, xm) + tok_bf (fused cvt:
// we already read every token element in f32, so emit its bf16 here and
// drop the dedicated 25MB-read cvt kernel).
// ---------------------------------------------------------------------------
__global__ __launch_bounds__(256) void ln_split_kernel(
    const float* __restrict__ tokens, const float* __restrict__ addvec,
    const float* __restrict__ gamma, const float* __restrict__ beta,
    short* __restrict__ xh, short* __restrict__ xm,
    short* __restrict__ tok_bf) {
  int row = blockIdx.x;
  int b = row >> 10;
  __shared__ float s_row[EMBED];
  __shared__ float s_red[4];
  const float* tr = tokens + (size_t)row * EMBED;
  const float* av = addvec + b * EMBED;
  float lsum = 0.f;
  for (int c = threadIdx.x; c < EMBED; c += 256) {
    float t = tr[c];
    tok_bf[(size_t)row * EMBED + c] = f2bf(t);
    float v = t + av[c];
    s_row[c] = v;
    lsum += v;
  }
  for (int o = 32; o; o >>= 1) lsum += __shfl_down(lsum, o, 64);
  int wid = threadIdx.x >> 6;
  if ((threadIdx.x & 63) == 0) s_red[wid] = lsum;
  __syncthreads();
  float mu = (s_red[0] + s_red[1] + s_red[2] + s_red[3]) * (1.f / EMBED);
  float lss = 0.f;
  for (int c = threadIdx.x; c < EMBED; c += 256) {
    float d = s_row[c] - mu;
    lss += d * d;
  }
  for (int o = 32; o; o >>= 1) lss += __shfl_down(lss, o, 64);
  __syncthreads();
  if ((threadIdx.x & 63) == 0) s_red[wid] = lss;
  __syncthreads();
  float var = (s_red[0] + s_red[1] + s_red[2] + s_red[3]) * (1.f / EMBED);
  float rinv = 1.0f / sqrtf(var + 1e-5f);
  for (int c = threadIdx.x; c < EMBED; c += 256) {
    float v = (s_row[c] - mu) * rinv * gamma[c] + beta[c];
    short h, m;
    split2h(v, h, m);
    size_t idx = (size_t)row * EMBED + c;
    xh[idx] = h; xm[idx] = m;
  }
}

// ---------------------------------------------------------------------------
// Split-fp16 MFMA GEMM (~2^-22 exact): C = A@W^T + bias, gelu.
// R1/R4 proven schedule. OUT==0: write fp16 h/m planes (h1).
// OUT==1: FUSED LOGITS — no h2 materialization; per-thread partial
// sum(g * w3[col]), shfl_xor reduce over the 16-lane col group, one
// atomicAdd per (row, col-tile) into lgt[row]. Saves 25MB of h2 traffic
// + the logits kernel. (sigmoid is applied implicitly in mask: monotone.)
// ---------------------------------------------------------------------------
__device__ inline float gelu_exact(float x) {
  return 0.5f * x * (1.0f + erff(x * 0.70710678118654752f));
}

template <int OUT>
__global__ __launch_bounds__(256) void gemm_split_kernel(
    const short* __restrict__ Ah, const short* __restrict__ Am,
    const short* __restrict__ Wh, const short* __restrict__ Wm,
    const float* __restrict__ bias, short* __restrict__ Ch,
    short* __restrict__ Cm, const float* __restrict__ w3,
    float* __restrict__ lgt, int M, int N, int K) {
  __shared__ short sA[2][64][40];
  __shared__ short sW[2][64][40];
  int tid = threadIdx.x;
  int w = tid >> 6, l = tid & 63, lg = l >> 4, lb = l & 15;
  int wr = (w >> 1) * 32, wc = (w & 1) * 32;
  int row0 = blockIdx.x * 64, col0 = blockIdx.y * 64;
  int srow = tid >> 2;
  int skk = (tid & 3) * 8;
  f32x4 acc0[2][2] = {}, acc1[2][2] = {};
  short8 ra0, ra1, rw0, rw1;
  {
    size_t aoff = (size_t)(row0 + srow) * K + skk;
    size_t woff = (size_t)(col0 + srow) * K + skk;
    ra0 = *(const short8*)(Ah + aoff);
    ra1 = *(const short8*)(Am + aoff);
    rw0 = *(const short8*)(Wh + woff);
    rw1 = *(const short8*)(Wm + woff);
  }
  for (int k0 = 0; k0 < K; k0 += 32) {
    __syncthreads();
    *(short8*)&sA[0][srow][skk] = ra0;
    *(short8*)&sA[1][srow][skk] = ra1;
    *(short8*)&sW[0][srow][skk] = rw0;
    *(short8*)&sW[1][srow][skk] = rw1;
    __syncthreads();
    if (k0 + 32 < K) {
      size_t aoff = (size_t)(row0 + srow) * K + k0 + 32 + skk;
      size_t woff = (size_t)(col0 + srow) * K + k0 + 32 + skk;
      ra0 = *(const short8*)(Ah + aoff);
      ra1 = *(const short8*)(Am + aoff);
      rw0 = *(const short8*)(Wh + woff);
      rw1 = *(const short8*)(Wm + woff);
    }
    half8 ah[2], am[2], bh[2], bm[2];
#pragma unroll
    for (int i = 0; i < 2; ++i) {
      ah[i] = *(half8*)&sA[0][wr + i * 16 + lb][lg * 8];
      am[i] = *(half8*)&sA[1][wr + i * 16 + lb][lg * 8];
      bh[i] = *(half8*)&sW[0][wc + i * 16 + lb][lg * 8];
      bm[i] = *(half8*)&sW[1][wc + i * 16 + lb][lg * 8];
    }
#pragma unroll
    for (int i = 0; i < 2; ++i)
#pragma unroll
      for (int j = 0; j < 2; ++j) {
        f32x4 c0 = acc0[i][j];
        f32x4 c1 = acc1[i][j];
        c0 = __builtin_amdgcn_mfma_f32_16x16x32_f16(ah[i], bh[j], c0, 0, 0, 0);
        c1 = __builtin_amdgcn_mfma_f32_16x16x32_f16(ah[i], bm[j], c1, 0, 0, 0);
        c0 = __builtin_amdgcn_mfma_f32_16x16x32_f16(am[i], bh[j], c0, 0, 0, 0);
        acc0[i][j] = c0;
        acc1[i][j] = c1;
      }
  }
  if (OUT == 0) {
#pragma unroll
    for (int i = 0; i < 2; ++i) {
#pragma unroll
      for (int j = 0; j < 2; ++j) {
#pragma unroll
        for (int r = 0; r < 4; ++r) {
          int grow = row0 + wr + i * 16 + lg * 4 + r;
          int gcol = col0 + wc + j * 16 + lb;
          float g = gelu_exact(acc0[i][j][r] + acc1[i][j][r] + bias[gcol]);
          size_t idx = (size_t)grow * N + gcol;
          short h, m;
          split2h(g, h, m);
          Ch[idx] = h; Cm[idx] = m;
        }
      }
    }
  } else {
    float part[2][4];
#pragma unroll
    for (int i = 0; i < 2; ++i)
#pragma unroll
      for (int r = 0; r < 4; ++r) part[i][r] = 0.f;
#pragma unroll
    for (int i = 0; i < 2; ++i) {
#pragma unroll
      for (int j = 0; j < 2; ++j) {
#pragma unroll
        for (int r = 0; r < 4; ++r) {
          int gcol = col0 + wc + j * 16 + lb;
          float g = gelu_exact(acc0[i][j][r] + acc1[i][j][r] + bias[gcol]);
          part[i][r] += g * w3[gcol];
        }
      }
    }
#pragma unroll
    for (int i = 0; i < 2; ++i) {
#pragma unroll
      for (int r = 0; r < 4; ++r) {
        float v = part[i][r];
        v += __shfl_xor(v, 1);
        v += __shfl_xor(v, 2);
        v += __shfl_xor(v, 4);
        v += __shfl_xor(v, 8);
        if (lb == 0) atomicAdd(&lgt[row0 + wr + i * 16 + lg * 4 + r], v);
      }
    }
  }
}

// ---------------------------------------------------------------------------
// mask v4: consumes RAW LOGITS (sigmoid monotone: p>=0.5 <=> logit+b3>=0;
// top-k order preserved). Bitonic key uses the sign-flip order-preserving
// map since logits can be negative. Then per-batch compaction.
// ---------------------------------------------------------------------------
__global__ __launch_bounds__(1024) void mask_kernel(
    const float* __restrict__ lgt, const float* __restrict__ b3,
    int* __restrict__ kidx, int* __restrict__ kc, float* __restrict__ biasc) {
  int b = blockIdx.x, tid = threadIdx.x;
  __shared__ unsigned long long keys[1024];
  __shared__ int flag[1024];
  __shared__ int wsum[16];
  float v = lgt[b * NTOK + tid] + b3[0];
  bool bin = (v >= 0.0f);
  int wid = tid >> 6, lane = tid & 63;
  unsigned long long bal = __ballot(bin);
  if (lane == 0) wsum[wid] = __popcll(bal);
  __syncthreads();
  int total = 0;
  for (int q = 0; q < 16; ++q) total += wsum[q];
  int mv;
  if (total >= MINKEEP) {
    mv = bin ? 1 : 0;
  } else {
    flag[tid] = 0;
    unsigned u = __float_as_uint(v);
    u = (u & 0x80000000u) ? ~u : (u | 0x80000000u);  // order-preserving map
    keys[tid] = ((unsigned long long)u << 32) | (unsigned)(1023 - tid);
    __syncthreads();
    for (int k2 = 2; k2 <= 1024; k2 <<= 1) {
      for (int j = k2 >> 1; j > 0; j >>= 1) {
        int ixj = tid ^ j;
        if (ixj > tid) {
          unsigned long long a = keys[tid], c = keys[ixj];
          bool desc = ((tid & k2) == 0);
          if (desc ? (a < c) : (a > c)) {
            keys[tid] = c;
            keys[ixj] = a;
          }
        }
        __syncthreads();
      }
    }
    if (tid < MINKEEP) {
      int idx = 1023 - (int)(keys[tid] & 0xFFFFFFFFu);
      flag[idx] = 1;
    }
    __syncthreads();
    mv = flag[tid];
  }
  if (tid == 0) mv = 1;
  __syncthreads();  // wsum reuse
  unsigned long long fb = __ballot(mv != 0);
  if (lane == 0) wsum[wid] = __popcll(fb);
  __syncthreads();
  int base = 0, tot = 0;
  for (int q = 0; q < 16; ++q) {
    int vq = wsum[q];
    if (q < wid) base += vq;
    tot += vq;
  }
  int pre = base + __popcll(fb & ((1ull << lane) - 1ull));
  if (mv) {
    kidx[b * NTOK + pre] = tid;
    biasc[b * NTOK + pre] = 0.f;
  }
  if (tid >= tot) {
    kidx[b * NTOK + tid] = 0;
    biasc[b * NTOK + tid] = -3.0e38f;
  }
  if (tid == 0) kc[b] = tot;
}

// ---------------------------------------------------------------------------
// QKV gather-GEMM (compacted rows). 128x128 tile, BK=64, reg prefetch.
// b = bx&7 so wgid%8 == batch -> all 8 XCDs active.
// ---------------------------------------------------------------------------
__global__ __launch_bounds__(256) void qkv_gather_kernel(
    const short* __restrict__ tok_bf, const short* __restrict__ W,
    const float* __restrict__ bias, const int* __restrict__ kidx,
    const int* __restrict__ kc, short* __restrict__ qq,
    short* __restrict__ kk_, short* __restrict__ vv) {
  __shared__ short sA[128][72];
  __shared__ short sW[128][72];
  __shared__ int s_idx[128];
  int bx = blockIdx.x;
  int b = bx & 7, bt = bx >> 3;
  int kcb = kc[b];
  if (bt * 128 >= kcb) return;
  int tid = threadIdx.x;
  if (tid < 128) s_idx[tid] = kidx[b * NTOK + bt * 128 + tid];
  int w = tid >> 6, l = tid & 63, lg = l >> 4, lb = l & 15;
  int wr = (w >> 1) * 64, wc = (w & 1) * 64;
  int col0 = blockIdx.y * 128;
  int r_ = tid >> 3, kq = (tid & 7) * 8;
  __syncthreads();  // s_idx ready
  const short* Ab = tok_bf + (size_t)b * NTOK * EMBED;
  f32x4 acc[4][4] = {};
  short8 pa[4], pw[4];
#pragma unroll
  for (int t = 0; t < 4; ++t) {
    pa[t] = *(const short8*)(Ab + (size_t)s_idx[t * 32 + r_] * EMBED + kq);
    pw[t] = *(const short8*)(W + (size_t)(col0 + t * 32 + r_) * EMBED + kq);
  }
  for (int k0 = 0; k0 < EMBED; k0 += 64) {
    __syncthreads();
#pragma unroll
    for (int t = 0; t < 4; ++t) {
      *(short8*)&sA[t * 32 + r_][kq] = pa[t];
      *(short8*)&sW[t * 32 + r_][kq] = pw[t];
    }
    __syncthreads();
    if (k0 + 64 < EMBED) {
#pragma unroll
      for (int t = 0; t < 4; ++t) {
        pa[t] = *(const short8*)(Ab + (size_t)s_idx[t * 32 + r_] * EMBED +
                                 k0 + 64 + kq);
        pw[t] = *(const short8*)(W + (size_t)(col0 + t * 32 + r_) * EMBED +
                                 k0 + 64 + kq);
      }
    }
#pragma unroll
    for (int half = 0; half < 2; ++half) {
      short8 af[4], bfr[4];
#pragma unroll
      for (int i = 0; i < 4; ++i)
        af[i] = *(short8*)&sA[wr + i * 16 + lb][half * 32 + lg * 8];
#pragma unroll
      for (int j = 0; j < 4; ++j)
        bfr[j] = *(short8*)&sW[wc + j * 16 + lb][half * 32 + lg * 8];
#pragma unroll
      for (int i = 0; i < 4; ++i)
#pragma unroll
        for (int j = 0; j < 4; ++j)
          acc[i][j] = __builtin_amdgcn_mfma_f32_16x16x32_bf16(af[i], bfr[j],
                                                              acc[i][j], 0, 0, 0);
    }
  }
#pragma unroll
  for (int i = 0; i < 4; ++i) {
#pragma unroll
    for (int j = 0; j < 4; ++j) {
#pragma unroll
      for (int r = 0; r < 4; ++r) {
        int jrow = bt * 128 + wr + i * 16 + lg * 4 + r;  // compacted position
        int gcol = col0 + wc + j * 16 + lb;
        float val = acc[i][j][r] + bias[gcol];
        int which = gcol / EMBED;
        int rem = gcol - which * EMBED;
        int h = rem >> 6, d = rem & 63;
        size_t dst = ((size_t)(b * NHEAD + h) * NTOK + jrow) * HDIM + d;
        if (which == 0)
          qq[dst] = f2bf(val * 0.125f);
        else if (which == 1)
          kk_[dst] = f2bf(val);
        else
          vv[dst] = f2bf(val);
      }
    }
  }
}

// ---------------------------------------------------------------------------
// V transpose: Vc[bh][j][d] -> VTc[bh][d][j]
// ---------------------------------------------------------------------------
__global__ __launch_bounds__(256) void vtrans_kernel(
    const short* __restrict__ Vb, short* __restrict__ VT) {
  int bh = blockIdx.y;
  int n0 = blockIdx.x * 64;
  __shared__ short st[64][72];
  int tid = threadIdx.x;
#pragma unroll
  for (int t = 0; t < 2; ++t) {
    int c = tid + t * 256;
    int n = c >> 3, ds = c & 7;
    *(short8*)&st[n][ds * 8] =
        *(const short8*)(Vb + ((size_t)bh * NTOK + n0 + n) * HDIM + ds * 8);
  }
  __syncthreads();
#pragma unroll
  for (int t = 0; t < 2; ++t) {
    int c = tid + t * 256;
    int d = c >> 3, ns = c & 7;
    short8 tmp;
#pragma unroll
    for (int jj = 0; jj < 8; ++jj) tmp[jj] = st[ns * 8 + jj][d];
    *(short8*)(VT + ((size_t)bh * HDIM + d) * NTOK + n0 + ns * 8) = tmp;
  }
}

// ---------------------------------------------------------------------------
// MFMA flash attention v3 — compacted token space. Loop count nt =
// ceil(kc[b]/64) read from device. Pad slots carry bias -3e38 -> P = 0.
// ---------------------------------------------------------------------------
#define ATTN_SWZ(row, colbyte) (((row)*128) + ((colbyte) ^ (((row)&7) << 4)))

__global__ __launch_bounds__(256) void attn_mfma3_kernel(
    const short* __restrict__ Qc, const short* __restrict__ Kc,
    const short* __restrict__ VTc, const float* __restrict__ biasc,
    const int* __restrict__ kc, short* __restrict__ ao) {
  __shared__ __align__(16) short sK[64 * 64];
  __shared__ __align__(16) short sVT[64 * 64];
  int bid = blockIdx.x;
  int xcd = bid & 7, slot = bid >> 3;
  int bh = xcd * 12 + (slot >> 3);
  int qt = slot & 7;
  int b = bh / NHEAD;
  int kcb = kc[b];
  if (qt * 128 >= kcb) return;
  int nt = (kcb + 63) >> 6;
  int tid = threadIdx.x;
  int w = tid >> 6, l = tid & 63, lg = l >> 4, lb = l & 15;
  int n0 = qt * 128 + w * 32;
  const short* Qp = Qc + ((size_t)bh * NTOK + n0) * HDIM;
  const short* Kp = Kc + (size_t)bh * NTOK * HDIM;
  const short* Vp = VTc + (size_t)bh * HDIM * NTOK;
  const float* bp = biasc + b * NTOK;

  short8 qf[2][2];
#pragma unroll
  for (int i = 0; i < 2; ++i)
#pragma unroll
    for (int hh = 0; hh < 2; ++hh)
      qf[i][hh] = *(const short8*)(Qp + (i * 16 + lb) * HDIM + hh * 32 + lg * 8);

  f32x4 acc[2][4] = {};
  float lr[2] = {0.f, 0.f};

  int srow = tid >> 3;
  int scol = (tid & 7) * 8;
  int scolb = scol * 2;
  short8 rk0, rk1, rv0, rv1;

#define ATTN_LOADT(m0_)                                                        \
  {                                                                            \
    rk0 = *(const short8*)(Kp + (size_t)((m0_) + srow) * HDIM + scol);         \
    rk1 = *(const short8*)(Kp + (size_t)((m0_) + srow + 32) * HDIM + scol);    \
    rv0 = *(const short8*)(Vp + (size_t)srow * NTOK + (m0_) + scol);           \
    rv1 = *(const short8*)(Vp + (size_t)(srow + 32) * NTOK + (m0_) + scol);    \
  }

  ATTN_LOADT(0);
  for (int t = 0; t < nt; ++t) {
    int m0 = t * 64;
    *(short8*)((char*)sK + ATTN_SWZ(srow, scolb)) = rk0;
    *(short8*)((char*)sK + ATTN_SWZ(srow + 32, scolb)) = rk1;
    *(short8*)((char*)sVT + ATTN_SWZ(srow, scolb)) = rv0;
    *(short8*)((char*)sVT + ATTN_SWZ(srow + 32, scolb)) = rv1;
    __syncthreads();
    if (t + 1 < nt) ATTN_LOADT(m0 + 64);

    f32x4 bias4[4];
#pragma unroll
    for (int s = 0; s < 4; ++s)
      bias4[s] = *(const f32x4*)(bp + m0 + s * 16 + lg * 4);

    f32x4 S[2][4];
#pragma unroll
    for (int s = 0; s < 4; ++s) {
      short8 kf0 = *(const short8*)((const char*)sK +
                                    ATTN_SWZ(s * 16 + lb, lg * 16));
      short8 kf1 = *(const short8*)((const char*)sK +
                                    ATTN_SWZ(s * 16 + lb, 64 + lg * 16));
#pragma unroll
      for (int i = 0; i < 2; ++i) {
        f32x4 c = bias4[s];
        c = __builtin_amdgcn_mfma_f32_16x16x32_bf16(kf0, qf[i][0], c, 0, 0, 0);
        c = __builtin_amdgcn_mfma_f32_16x16x32_bf16(kf1, qf[i][1], c, 0, 0, 0);
        S[i][s] = c;
      }
    }

    unsigned pk[2][4][2];
#pragma unroll
    for (int i = 0; i < 2; ++i) {
      float rs = 0.f;
#pragma unroll
      for (int s = 0; s < 4; ++s) {
        float p0 = __expf(S[i][s][0]);
        float p1 = __expf(S[i][s][1]);
        float p2 = __expf(S[i][s][2]);
        float p3 = __expf(S[i][s][3]);
        rs += (p0 + p1) + (p2 + p3);
        pk[i][s][0] = pack_bf2(p0, p1);
        pk[i][s][1] = pack_bf2(p2, p3);
      }
      rs += __shfl_xor(rs, 16);
      rs += __shfl_xor(rs, 32);
      lr[i] += rs;
    }

    bool hi = (lg & 2) != 0;
    int srcl = ((lg & 1) * 2) * 16 + lb;
#pragma unroll
    for (int t2 = 0; t2 < 2; ++t2) {
      short8 vf[4];
#pragma unroll
      for (int u = 0; u < 4; ++u)
        vf[u] = *(const short8*)((const char*)sVT +
                                 ATTN_SWZ(u * 16 + lb, t2 * 64 + lg * 16));
#pragma unroll
      for (int i = 0; i < 2; ++i) {
        int a0 = __shfl((int)pk[i][2 * t2][0], srcl);
        int b0 = __shfl((int)pk[i][2 * t2 + 1][0], srcl);
        int a1 = __shfl((int)pk[i][2 * t2][1], srcl);
        int b1 = __shfl((int)pk[i][2 * t2 + 1][1], srcl);
        int a2 = __shfl((int)pk[i][2 * t2][0], srcl + 16);
        int b2 = __shfl((int)pk[i][2 * t2 + 1][0], srcl + 16);
        int a3 = __shfl((int)pk[i][2 * t2][1], srcl + 16);
        int b3 = __shfl((int)pk[i][2 * t2 + 1][1], srcl + 16);
        union { short8 s8; int u[4]; } pa;
        pa.u[0] = hi ? b0 : a0;
        pa.u[1] = hi ? b1 : a1;
        pa.u[2] = hi ? b2 : a2;
        pa.u[3] = hi ? b3 : a3;
#pragma unroll
        for (int u = 0; u < 4; ++u)
          acc[i][u] = __builtin_amdgcn_mfma_f32_16x16x32_bf16(pa.s8, vf[u],
                                                              acc[i][u], 0, 0, 0);
      }
    }
    __syncthreads();
  }

  int h = bh - b * NHEAD;
#pragma unroll
  for (int i = 0; i < 2; ++i) {
#pragma unroll
    for (int r = 0; r < 4; ++r) {
      float inv = 1.0f / __shfl(lr[i], lg * 4 + r);
      int j = n0 + i * 16 + lg * 4 + r;  // compacted row
#pragma unroll
      for (int u = 0; u < 4; ++u) {
        ao[((size_t)b * NTOK + j) * EMBED + h * HDIM + u * 16 + lb] =
            f2bf(acc[i][u][r] * inv);
      }
    }
  }
}

// ---------------------------------------------------------------------------
// Proj gather-GEMM: A = aoc (compacted rows, dense), W = proj weights.
// ---------------------------------------------------------------------------
__global__ __launch_bounds__(256) void proj_gather_kernel(
    const short* __restrict__ A, const short* __restrict__ W,
    const float* __restrict__ bias, const int* __restrict__ kidx,
    const int* __restrict__ kc, float* __restrict__ out) {
  __shared__ short sA[128][72];
  __shared__ short sW[128][72];
  __shared__ int s_idx[128];
  int bx = blockIdx.x;
  int b = bx & 7, bt = bx >> 3;
  int kcb = kc[b];
  if (bt * 128 >= kcb) return;
  int tid = threadIdx.x;
  if (tid < 128) s_idx[tid] = kidx[b * NTOK + bt * 128 + tid];
  int w = tid >> 6, l = tid & 63, lg = l >> 4, lb = l & 15;
  int wr = (w >> 1) * 64, wc = (w & 1) * 64;
  int col0 = blockIdx.y * 128;
  int r_ = tid >> 3, kq = (tid & 7) * 8;
  const short* Ab = A + ((size_t)b * NTOK + bt * 128) * EMBED;
  f32x4 acc[4][4] = {};
  short8 pa[4], pw[4];
#pragma unroll
  for (int t = 0; t < 4; ++t) {
    pa[t] = *(const short8*)(Ab + (size_t)(t * 32 + r_) * EMBED + kq);
    pw[t] = *(const short8*)(W + (size_t)(col0 + t * 32 + r_) * EMBED + kq);
  }
  for (int k0 = 0; k0 < EMBED; k0 += 64) {
    __syncthreads();
#pragma unroll
    for (int t = 0; t < 4; ++t) {
      *(short8*)&sA[t * 32 + r_][kq] = pa[t];
      *(short8*)&sW[t * 32 + r_][kq] = pw[t];
    }
    __syncthreads();
    if (k0 + 64 < EMBED) {
#pragma unroll
      for (int t = 0; t < 4; ++t) {
        pa[t] = *(const short8*)(Ab + (size_t)(t * 32 + r_) * EMBED + k0 + 64 + kq);
        pw[t] = *(const short8*)(W + (size_t)(col0 + t * 32 + r_) * EMBED + k0 + 64 + kq);
      }
    }
#pragma unroll
    for (int half = 0; half < 2; ++half) {
      short8 af[4], bfr[4];
#pragma unroll
      for (int i = 0; i < 4; ++i)
        af[i] = *(short8*)&sA[wr + i * 16 + lb][half * 32 + lg * 8];
#pragma unroll
      for (int j = 0; j < 4; ++j)
        bfr[j] = *(short8*)&sW[wc + j * 16 + lb][half * 32 + lg * 8];
#pragma unroll
      for (int i = 0; i < 4; ++i)
#pragma unroll
        for (int j = 0; j < 4; ++j)
          acc[i][j] = __builtin_amdgcn_mfma_f32_16x16x32_bf16(af[i], bfr[j],
                                                              acc[i][j], 0, 0, 0);
    }
  }
#pragma unroll
  for (int i = 0; i < 4; ++i) {
#pragma unroll
    for (int j = 0; j < 4; ++j) {
#pragma unroll
      for (int r = 0; r < 4; ++r) {
        int jloc = wr + i * 16 + lg * 4 + r;
        int jrow = bt * 128 + jloc;
        int gcol = col0 + wc + j * 16 + lb;
        if (jrow < kcb) {
          int n = s_idx[jloc];
          out[((size_t)b * NTOK + n) * EMBED + gcol] = acc[i][j][r] + bias[gcol];
        }
      }
    }
  }
}

// ---------------------------------------------------------------------------
extern "C" void kernel_launch(void* const* d_in, const int* in_sizes, int n_in,
                              void* d_out, int out_size, void* d_ws, size_t ws_size,
                              hipStream_t stream) {
  const float* tokens   = (const float*)d_in[0];
  const int*   lidx     = (const int*)d_in[1];
  const float* layer_emb= (const float*)d_in[2];
  const float* ln_g     = (const float*)d_in[3];
  const float* ln_b     = (const float*)d_in[4];
  const float* w1       = (const float*)d_in[5];
  const float* b1       = (const float*)d_in[6];
  const float* w2       = (const float*)d_in[7];
  const float* b2       = (const float*)d_in[8];
  const float* w3       = (const float*)d_in[9];
  const float* b3       = (const float*)d_in[10];
  const float* qkv_w    = (const float*)d_in[11];
  const float* qkv_b    = (const float*)d_in[12];
  const float* proj_w   = (const float*)d_in[13];
  const float* proj_b   = (const float*)d_in[14];
  float* out = (float*)d_out;
  float* ws = (float*)d_ws;

  float* addvec = ws;
  float* lgt    = ws + 6144;           // raw logits [8192]
  int*   kidx   = (int*)(ws + 14336);
  float* biasc  = ws + 22528;
  int*   kc     = (int*)(ws + 30720);
  short* tok_bf = (short*)(ws + 30736);
  short* wq_bf  = (short*)(ws + 3176464);
  short* wp_bf  = (short*)(ws + 4061200);
  short* w1h = (short*)(ws + 4356112);
  short* w1m = (short*)(ws + 4503568);
  short* w2h = (short*)(ws + 4798480);
  short* w2m = (short*)(ws + 4872208);
  const size_t X0 = 5019664;
  short* xh  = (short*)(ws + X0);
  short* xm  = (short*)(ws + X0 + 3145728);
  short* h1h = (short*)(ws + X0 + 9437184);
  short* h1m = (short*)(ws + X0 + 11010048);
  short* Qc   = (short*)(ws + X0);
  short* Kc   = (short*)(ws + X0 + 3145728);
  short* Vc   = (short*)(ws + X0 + 6291456);
  short* VTc  = (short*)(ws + X0 + 9437184);
  short* aoc  = (short*)(ws + X0 + 12582912);

  // masked output rows are exactly 0 in the reference -> pre-zero d_out;
  // lgt accumulated via atomicAdd -> pre-zero.
  hipMemsetAsync(d_out, 0, (size_t)out_size * sizeof(float), stream);
  hipMemsetAsync(lgt, 0, BATCH * NTOK * sizeof(float), stream);

  // all weight conversions + addvec init in one dispatch
  prep_kernel<<<dim3(2760), dim3(256), 0, stream>>>(
      qkv_w, wq_bf, proj_w, wp_bf, w1, w1h, w1m, w2, w2h, w2m,
      layer_emb, lidx, addvec);

  // mask path (~2^-22-exact via 2-plane fp16 split MFMA; logits fused
  // into gemm<1> epilogue; sigmoid folded into mask threshold)
  colmean_kernel<<<dim3(BATCH, 16), dim3(768), 0, stream>>>(tokens, addvec);
  ln_split_kernel<<<dim3(BATCH * NTOK), dim3(256), 0, stream>>>(
      tokens, addvec, ln_g, ln_b, xh, xm, tok_bf);
  gemm_split_kernel<0><<<dim3(128, 6), dim3(256), 0, stream>>>(
      xh, xm, w1h, w1m, b1, h1h, h1m, nullptr, nullptr,
      BATCH * NTOK, HID, EMBED);
  gemm_split_kernel<1><<<dim3(128, 6), dim3(256), 0, stream>>>(
      h1h, h1m, w2h, w2m, b2, nullptr, nullptr, w3, lgt,
      BATCH * NTOK, HID, HID);
  mask_kernel<<<dim3(BATCH), dim3(1024), 0, stream>>>(lgt, b3, kidx, kc, biasc);

  // attention path, compacted token space (~kc of 1024 tokens per batch)
  qkv_gather_kernel<<<dim3(64, 18), dim3(256), 0, stream>>>(
      tok_bf, wq_bf, qkv_b, kidx, kc, Qc, Kc, Vc);
  vtrans_kernel<<<dim3(16, BATCH * NHEAD), dim3(256), 0, stream>>>(Vc, VTc);
  attn_mfma3_kernel<<<dim3(768), dim3(256), 0, stream>>>(
      Qc, Kc, VTc, biasc, kc, aoc);
  proj_gather_kernel<<<dim3(64, 6), dim3(256), 0, stream>>>(
      aoc, wp_bf, proj_b, kidx, kc, out);
}

// Round 10
// 155.866 us; speedup vs baseline: 1.5801x; 1.0678x over previous
//
#include <hip/hip_runtime.h>
#include <cstdint>
#include <cmath>

#define EMBED 768
#define HID 384
#define NHEAD 12
#define HDIM 64
#define BATCH 8
#define NTOK 1024
#define MINKEEP 102

using f32x4  = __attribute__((ext_vector_type(4))) float;
using short8 = __attribute__((ext_vector_type(8))) short;
using short4v = __attribute__((ext_vector_type(4))) short;
using half8  = __attribute__((ext_vector_type(8))) _Float16;

__device__ inline short f2bf(float f) {
  unsigned u = __float_as_uint(f);
  u += 0x7fffu + ((u >> 16) & 1u);
  return (short)(u >> 16);
}
__device__ inline float bf2f(short s) {
  return __uint_as_float(((unsigned)(unsigned short)s) << 16);
}
__device__ inline unsigned pack_bf2(float lo, float hi) {
  unsigned ul = __float_as_uint(lo);
  ul += 0x7fffu + ((ul >> 16) & 1u);
  unsigned uh = __float_as_uint(hi);
  uh += 0x7fffu + ((uh >> 16) & 1u);
  return (ul >> 16) | (uh & 0xffff0000u);
}
// fp16 2-way split: v = h + m + O(2^-22 v).
__device__ inline void split2h(float v, short& h, short& m) {
  _Float16 h0 = (_Float16)v;
  float r = v - (float)h0;
  _Float16 m0 = (_Float16)r;
  h = __builtin_bit_cast(short, h0);
  m = __builtin_bit_cast(short, m0);
}

// ---------------------------------------------------------------------------
// prep: weight conversions + lgt zero + colmean partials, ONE dispatch.
//  [0,1728)      qkv_w  -> bf16
//  [1728,2304)   proj_w -> bf16
//  [2304,2592)   w1     -> fp16 h/m
//  [2592,2736)   w2     -> fp16 h/m
//  [2736,2744)   lgt = 0                 (8 blk x 256 x float4)
//  [2744,2872)   colsum[b][c] += sum_{n in chunk} tokens[b,n,c]
//                (colsum pre-zeroed by memset; addvec eliminated —
//                 ln_split computes 2*emb + colsum/NTOK inline)
// ---------------------------------------------------------------------------
__global__ __launch_bounds__(256) void prep_kernel(
    const float* __restrict__ qkv_w, short* __restrict__ wq_bf,
    const float* __restrict__ proj_w, short* __restrict__ wp_bf,
    const float* __restrict__ w1, short* __restrict__ w1h, short* __restrict__ w1m,
    const float* __restrict__ w2, short* __restrict__ w2h, short* __restrict__ w2m,
    const float* __restrict__ tokens, float* __restrict__ colsum,
    float* __restrict__ lgt) {
  int blk = blockIdx.x, tid = threadIdx.x;
  if (blk < 2304) {
    const float* in = (blk < 1728) ? qkv_w : proj_w;
    short* out = (blk < 1728) ? wq_bf : wp_bf;
    int i = (blk < 1728 ? blk : blk - 1728) * 256 + tid;
    float4 f = ((const float4*)in)[i];
    short4v s;
    s[0] = f2bf(f.x); s[1] = f2bf(f.y); s[2] = f2bf(f.z); s[3] = f2bf(f.w);
    ((short4v*)out)[i] = s;
  } else if (blk < 2736) {
    const float* in = (blk < 2592) ? w1 : w2;
    short* oh = (blk < 2592) ? w1h : w2h;
    short* om = (blk < 2592) ? w1m : w2m;
    int i = (blk < 2592 ? blk - 2304 : blk - 2592) * 256 + tid;
    float4 f = ((const float4*)in)[i];
    short4v h, m;
    short th, tm;
    split2h(f.x, th, tm); h[0] = th; m[0] = tm;
    split2h(f.y, th, tm); h[1] = th; m[1] = tm;
    split2h(f.z, th, tm); h[2] = th; m[2] = tm;
    split2h(f.w, th, tm); h[3] = th; m[3] = tm;
    ((short4v*)oh)[i] = h;
    ((short4v*)om)[i] = m;
  } else if (blk < 2744) {
    int i = (blk - 2736) * 256 + tid;
    ((float4*)lgt)[i] = make_float4(0.f, 0.f, 0.f, 0.f);
  } else {
    int idx = blk - 2744;  // 0..127
    int b = idx >> 4, chunk = idx & 15;
    const float* tb = tokens + ((size_t)b * NTOK + chunk * 64) * EMBED;
    float s0 = 0.f, s1 = 0.f, s2 = 0.f;
#pragma unroll 8
    for (int n = 0; n < 64; ++n) {
      const float* r = tb + (size_t)n * EMBED;
      s0 += r[tid]; s1 += r[tid + 256]; s2 += r[tid + 512];
    }
    atomicAdd(&colsum[b * EMBED + tid], s0);
    atomicAdd(&colsum[b * EMBED + tid + 256], s1);
    atomicAdd(&colsum[b * EMBED + tid + 512], s2);
  }
}

// ---------------------------------------------------------------------------
// K2: layernorm per row (768) -> 2 fp16 planes (xh, xm) + tok_bf.
// addvec inline: av = 2*emb[lidx][c] + colsum[b][c]/NTOK.
// ---------------------------------------------------------------------------
__global__ __launch_bounds__(256) void ln_split_kernel(
    const float* __restrict__ tokens, const float* __restrict__ colsum,
    const float* __restrict__ layer_emb, const int* __restrict__ lidx,
    const float* __restrict__ gamma, const float* __restrict__ beta,
    short* __restrict__ xh, short* __restrict__ xm,
    short* __restrict__ tok_bf) {
  int row = blockIdx.x;
  int b = row >> 10;
  __shared__ float s_row[EMBED];
  __shared__ float s_red[4];
  const float* tr = tokens + (size_t)row * EMBED;
  const float* cs = colsum + b * EMBED;
  const float* eb = layer_emb + lidx[0] * EMBED;
  float lsum = 0.f;
  for (int c = threadIdx.x; c < EMBED; c += 256) {
    float t = tr[c];
    tok_bf[(size_t)row * EMBED + c] = f2bf(t);
    float v = t + 2.0f * eb[c] + cs[c] * (1.0f / NTOK);
    s_row[c] = v;
    lsum += v;
  }
  for (int o = 32; o; o >>= 1) lsum += __shfl_down(lsum, o, 64);
  int wid = threadIdx.x >> 6;
  if ((threadIdx.x & 63) == 0) s_red[wid] = lsum;
  __syncthreads();
  float mu = (s_red[0] + s_red[1] + s_red[2] + s_red[3]) * (1.f / EMBED);
  float lss = 0.f;
  for (int c = threadIdx.x; c < EMBED; c += 256) {
    float d = s_row[c] - mu;
    lss += d * d;
  }
  for (int o = 32; o; o >>= 1) lss += __shfl_down(lss, o, 64);
  __syncthreads();
  if ((threadIdx.x & 63) == 0) s_red[wid] = lss;
  __syncthreads();
  float var = (s_red[0] + s_red[1] + s_red[2] + s_red[3]) * (1.f / EMBED);
  float rinv = 1.0f / sqrtf(var + 1e-5f);
  for (int c = threadIdx.x; c < EMBED; c += 256) {
    float v = (s_row[c] - mu) * rinv * gamma[c] + beta[c];
    short h, m;
    split2h(v, h, m);
    size_t idx = (size_t)row * EMBED + c;
    xh[idx] = h; xm[idx] = m;
  }
}

// ---------------------------------------------------------------------------
// Split-fp16 MFMA GEMM (~2^-22 exact): C = A@W^T + bias, gelu.
// OUT==0: write fp16 h/m planes. OUT==1: fused logits via atomicAdd.
// ---------------------------------------------------------------------------
__device__ inline float gelu_exact(float x) {
  return 0.5f * x * (1.0f + erff(x * 0.70710678118654752f));
}

template <int OUT>
__global__ __launch_bounds__(256) void gemm_split_kernel(
    const short* __restrict__ Ah, const short* __restrict__ Am,
    const short* __restrict__ Wh, const short* __restrict__ Wm,
    const float* __restrict__ bias, short* __restrict__ Ch,
    short* __restrict__ Cm, const float* __restrict__ w3,
    float* __restrict__ lgt, int M, int N, int K) {
  __shared__ short sA[2][64][40];
  __shared__ short sW[2][64][40];
  int tid = threadIdx.x;
  int w = tid >> 6, l = tid & 63, lg = l >> 4, lb = l & 15;
  int wr = (w >> 1) * 32, wc = (w & 1) * 32;
  int row0 = blockIdx.x * 64, col0 = blockIdx.y * 64;
  int srow = tid >> 2;
  int skk = (tid & 3) * 8;
  f32x4 acc0[2][2] = {}, acc1[2][2] = {};
  short8 ra0, ra1, rw0, rw1;
  {
    size_t aoff = (size_t)(row0 + srow) * K + skk;
    size_t woff = (size_t)(col0 + srow) * K + skk;
    ra0 = *(const short8*)(Ah + aoff);
    ra1 = *(const short8*)(Am + aoff);
    rw0 = *(const short8*)(Wh + woff);
    rw1 = *(const short8*)(Wm + woff);
  }
  for (int k0 = 0; k0 < K; k0 += 32) {
    __syncthreads();
    *(short8*)&sA[0][srow][skk] = ra0;
    *(short8*)&sA[1][srow][skk] = ra1;
    *(short8*)&sW[0][srow][skk] = rw0;
    *(short8*)&sW[1][srow][skk] = rw1;
    __syncthreads();
    if (k0 + 32 < K) {
      size_t aoff = (size_t)(row0 + srow) * K + k0 + 32 + skk;
      size_t woff = (size_t)(col0 + srow) * K + k0 + 32 + skk;
      ra0 = *(const short8*)(Ah + aoff);
      ra1 = *(const short8*)(Am + aoff);
      rw0 = *(const short8*)(Wh + woff);
      rw1 = *(const short8*)(Wm + woff);
    }
    half8 ah[2], am[2], bh[2], bm[2];
#pragma unroll
    for (int i = 0; i < 2; ++i) {
      ah[i] = *(half8*)&sA[0][wr + i * 16 + lb][lg * 8];
      am[i] = *(half8*)&sA[1][wr + i * 16 + lb][lg * 8];
      bh[i] = *(half8*)&sW[0][wc + i * 16 + lb][lg * 8];
      bm[i] = *(half8*)&sW[1][wc + i * 16 + lb][lg * 8];
    }
#pragma unroll
    for (int i = 0; i < 2; ++i)
#pragma unroll
      for (int j = 0; j < 2; ++j) {
        f32x4 c0 = acc0[i][j];
        f32x4 c1 = acc1[i][j];
        c0 = __builtin_amdgcn_mfma_f32_16x16x32_f16(ah[i], bh[j], c0, 0, 0, 0);
        c1 = __builtin_amdgcn_mfma_f32_16x16x32_f16(ah[i], bm[j], c1, 0, 0, 0);
        c0 = __builtin_amdgcn_mfma_f32_16x16x32_f16(am[i], bh[j], c0, 0, 0, 0);
        acc0[i][j] = c0;
        acc1[i][j] = c1;
      }
  }
  if (OUT == 0) {
#pragma unroll
    for (int i = 0; i < 2; ++i) {
#pragma unroll
      for (int j = 0; j < 2; ++j) {
#pragma unroll
        for (int r = 0; r < 4; ++r) {
          int grow = row0 + wr + i * 16 + lg * 4 + r;
          int gcol = col0 + wc + j * 16 + lb;
          float g = gelu_exact(acc0[i][j][r] + acc1[i][j][r] + bias[gcol]);
          size_t idx = (size_t)grow * N + gcol;
          short h, m;
          split2h(g, h, m);
          Ch[idx] = h; Cm[idx] = m;
        }
      }
    }
  } else {
    float part[2][4];
#pragma unroll
    for (int i = 0; i < 2; ++i)
#pragma unroll
      for (int r = 0; r < 4; ++r) part[i][r] = 0.f;
#pragma unroll
    for (int i = 0; i < 2; ++i) {
#pragma unroll
      for (int j = 0; j < 2; ++j) {
#pragma unroll
        for (int r = 0; r < 4; ++r) {
          int gcol = col0 + wc + j * 16 + lb;
          float g = gelu_exact(acc0[i][j][r] + acc1[i][j][r] + bias[gcol]);
          part[i][r] += g * w3[gcol];
        }
      }
    }
#pragma unroll
    for (int i = 0; i < 2; ++i) {
#pragma unroll
      for (int r = 0; r < 4; ++r) {
        float v = part[i][r];
        v += __shfl_xor(v, 1);
        v += __shfl_xor(v, 2);
        v += __shfl_xor(v, 4);
        v += __shfl_xor(v, 8);
        if (lb == 0) atomicAdd(&lgt[row0 + wr + i * 16 + lg * 4 + r], v);
      }
    }
  }
}

// ---------------------------------------------------------------------------
// mask v4: raw logits; sigmoid folded into the threshold (monotone).
// ---------------------------------------------------------------------------
__global__ __launch_bounds__(1024) void mask_kernel(
    const float* __restrict__ lgt, const float* __restrict__ b3,
    int* __restrict__ kidx, int* __restrict__ kc, float* __restrict__ biasc) {
  int b = blockIdx.x, tid = threadIdx.x;
  __shared__ unsigned long long keys[1024];
  __shared__ int flag[1024];
  __shared__ int wsum[16];
  float v = lgt[b * NTOK + tid] + b3[0];
  bool bin = (v >= 0.0f);
  int wid = tid >> 6, lane = tid & 63;
  unsigned long long bal = __ballot(bin);
  if (lane == 0) wsum[wid] = __popcll(bal);
  __syncthreads();
  int total = 0;
  for (int q = 0; q < 16; ++q) total += wsum[q];
  int mv;
  if (total >= MINKEEP) {
    mv = bin ? 1 : 0;
  } else {
    flag[tid] = 0;
    unsigned u = __float_as_uint(v);
    u = (u & 0x80000000u) ? ~u : (u | 0x80000000u);  // order-preserving map
    keys[tid] = ((unsigned long long)u << 32) | (unsigned)(1023 - tid);
    __syncthreads();
    for (int k2 = 2; k2 <= 1024; k2 <<= 1) {
      for (int j = k2 >> 1; j > 0; j >>= 1) {
        int ixj = tid ^ j;
        if (ixj > tid) {
          unsigned long long a = keys[tid], c = keys[ixj];
          bool desc = ((tid & k2) == 0);
          if (desc ? (a < c) : (a > c)) {
            keys[tid] = c;
            keys[ixj] = a;
          }
        }
        __syncthreads();
      }
    }
    if (tid < MINKEEP) {
      int idx = 1023 - (int)(keys[tid] & 0xFFFFFFFFu);
      flag[idx] = 1;
    }
    __syncthreads();
    mv = flag[tid];
  }
  if (tid == 0) mv = 1;
  __syncthreads();  // wsum reuse
  unsigned long long fb = __ballot(mv != 0);
  if (lane == 0) wsum[wid] = __popcll(fb);
  __syncthreads();
  int base = 0, tot = 0;
  for (int q = 0; q < 16; ++q) {
    int vq = wsum[q];
    if (q < wid) base += vq;
    tot += vq;
  }
  int pre = base + __popcll(fb & ((1ull << lane) - 1ull));
  if (mv) {
    kidx[b * NTOK + pre] = tid;
    biasc[b * NTOK + pre] = 0.f;
  }
  if (tid >= tot) {
    kidx[b * NTOK + tid] = 0;
    biasc[b * NTOK + tid] = -3.0e38f;
  }
  if (tid == 0) kc[b] = tot;
}

// ---------------------------------------------------------------------------
// QKV gather-GEMM (compacted rows). 128x128 tile, BK=64, reg prefetch.
// b = bx&7 -> all 8 XCDs active. V blocks (blockIdx.y >= 12) write VTc
// DIRECTLY via an LDS transpose of the output tile (stride-136 rows:
// 16B-aligned, 2-way-bank = free) — the Vc buffer and the vtrans kernel
// are deleted. Rows beyond the active bt tiles are never read by attn
// (nt*64 <= ceil(kc/128)*128).
// ---------------------------------------------------------------------------
__global__ __launch_bounds__(256) void qkv_gather_kernel(
    const short* __restrict__ tok_bf, const short* __restrict__ W,
    const float* __restrict__ bias, const int* __restrict__ kidx,
    const int* __restrict__ kc, short* __restrict__ qq,
    short* __restrict__ kk_, short* __restrict__ VTc) {
  __shared__ short smem[2 * 128 * 72];
  short (*sA)[72] = (short(*)[72])smem;
  short (*sW)[72] = (short(*)[72])(smem + 128 * 72);
  __shared__ int s_idx[128];
  int bx = blockIdx.x;
  int b = bx & 7, bt = bx >> 3;
  int kcb = kc[b];
  if (bt * 128 >= kcb) return;
  int tid = threadIdx.x;
  if (tid < 128) s_idx[tid] = kidx[b * NTOK + bt * 128 + tid];
  int w = tid >> 6, l = tid & 63, lg = l >> 4, lb = l & 15;
  int wr = (w >> 1) * 64, wc = (w & 1) * 64;
  int col0 = blockIdx.y * 128;
  int r_ = tid >> 3, kq = (tid & 7) * 8;
  __syncthreads();  // s_idx ready
  const short* Ab = tok_bf + (size_t)b * NTOK * EMBED;
  f32x4 acc[4][4] = {};
  short8 pa[4], pw[4];
#pragma unroll
  for (int t = 0; t < 4; ++t) {
    pa[t] = *(const short8*)(Ab + (size_t)s_idx[t * 32 + r_] * EMBED + kq);
    pw[t] = *(const short8*)(W + (size_t)(col0 + t * 32 + r_) * EMBED + kq);
  }
  for (int k0 = 0; k0 < EMBED; k0 += 64) {
    __syncthreads();
#pragma unroll
    for (int t = 0; t < 4; ++t) {
      *(short8*)&sA[t * 32 + r_][kq] = pa[t];
      *(short8*)&sW[t * 32 + r_][kq] = pw[t];
    }
    __syncthreads();
    if (k0 + 64 < EMBED) {
#pragma unroll
      for (int t = 0; t < 4; ++t) {
        pa[t] = *(const short8*)(Ab + (size_t)s_idx[t * 32 + r_] * EMBED +
                                 k0 + 64 + kq);
        pw[t] = *(const short8*)(W + (size_t)(col0 + t * 32 + r_) * EMBED +
                                 k0 + 64 + kq);
      }
    }
#pragma unroll
    for (int half = 0; half < 2; ++half) {
      short8 af[4], bfr[4];
#pragma unroll
      for (int i = 0; i < 4; ++i)
        af[i] = *(short8*)&sA[wr + i * 16 + lb][half * 32 + lg * 8];
#pragma unroll
      for (int j = 0; j < 4; ++j)
        bfr[j] = *(short8*)&sW[wc + j * 16 + lb][half * 32 + lg * 8];
#pragma unroll
      for (int i = 0; i < 4; ++i)
#pragma unroll
        for (int j = 0; j < 4; ++j)
          acc[i][j] = __builtin_amdgcn_mfma_f32_16x16x32_bf16(af[i], bfr[j],
                                                              acc[i][j], 0, 0, 0);
    }
  }
  if (col0 >= 2 * EMBED) {
    // ---- V block: LDS-transpose epilogue, write VTc directly ----
    __syncthreads();  // all fragment reads done before smem reuse
    short (*sT)[136] = (short(*)[136])smem;  // 128x136x2B = 34816B <= 36864B
#pragma unroll
    for (int i = 0; i < 4; ++i) {
#pragma unroll
      for (int j = 0; j < 4; ++j) {
        int col_local = wc + j * 16 + lb;
        int jr0 = wr + i * 16 + lg * 4;
        short4v v4;
#pragma unroll
        for (int r = 0; r < 4; ++r)
          v4[r] = f2bf(acc[i][j][r] + bias[col0 + col_local]);
        *(short4v*)&sT[col_local][jr0] = v4;
      }
    }
    __syncthreads();
    int rem = col0 - 2 * EMBED;  // 0,128,...,640
#pragma unroll
    for (int t = 0; t < 8; ++t) {
      int c = tid + t * 256;     // chunk 0..2047
      int rowl = c >> 4;         // col_local 0..127
      int off = (c & 15) * 8;    // jrow offset
      int vcol = rem + rowl;
      int h = vcol >> 6, d = vcol & 63;
      size_t dst = ((size_t)(b * NHEAD + h) * HDIM + d) * NTOK + bt * 128 + off;
      *(short8*)(VTc + dst) = *(short8*)&sT[rowl][off];
    }
    return;
  }
#pragma unroll
  for (int i = 0; i < 4; ++i) {
#pragma unroll
    for (int j = 0; j < 4; ++j) {
#pragma unroll
      for (int r = 0; r < 4; ++r) {
        int jrow = bt * 128 + wr + i * 16 + lg * 4 + r;  // compacted position
        int gcol = col0 + wc + j * 16 + lb;
        float val = acc[i][j][r] + bias[gcol];
        int which = gcol / EMBED;  // 0 or 1 here
        int rem2 = gcol - which * EMBED;
        int h = rem2 >> 6, d = rem2 & 63;
        size_t dst = ((size_t)(b * NHEAD + h) * NTOK + jrow) * HDIM + d;
        if (which == 0)
          qq[dst] = f2bf(val * 0.125f);
        else
          kk_[dst] = f2bf(val);
      }
    }
  }
}

// ---------------------------------------------------------------------------
// MFMA flash attention v3 — compacted token space.
// ---------------------------------------------------------------------------
#define ATTN_SWZ(row, colbyte) (((row)*128) + ((colbyte) ^ (((row)&7) << 4)))

__global__ __launch_bounds__(256) void attn_mfma3_kernel(
    const short* __restrict__ Qc, const short* __restrict__ Kc,
    const short* __restrict__ VTc, const float* __restrict__ biasc,
    const int* __restrict__ kc, short* __restrict__ ao) {
  __shared__ __align__(16) short sK[64 * 64];
  __shared__ __align__(16) short sVT[64 * 64];
  int bid = blockIdx.x;
  int xcd = bid & 7, slot = bid >> 3;
  int bh = xcd * 12 + (slot >> 3);
  int qt = slot & 7;
  int b = bh / NHEAD;
  int kcb = kc[b];
  if (qt * 128 >= kcb) return;
  int nt = (kcb + 63) >> 6;
  int tid = threadIdx.x;
  int w = tid >> 6, l = tid & 63, lg = l >> 4, lb = l & 15;
  int n0 = qt * 128 + w * 32;
  const short* Qp = Qc + ((size_t)bh * NTOK + n0) * HDIM;
  const short* Kp = Kc + (size_t)bh * NTOK * HDIM;
  const short* Vp = VTc + (size_t)bh * HDIM * NTOK;
  const float* bp = biasc + b * NTOK;

  short8 qf[2][2];
#pragma unroll
  for (int i = 0; i < 2; ++i)
#pragma unroll
    for (int hh = 0; hh < 2; ++hh)
      qf[i][hh] = *(const short8*)(Qp + (i * 16 + lb) * HDIM + hh * 32 + lg * 8);

  f32x4 acc[2][4] = {};
  float lr[2] = {0.f, 0.f};

  int srow = tid >> 3;
  int scol = (tid & 7) * 8;
  int scolb = scol * 2;
  short8 rk0, rk1, rv0, rv1;

#define ATTN_LOADT(m0_)                                                        \
  {                                                                            \
    rk0 = *(const short8*)(Kp + (size_t)((m0_) + srow) * HDIM + scol);         \
    rk1 = *(const short8*)(Kp + (size_t)((m0_) + srow + 32) * HDIM + scol);    \
    rv0 = *(const short8*)(Vp + (size_t)srow * NTOK + (m0_) + scol);           \
    rv1 = *(const short8*)(Vp + (size_t)(srow + 32) * NTOK + (m0_) + scol);    \
  }

  ATTN_LOADT(0);
  for (int t = 0; t < nt; ++t) {
    int m0 = t * 64;
    *(short8*)((char*)sK + ATTN_SWZ(srow, scolb)) = rk0;
    *(short8*)((char*)sK + ATTN_SWZ(srow + 32, scolb)) = rk1;
    *(short8*)((char*)sVT + ATTN_SWZ(srow, scolb)) = rv0;
    *(short8*)((char*)sVT + ATTN_SWZ(srow + 32, scolb)) = rv1;
    __syncthreads();
    if (t + 1 < nt) ATTN_LOADT(m0 + 64);

    f32x4 bias4[4];
#pragma unroll
    for (int s = 0; s < 4; ++s)
      bias4[s] = *(const f32x4*)(bp + m0 + s * 16 + lg * 4);

    f32x4 S[2][4];
#pragma unroll
    for (int s = 0; s < 4; ++s) {
      short8 kf0 = *(const short8*)((const char*)sK +
                                    ATTN_SWZ(s * 16 + lb, lg * 16));
      short8 kf1 = *(const short8*)((const char*)sK +
                                    ATTN_SWZ(s * 16 + lb, 64 + lg * 16));
#pragma unroll
      for (int i = 0; i < 2; ++i) {
        f32x4 c = bias4[s];
        c = __builtin_amdgcn_mfma_f32_16x16x32_bf16(kf0, qf[i][0], c, 0, 0, 0);
        c = __builtin_amdgcn_mfma_f32_16x16x32_bf16(kf1, qf[i][1], c, 0, 0, 0);
        S[i][s] = c;
      }
    }

    unsigned pk[2][4][2];
#pragma unroll
    for (int i = 0; i < 2; ++i) {
      float rs = 0.f;
#pragma unroll
      for (int s = 0; s < 4; ++s) {
        float p0 = __expf(S[i][s][0]);
        float p1 = __expf(S[i][s][1]);
        float p2 = __expf(S[i][s][2]);
        float p3 = __expf(S[i][s][3]);
        rs += (p0 + p1) + (p2 + p3);
        pk[i][s][0] = pack_bf2(p0, p1);
        pk[i][s][1] = pack_bf2(p2, p3);
      }
      rs += __shfl_xor(rs, 16);
      rs += __shfl_xor(rs, 32);
      lr[i] += rs;
    }

    bool hi = (lg & 2) != 0;
    int srcl = ((lg & 1) * 2) * 16 + lb;
#pragma unroll
    for (int t2 = 0; t2 < 2; ++t2) {
      short8 vf[4];
#pragma unroll
      for (int u = 0; u < 4; ++u)
        vf[u] = *(const short8*)((const char*)sVT +
                                 ATTN_SWZ(u * 16 + lb, t2 * 64 + lg * 16));
#pragma unroll
      for (int i = 0; i < 2; ++i) {
        int a0 = __shfl((int)pk[i][2 * t2][0], srcl);
        int b0 = __shfl((int)pk[i][2 * t2 + 1][0], srcl);
        int a1 = __shfl((int)pk[i][2 * t2][1], srcl);
        int b1 = __shfl((int)pk[i][2 * t2 + 1][1], srcl);
        int a2 = __shfl((int)pk[i][2 * t2][0], srcl + 16);
        int b2 = __shfl((int)pk[i][2 * t2 + 1][0], srcl + 16);
        int a3 = __shfl((int)pk[i][2 * t2][1], srcl + 16);
        int b3 = __shfl((int)pk[i][2 * t2 + 1][1], srcl + 16);
        union { short8 s8; int u[4]; } pa;
        pa.u[0] = hi ? b0 : a0;
        pa.u[1] = hi ? b1 : a1;
        pa.u[2] = hi ? b2 : a2;
        pa.u[3] = hi ? b3 : a3;
#pragma unroll
        for (int u = 0; u < 4; ++u)
          acc[i][u] = __builtin_amdgcn_mfma_f32_16x16x32_bf16(pa.s8, vf[u],
                                                              acc[i][u], 0, 0, 0);
      }
    }
    __syncthreads();
  }

  int h = bh - b * NHEAD;
#pragma unroll
  for (int i = 0; i < 2; ++i) {
#pragma unroll
    for (int r = 0; r < 4; ++r) {
      float inv = 1.0f / __shfl(lr[i], lg * 4 + r);
      int j = n0 + i * 16 + lg * 4 + r;  // compacted row
#pragma unroll
      for (int u = 0; u < 4; ++u) {
        ao[((size_t)b * NTOK + j) * EMBED + h * HDIM + u * 16 + lb] =
            f2bf(acc[i][u][r] * inv);
      }
    }
  }
}

// ---------------------------------------------------------------------------
// Proj gather-GEMM: A = aoc (compacted rows, dense), W = proj weights.
// ---------------------------------------------------------------------------
__global__ __launch_bounds__(256) void proj_gather_kernel(
    const short* __restrict__ A, const short* __restrict__ W,
    const float* __restrict__ bias, const int* __restrict__ kidx,
    const int* __restrict__ kc, float* __restrict__ out) {
  __shared__ short sA[128][72];
  __shared__ short sW[128][72];
  __shared__ int s_idx[128];
  int bx = blockIdx.x;
  int b = bx & 7, bt = bx >> 3;
  int kcb = kc[b];
  if (bt * 128 >= kcb) return;
  int tid = threadIdx.x;
  if (tid < 128) s_idx[tid] = kidx[b * NTOK + bt * 128 + tid];
  int w = tid >> 6, l = tid & 63, lg = l >> 4, lb = l & 15;
  int wr = (w >> 1) * 64, wc = (w & 1) * 64;
  int col0 = blockIdx.y * 128;
  int r_ = tid >> 3, kq = (tid & 7) * 8;
  const short* Ab = A + ((size_t)b * NTOK + bt * 128) * EMBED;
  f32x4 acc[4][4] = {};
  short8 pa[4], pw[4];
#pragma unroll
  for (int t = 0; t < 4; ++t) {
    pa[t] = *(const short8*)(Ab + (size_t)(t * 32 + r_) * EMBED + kq);
    pw[t] = *(const short8*)(W + (size_t)(col0 + t * 32 + r_) * EMBED + kq);
  }
  for (int k0 = 0; k0 < EMBED; k0 += 64) {
    __syncthreads();
#pragma unroll
    for (int t = 0; t < 4; ++t) {
      *(short8*)&sA[t * 32 + r_][kq] = pa[t];
      *(short8*)&sW[t * 32 + r_][kq] = pw[t];
    }
    __syncthreads();
    if (k0 + 64 < EMBED) {
#pragma unroll
      for (int t = 0; t < 4; ++t) {
        pa[t] = *(const short8*)(Ab + (size_t)(t * 32 + r_) * EMBED + k0 + 64 + kq);
        pw[t] = *(const short8*)(W + (size_t)(col0 + t * 32 + r_) * EMBED + k0 + 64 + kq);
      }
    }
#pragma unroll
    for (int half = 0; half < 2; ++half) {
      short8 af[4], bfr[4];
#pragma unroll
      for (int i = 0; i < 4; ++i)
        af[i] = *(short8*)&sA[wr + i * 16 + lb][half * 32 + lg * 8];
#pragma unroll
      for (int j = 0; j < 4; ++j)
        bfr[j] = *(short8*)&sW[wc + j * 16 + lb][half * 32 + lg * 8];
#pragma unroll
      for (int i = 0; i < 4; ++i)
#pragma unroll
        for (int j = 0; j < 4; ++j)
          acc[i][j] = __builtin_amdgcn_mfma_f32_16x16x32_bf16(af[i], bfr[j],
                                                              acc[i][j], 0, 0, 0);
    }
  }
#pragma unroll
  for (int i = 0; i < 4; ++i) {
#pragma unroll
    for (int j = 0; j < 4; ++j) {
#pragma unroll
      for (int r = 0; r < 4; ++r) {
        int jloc = wr + i * 16 + lg * 4 + r;
        int jrow = bt * 128 + jloc;
        int gcol = col0 + wc + j * 16 + lb;
        if (jrow < kcb) {
          int n = s_idx[jloc];
          out[((size_t)b * NTOK + n) * EMBED + gcol] = acc[i][j][r] + bias[gcol];
        }
      }
    }
  }
}

// ---------------------------------------------------------------------------
extern "C" void kernel_launch(void* const* d_in, const int* in_sizes, int n_in,
                              void* d_out, int out_size, void* d_ws, size_t ws_size,
                              hipStream_t stream) {
  const float* tokens   = (const float*)d_in[0];
  const int*   lidx     = (const int*)d_in[1];
  const float* layer_emb= (const float*)d_in[2];
  const float* ln_g     = (const float*)d_in[3];
  const float* ln_b     = (const float*)d_in[4];
  const float* w1       = (const float*)d_in[5];
  const float* b1       = (const float*)d_in[6];
  const float* w2       = (const float*)d_in[7];
  const float* b2       = (const float*)d_in[8];
  const float* w3       = (const float*)d_in[9];
  const float* b3       = (const float*)d_in[10];
  const float* qkv_w    = (const float*)d_in[11];
  const float* qkv_b    = (const float*)d_in[12];
  const float* proj_w   = (const float*)d_in[13];
  const float* proj_b   = (const float*)d_in[14];
  float* out = (float*)d_out;
  float* ws = (float*)d_ws;

  float* colsum = ws;                  // [6144]
  float* lgt    = ws + 6144;           // raw logits [8192]
  int*   kidx   = (int*)(ws + 14336);
  float* biasc  = ws + 22528;
  int*   kc     = (int*)(ws + 30720);
  short* tok_bf = (short*)(ws + 30736);
  short* wq_bf  = (short*)(ws + 3176464);
  short* wp_bf  = (short*)(ws + 4061200);
  short* w1h = (short*)(ws + 4356112);
  short* w1m = (short*)(ws + 4503568);
  short* w2h = (short*)(ws + 4798480);
  short* w2m = (short*)(ws + 4872208);
  const size_t X0 = 5019664;
  short* xh  = (short*)(ws + X0);
  short* xm  = (short*)(ws + X0 + 3145728);
  short* h1h = (short*)(ws + X0 + 9437184);
  short* h1m = (short*)(ws + X0 + 11010048);
  short* Qc   = (short*)(ws + X0);
  short* Kc   = (short*)(ws + X0 + 3145728);
  short* VTc  = (short*)(ws + X0 + 9437184);
  short* aoc  = (short*)(ws + X0 + 12582912);

  // masked output rows are exactly 0 in the reference -> pre-zero d_out;
  // colsum accumulated via atomicAdd in prep -> pre-zero (lgt zeroed by prep).
  hipMemsetAsync(d_out, 0, (size_t)out_size * sizeof(float), stream);
  hipMemsetAsync(colsum, 0, BATCH * EMBED * sizeof(float), stream);

  // weight conversions + lgt zero + colmean partials, one dispatch
  prep_kernel<<<dim3(2872), dim3(256), 0, stream>>>(
      qkv_w, wq_bf, proj_w, wp_bf, w1, w1h, w1m, w2, w2h, w2m,
      tokens, colsum, lgt);

  // mask path (~2^-22-exact fp16-split MFMA; logits fused into gemm<1>)
  ln_split_kernel<<<dim3(BATCH * NTOK), dim3(256), 0, stream>>>(
      tokens, colsum, layer_emb, lidx, ln_g, ln_b, xh, xm, tok_bf);
  gemm_split_kernel<0><<<dim3(128, 6), dim3(256), 0, stream>>>(
      xh, xm, w1h, w1m, b1, h1h, h1m, nullptr, nullptr,
      BATCH * NTOK, HID, EMBED);
  gemm_split_kernel<1><<<dim3(128, 6), dim3(256), 0, stream>>>(
      h1h, h1m, w2h, w2m, b2, nullptr, nullptr, w3, lgt,
      BATCH * NTOK, HID, HID);
  mask_kernel<<<dim3(BATCH), dim3(1024), 0, stream>>>(lgt, b3, kidx, kc, biasc);

  // attention path, compacted token space (V transposed in-kernel)
  qkv_gather_kernel<<<dim3(64, 18), dim3(256), 0, stream>>>(
      tok_bf, wq_bf, qkv_b, kidx, kc, Qc, Kc, VTc);
  attn_mfma3_kernel<<<dim3(768), dim3(256), 0, stream>>>(
      Qc, Kc, VTc, biasc, kc, aoc);
  proj_gather_kernel<<<dim3(64, 6), dim3(256), 0, stream>>>(
      aoc, wp_bf, proj_b, kidx, kc, out);
}

// Round 11
// 153.542 us; speedup vs baseline: 1.6041x; 1.0151x over previous
//
#include <hip/hip_runtime.h>
#include <cstdint>
#include <cmath>

#define EMBED 768
#define HID 384
#define NHEAD 12
#define HDIM 64
#define BATCH 8
#define NTOK 1024
#define MINKEEP 102

using f32x4  = __attribute__((ext_vector_type(4))) float;
using short8 = __attribute__((ext_vector_type(8))) short;
using short4v = __attribute__((ext_vector_type(4))) short;
using half8  = __attribute__((ext_vector_type(8))) _Float16;

__device__ inline short f2bf(float f) {
  unsigned u = __float_as_uint(f);
  u += 0x7fffu + ((u >> 16) & 1u);
  return (short)(u >> 16);
}
__device__ inline float bf2f(short s) {
  return __uint_as_float(((unsigned)(unsigned short)s) << 16);
}
__device__ inline unsigned pack_bf2(float lo, float hi) {
  unsigned ul = __float_as_uint(lo);
  ul += 0x7fffu + ((ul >> 16) & 1u);
  unsigned uh = __float_as_uint(hi);
  uh += 0x7fffu + ((uh >> 16) & 1u);
  return (ul >> 16) | (uh & 0xffff0000u);
}
// fp16 2-way split: v = h + m + O(2^-22 v).
__device__ inline void split2h(float v, short& h, short& m) {
  _Float16 h0 = (_Float16)v;
  float r = v - (float)h0;
  _Float16 m0 = (_Float16)r;
  h = __builtin_bit_cast(short, h0);
  m = __builtin_bit_cast(short, m0);
}

// ---------------------------------------------------------------------------
// prep: weight conversions + lgt zero + colmean partials, ONE dispatch.
// ---------------------------------------------------------------------------
__global__ __launch_bounds__(256) void prep_kernel(
    const float* __restrict__ qkv_w, short* __restrict__ wq_bf,
    const float* __restrict__ proj_w, short* __restrict__ wp_bf,
    const float* __restrict__ w1, short* __restrict__ w1h, short* __restrict__ w1m,
    const float* __restrict__ w2, short* __restrict__ w2h, short* __restrict__ w2m,
    const float* __restrict__ tokens, float* __restrict__ colsum,
    float* __restrict__ lgt) {
  int blk = blockIdx.x, tid = threadIdx.x;
  if (blk < 2304) {
    const float* in = (blk < 1728) ? qkv_w : proj_w;
    short* out = (blk < 1728) ? wq_bf : wp_bf;
    int i = (blk < 1728 ? blk : blk - 1728) * 256 + tid;
    float4 f = ((const float4*)in)[i];
    short4v s;
    s[0] = f2bf(f.x); s[1] = f2bf(f.y); s[2] = f2bf(f.z); s[3] = f2bf(f.w);
    ((short4v*)out)[i] = s;
  } else if (blk < 2736) {
    const float* in = (blk < 2592) ? w1 : w2;
    short* oh = (blk < 2592) ? w1h : w2h;
    short* om = (blk < 2592) ? w1m : w2m;
    int i = (blk < 2592 ? blk - 2304 : blk - 2592) * 256 + tid;
    float4 f = ((const float4*)in)[i];
    short4v h, m;
    short th, tm;
    split2h(f.x, th, tm); h[0] = th; m[0] = tm;
    split2h(f.y, th, tm); h[1] = th; m[1] = tm;
    split2h(f.z, th, tm); h[2] = th; m[2] = tm;
    split2h(f.w, th, tm); h[3] = th; m[3] = tm;
    ((short4v*)oh)[i] = h;
    ((short4v*)om)[i] = m;
  } else if (blk < 2744) {
    int i = (blk - 2736) * 256 + tid;
    ((float4*)lgt)[i] = make_float4(0.f, 0.f, 0.f, 0.f);
  } else {
    int idx = blk - 2744;  // 0..127
    int b = idx >> 4, chunk = idx & 15;
    const float* tb = tokens + ((size_t)b * NTOK + chunk * 64) * EMBED;
    float s0 = 0.f, s1 = 0.f, s2 = 0.f;
#pragma unroll 8
    for (int n = 0; n < 64; ++n) {
      const float* r = tb + (size_t)n * EMBED;
      s0 += r[tid]; s1 += r[tid + 256]; s2 += r[tid + 512];
    }
    atomicAdd(&colsum[b * EMBED + tid], s0);
    atomicAdd(&colsum[b * EMBED + tid + 256], s1);
    atomicAdd(&colsum[b * EMBED + tid + 512], s2);
  }
}

// ---------------------------------------------------------------------------
// K2: layernorm per row (768) -> 2 fp16 planes (xh, xm) + tok_bf.
// ---------------------------------------------------------------------------
__global__ __launch_bounds__(256) void ln_split_kernel(
    const float* __restrict__ tokens, const float* __restrict__ colsum,
    const float* __restrict__ layer_emb, const int* __restrict__ lidx,
    const float* __restrict__ gamma, const float* __restrict__ beta,
    short* __restrict__ xh, short* __restrict__ xm,
    short* __restrict__ tok_bf) {
  int row = blockIdx.x;
  int b = row >> 10;
  __shared__ float s_row[EMBED];
  __shared__ float s_red[4];
  const float* tr = tokens + (size_t)row * EMBED;
  const float* cs = colsum + b * EMBED;
  const float* eb = layer_emb + lidx[0] * EMBED;
  float lsum = 0.f;
  for (int c = threadIdx.x; c < EMBED; c += 256) {
    float t = tr[c];
    tok_bf[(size_t)row * EMBED + c] = f2bf(t);
    float v = t + 2.0f * eb[c] + cs[c] * (1.0f / NTOK);
    s_row[c] = v;
    lsum += v;
  }
  for (int o = 32; o; o >>= 1) lsum += __shfl_down(lsum, o, 64);
  int wid = threadIdx.x >> 6;
  if ((threadIdx.x & 63) == 0) s_red[wid] = lsum;
  __syncthreads();
  float mu = (s_red[0] + s_red[1] + s_red[2] + s_red[3]) * (1.f / EMBED);
  float lss = 0.f;
  for (int c = threadIdx.x; c < EMBED; c += 256) {
    float d = s_row[c] - mu;
    lss += d * d;
  }
  for (int o = 32; o; o >>= 1) lss += __shfl_down(lss, o, 64);
  __syncthreads();
  if ((threadIdx.x & 63) == 0) s_red[wid] = lss;
  __syncthreads();
  float var = (s_red[0] + s_red[1] + s_red[2] + s_red[3]) * (1.f / EMBED);
  float rinv = 1.0f / sqrtf(var + 1e-5f);
  for (int c = threadIdx.x; c < EMBED; c += 256) {
    float v = (s_row[c] - mu) * rinv * gamma[c] + beta[c];
    short h, m;
    split2h(v, h, m);
    size_t idx = (size_t)row * EMBED + c;
    xh[idx] = h; xm[idx] = m;
  }
}

// ---------------------------------------------------------------------------
// Split-fp16 MFMA GEMM (~2^-22 exact): C = A@W^T + bias, gelu.
// OUT==0: write fp16 h/m planes. OUT==1: fused logits via atomicAdd.
// ---------------------------------------------------------------------------
__device__ inline float gelu_exact(float x) {
  return 0.5f * x * (1.0f + erff(x * 0.70710678118654752f));
}

template <int OUT>
__global__ __launch_bounds__(256) void gemm_split_kernel(
    const short* __restrict__ Ah, const short* __restrict__ Am,
    const short* __restrict__ Wh, const short* __restrict__ Wm,
    const float* __restrict__ bias, short* __restrict__ Ch,
    short* __restrict__ Cm, const float* __restrict__ w3,
    float* __restrict__ lgt, int M, int N, int K) {
  __shared__ short sA[2][64][40];
  __shared__ short sW[2][64][40];
  int tid = threadIdx.x;
  int w = tid >> 6, l = tid & 63, lg = l >> 4, lb = l & 15;
  int wr = (w >> 1) * 32, wc = (w & 1) * 32;
  int row0 = blockIdx.x * 64, col0 = blockIdx.y * 64;
  int srow = tid >> 2;
  int skk = (tid & 3) * 8;
  f32x4 acc0[2][2] = {}, acc1[2][2] = {};
  short8 ra0, ra1, rw0, rw1;
  {
    size_t aoff = (size_t)(row0 + srow) * K + skk;
    size_t woff = (size_t)(col0 + srow) * K + skk;
    ra0 = *(const short8*)(Ah + aoff);
    ra1 = *(const short8*)(Am + aoff);
    rw0 = *(const short8*)(Wh + woff);
    rw1 = *(const short8*)(Wm + woff);
  }
  for (int k0 = 0; k0 < K; k0 += 32) {
    __syncthreads();
    *(short8*)&sA[0][srow][skk] = ra0;
    *(short8*)&sA[1][srow][skk] = ra1;
    *(short8*)&sW[0][srow][skk] = rw0;
    *(short8*)&sW[1][srow][skk] = rw1;
    __syncthreads();
    if (k0 + 32 < K) {
      size_t aoff = (size_t)(row0 + srow) * K + k0 + 32 + skk;
      size_t woff = (size_t)(col0 + srow) * K + k0 + 32 + skk;
      ra0 = *(const short8*)(Ah + aoff);
      ra1 = *(const short8*)(Am + aoff);
      rw0 = *(const short8*)(Wh + woff);
      rw1 = *(const short8*)(Wm + woff);
    }
    half8 ah[2], am[2], bh[2], bm[2];
#pragma unroll
    for (int i = 0; i < 2; ++i) {
      ah[i] = *(half8*)&sA[0][wr + i * 16 + lb][lg * 8];
      am[i] = *(half8*)&sA[1][wr + i * 16 + lb][lg * 8];
      bh[i] = *(half8*)&sW[0][wc + i * 16 + lb][lg * 8];
      bm[i] = *(half8*)&sW[1][wc + i * 16 + lb][lg * 8];
    }
#pragma unroll
    for (int i = 0; i < 2; ++i)
#pragma unroll
      for (int j = 0; j < 2; ++j) {
        f32x4 c0 = acc0[i][j];
        f32x4 c1 = acc1[i][j];
        c0 = __builtin_amdgcn_mfma_f32_16x16x32_f16(ah[i], bh[j], c0, 0, 0, 0);
        c1 = __builtin_amdgcn_mfma_f32_16x16x32_f16(ah[i], bm[j], c1, 0, 0, 0);
        c0 = __builtin_amdgcn_mfma_f32_16x16x32_f16(am[i], bh[j], c0, 0, 0, 0);
        acc0[i][j] = c0;
        acc1[i][j] = c1;
      }
  }
  if (OUT == 0) {
#pragma unroll
    for (int i = 0; i < 2; ++i) {
#pragma unroll
      for (int j = 0; j < 2; ++j) {
#pragma unroll
        for (int r = 0; r < 4; ++r) {
          int grow = row0 + wr + i * 16 + lg * 4 + r;
          int gcol = col0 + wc + j * 16 + lb;
          float g = gelu_exact(acc0[i][j][r] + acc1[i][j][r] + bias[gcol]);
          size_t idx = (size_t)grow * N + gcol;
          short h, m;
          split2h(g, h, m);
          Ch[idx] = h; Cm[idx] = m;
        }
      }
    }
  } else {
    float part[2][4];
#pragma unroll
    for (int i = 0; i < 2; ++i)
#pragma unroll
      for (int r = 0; r < 4; ++r) part[i][r] = 0.f;
#pragma unroll
    for (int i = 0; i < 2; ++i) {
#pragma unroll
      for (int j = 0; j < 2; ++j) {
#pragma unroll
        for (int r = 0; r < 4; ++r) {
          int gcol = col0 + wc + j * 16 + lb;
          float g = gelu_exact(acc0[i][j][r] + acc1[i][j][r] + bias[gcol]);
          part[i][r] += g * w3[gcol];
        }
      }
    }
#pragma unroll
    for (int i = 0; i < 2; ++i) {
#pragma unroll
      for (int r = 0; r < 4; ++r) {
        float v = part[i][r];
        v += __shfl_xor(v, 1);
        v += __shfl_xor(v, 2);
        v += __shfl_xor(v, 4);
        v += __shfl_xor(v, 8);
        if (lb == 0) atomicAdd(&lgt[row0 + wr + i * 16 + lg * 4 + r], v);
      }
    }
  }
}

// ---------------------------------------------------------------------------
// mask v5: raw logits (sigmoid folded into threshold). Writes the KEPT list
// to kidx[b][0..kc) AND the COMPLEMENT list to kidx[b][kc..1024) — proj uses
// the complement to scatter exact zeros (d_out memset eliminated).
// biasc: 0 for kept positions, -3e38 for complement positions.
// ---------------------------------------------------------------------------
__global__ __launch_bounds__(1024) void mask_kernel(
    const float* __restrict__ lgt, const float* __restrict__ b3,
    int* __restrict__ kidx, int* __restrict__ kc, float* __restrict__ biasc) {
  int b = blockIdx.x, tid = threadIdx.x;
  __shared__ unsigned long long keys[1024];
  __shared__ int flag[1024];
  __shared__ int wsum[16];
  float v = lgt[b * NTOK + tid] + b3[0];
  bool bin = (v >= 0.0f);
  int wid = tid >> 6, lane = tid & 63;
  unsigned long long bal = __ballot(bin);
  if (lane == 0) wsum[wid] = __popcll(bal);
  __syncthreads();
  int total = 0;
  for (int q = 0; q < 16; ++q) total += wsum[q];
  int mv;
  if (total >= MINKEEP) {
    mv = bin ? 1 : 0;
  } else {
    flag[tid] = 0;
    unsigned u = __float_as_uint(v);
    u = (u & 0x80000000u) ? ~u : (u | 0x80000000u);  // order-preserving map
    keys[tid] = ((unsigned long long)u << 32) | (unsigned)(1023 - tid);
    __syncthreads();
    for (int k2 = 2; k2 <= 1024; k2 <<= 1) {
      for (int j = k2 >> 1; j > 0; j >>= 1) {
        int ixj = tid ^ j;
        if (ixj > tid) {
          unsigned long long a = keys[tid], c = keys[ixj];
          bool desc = ((tid & k2) == 0);
          if (desc ? (a < c) : (a > c)) {
            keys[tid] = c;
            keys[ixj] = a;
          }
        }
        __syncthreads();
      }
    }
    if (tid < MINKEEP) {
      int idx = 1023 - (int)(keys[tid] & 0xFFFFFFFFu);
      flag[idx] = 1;
    }
    __syncthreads();
    mv = flag[tid];
  }
  if (tid == 0) mv = 1;
  __syncthreads();  // wsum reuse
  unsigned long long fb = __ballot(mv != 0);
  if (lane == 0) wsum[wid] = __popcll(fb);
  __syncthreads();
  int base = 0, tot = 0;
  for (int q = 0; q < 16; ++q) {
    int vq = wsum[q];
    if (q < wid) base += vq;
    tot += vq;
  }
  if (mv) {
    int pre = base + __popcll(fb & ((1ull << lane) - 1ull));
    kidx[b * NTOK + pre] = tid;
    biasc[b * NTOK + pre] = 0.f;
  } else {
    int nbase = wid * 64 - base;  // non-kept threads before this wave
    int npre = nbase + __popcll(~fb & ((1ull << lane) - 1ull));
    kidx[b * NTOK + tot + npre] = tid;
    biasc[b * NTOK + tot + npre] = -3.0e38f;
  }
  if (tid == 0) kc[b] = tot;
}

// ---------------------------------------------------------------------------
// QKV gather-GEMM (compacted rows). 128x128 tile, BK=64, reg prefetch.
// b = bx&7 -> all 8 XCDs active. V blocks (col0 >= 2*EMBED) write VTc
// directly via LDS transpose.
// ---------------------------------------------------------------------------
__global__ __launch_bounds__(256) void qkv_gather_kernel(
    const short* __restrict__ tok_bf, const short* __restrict__ W,
    const float* __restrict__ bias, const int* __restrict__ kidx,
    const int* __restrict__ kc, short* __restrict__ qq,
    short* __restrict__ kk_, short* __restrict__ VTc) {
  __shared__ short smem[2 * 128 * 72];
  short (*sA)[72] = (short(*)[72])smem;
  short (*sW)[72] = (short(*)[72])(smem + 128 * 72);
  __shared__ int s_idx[128];
  int bx = blockIdx.x;
  int b = bx & 7, bt = bx >> 3;
  int kcb = kc[b];
  if (bt * 128 >= kcb) return;
  int tid = threadIdx.x;
  if (tid < 128) s_idx[tid] = kidx[b * NTOK + bt * 128 + tid];
  int w = tid >> 6, l = tid & 63, lg = l >> 4, lb = l & 15;
  int wr = (w >> 1) * 64, wc = (w & 1) * 64;
  int col0 = blockIdx.y * 128;
  int r_ = tid >> 3, kq = (tid & 7) * 8;
  __syncthreads();  // s_idx ready
  const short* Ab = tok_bf + (size_t)b * NTOK * EMBED;
  f32x4 acc[4][4] = {};
  short8 pa[4], pw[4];
#pragma unroll
  for (int t = 0; t < 4; ++t) {
    pa[t] = *(const short8*)(Ab + (size_t)s_idx[t * 32 + r_] * EMBED + kq);
    pw[t] = *(const short8*)(W + (size_t)(col0 + t * 32 + r_) * EMBED + kq);
  }
  for (int k0 = 0; k0 < EMBED; k0 += 64) {
    __syncthreads();
#pragma unroll
    for (int t = 0; t < 4; ++t) {
      *(short8*)&sA[t * 32 + r_][kq] = pa[t];
      *(short8*)&sW[t * 32 + r_][kq] = pw[t];
    }
    __syncthreads();
    if (k0 + 64 < EMBED) {
#pragma unroll
      for (int t = 0; t < 4; ++t) {
        pa[t] = *(const short8*)(Ab + (size_t)s_idx[t * 32 + r_] * EMBED +
                                 k0 + 64 + kq);
        pw[t] = *(const short8*)(W + (size_t)(col0 + t * 32 + r_) * EMBED +
                                 k0 + 64 + kq);
      }
    }
#pragma unroll
    for (int half = 0; half < 2; ++half) {
      short8 af[4], bfr[4];
#pragma unroll
      for (int i = 0; i < 4; ++i)
        af[i] = *(short8*)&sA[wr + i * 16 + lb][half * 32 + lg * 8];
#pragma unroll
      for (int j = 0; j < 4; ++j)
        bfr[j] = *(short8*)&sW[wc + j * 16 + lb][half * 32 + lg * 8];
#pragma unroll
      for (int i = 0; i < 4; ++i)
#pragma unroll
        for (int j = 0; j < 4; ++j)
          acc[i][j] = __builtin_amdgcn_mfma_f32_16x16x32_bf16(af[i], bfr[j],
                                                              acc[i][j], 0, 0, 0);
    }
  }
  if (col0 >= 2 * EMBED) {
    // ---- V block: LDS-transpose epilogue, write VTc directly ----
    __syncthreads();  // all fragment reads done before smem reuse
    short (*sT)[136] = (short(*)[136])smem;  // 128x136x2B = 34816B
#pragma unroll
    for (int i = 0; i < 4; ++i) {
#pragma unroll
      for (int j = 0; j < 4; ++j) {
        int col_local = wc + j * 16 + lb;
        int jr0 = wr + i * 16 + lg * 4;
        short4v v4;
#pragma unroll
        for (int r = 0; r < 4; ++r)
          v4[r] = f2bf(acc[i][j][r] + bias[col0 + col_local]);
        *(short4v*)&sT[col_local][jr0] = v4;
      }
    }
    __syncthreads();
    int rem = col0 - 2 * EMBED;  // 0,128,...,640
#pragma unroll
    for (int t = 0; t < 8; ++t) {
      int c = tid + t * 256;     // chunk 0..2047
      int rowl = c >> 4;         // col_local 0..127
      int off = (c & 15) * 8;    // jrow offset
      int vcol = rem + rowl;
      int h = vcol >> 6, d = vcol & 63;
      size_t dst = ((size_t)(b * NHEAD + h) * HDIM + d) * NTOK + bt * 128 + off;
      *(short8*)(VTc + dst) = *(short8*)&sT[rowl][off];
    }
    return;
  }
#pragma unroll
  for (int i = 0; i < 4; ++i) {
#pragma unroll
    for (int j = 0; j < 4; ++j) {
#pragma unroll
      for (int r = 0; r < 4; ++r) {
        int jrow = bt * 128 + wr + i * 16 + lg * 4 + r;  // compacted position
        int gcol = col0 + wc + j * 16 + lb;
        float val = acc[i][j][r] + bias[gcol];
        int which = gcol / EMBED;  // 0 or 1 here
        int rem2 = gcol - which * EMBED;
        int h = rem2 >> 6, d = rem2 & 63;
        size_t dst = ((size_t)(b * NHEAD + h) * NTOK + jrow) * HDIM + d;
        if (which == 0)
          qq[dst] = f2bf(val * 0.125f);
        else
          kk_[dst] = f2bf(val);
      }
    }
  }
}

// ---------------------------------------------------------------------------
// MFMA flash attention v4 — compacted token space, 64-row Q tiles
// (was 128): active blocks ~2x (TLP; R6 lesson applied favorably). Each of
// the 4 warps owns 16 Q-rows (n0 = qt*64 + w*16, acc[1][4] -> acc[4]).
// K/V staging, swizzle, softmax mechanics unchanged.
// ---------------------------------------------------------------------------
#define ATTN_SWZ(row, colbyte) (((row)*128) + ((colbyte) ^ (((row)&7) << 4)))

__global__ __launch_bounds__(256) void attn_mfma3_kernel(
    const short* __restrict__ Qc, const short* __restrict__ Kc,
    const short* __restrict__ VTc, const float* __restrict__ biasc,
    const int* __restrict__ kc, short* __restrict__ ao) {
  __shared__ __align__(16) short sK[64 * 64];
  __shared__ __align__(16) short sVT[64 * 64];
  int bid = blockIdx.x;
  int xcd = bid & 7, slot = bid >> 3;        // slot 0..191
  int bh = xcd * 12 + (slot >> 4);
  int qt = slot & 15;
  int b = bh / NHEAD;
  int kcb = kc[b];
  if (qt * 64 >= kcb) return;
  int nt = (kcb + 63) >> 6;
  int tid = threadIdx.x;
  int w = tid >> 6, l = tid & 63, lg = l >> 4, lb = l & 15;
  int n0 = qt * 64 + w * 16;
  const short* Qp = Qc + ((size_t)bh * NTOK + n0) * HDIM;
  const short* Kp = Kc + (size_t)bh * NTOK * HDIM;
  const short* Vp = VTc + (size_t)bh * HDIM * NTOK;
  const float* bp = biasc + b * NTOK;

  short8 qf[2];
#pragma unroll
  for (int hh = 0; hh < 2; ++hh)
    qf[hh] = *(const short8*)(Qp + lb * HDIM + hh * 32 + lg * 8);

  f32x4 acc[4] = {};
  float lr = 0.f;

  int srow = tid >> 3;
  int scol = (tid & 7) * 8;
  int scolb = scol * 2;
  short8 rk0, rk1, rv0, rv1;

#define ATTN_LOADT(m0_)                                                        \
  {                                                                            \
    rk0 = *(const short8*)(Kp + (size_t)((m0_) + srow) * HDIM + scol);         \
    rk1 = *(const short8*)(Kp + (size_t)((m0_) + srow + 32) * HDIM + scol);    \
    rv0 = *(const short8*)(Vp + (size_t)srow * NTOK + (m0_) + scol);           \
    rv1 = *(const short8*)(Vp + (size_t)(srow + 32) * NTOK + (m0_) + scol);    \
  }

  ATTN_LOADT(0);
  for (int t = 0; t < nt; ++t) {
    int m0 = t * 64;
    *(short8*)((char*)sK + ATTN_SWZ(srow, scolb)) = rk0;
    *(short8*)((char*)sK + ATTN_SWZ(srow + 32, scolb)) = rk1;
    *(short8*)((char*)sVT + ATTN_SWZ(srow, scolb)) = rv0;
    *(short8*)((char*)sVT + ATTN_SWZ(srow + 32, scolb)) = rv1;
    __syncthreads();
    if (t + 1 < nt) ATTN_LOADT(m0 + 64);

    f32x4 bias4[4];
#pragma unroll
    for (int s = 0; s < 4; ++s)
      bias4[s] = *(const f32x4*)(bp + m0 + s * 16 + lg * 4);

    f32x4 S[4];
#pragma unroll
    for (int s = 0; s < 4; ++s) {
      short8 kf0 = *(const short8*)((const char*)sK +
                                    ATTN_SWZ(s * 16 + lb, lg * 16));
      short8 kf1 = *(const short8*)((const char*)sK +
                                    ATTN_SWZ(s * 16 + lb, 64 + lg * 16));
      f32x4 c = bias4[s];
      c = __builtin_amdgcn_mfma_f32_16x16x32_bf16(kf0, qf[0], c, 0, 0, 0);
      c = __builtin_amdgcn_mfma_f32_16x16x32_bf16(kf1, qf[1], c, 0, 0, 0);
      S[s] = c;
    }

    unsigned pk[4][2];
    {
      float rs = 0.f;
#pragma unroll
      for (int s = 0; s < 4; ++s) {
        float p0 = __expf(S[s][0]);
        float p1 = __expf(S[s][1]);
        float p2 = __expf(S[s][2]);
        float p3 = __expf(S[s][3]);
        rs += (p0 + p1) + (p2 + p3);
        pk[s][0] = pack_bf2(p0, p1);
        pk[s][1] = pack_bf2(p2, p3);
      }
      rs += __shfl_xor(rs, 16);
      rs += __shfl_xor(rs, 32);
      lr += rs;
    }

    bool hi = (lg & 2) != 0;
    int srcl = ((lg & 1) * 2) * 16 + lb;
#pragma unroll
    for (int t2 = 0; t2 < 2; ++t2) {
      short8 vf[4];
#pragma unroll
      for (int u = 0; u < 4; ++u)
        vf[u] = *(const short8*)((const char*)sVT +
                                 ATTN_SWZ(u * 16 + lb, t2 * 64 + lg * 16));
      int a0 = __shfl((int)pk[2 * t2][0], srcl);
      int b0 = __shfl((int)pk[2 * t2 + 1][0], srcl);
      int a1 = __shfl((int)pk[2 * t2][1], srcl);
      int b1 = __shfl((int)pk[2 * t2 + 1][1], srcl);
      int a2 = __shfl((int)pk[2 * t2][0], srcl + 16);
      int b2 = __shfl((int)pk[2 * t2 + 1][0], srcl + 16);
      int a3 = __shfl((int)pk[2 * t2][1], srcl + 16);
      int b3 = __shfl((int)pk[2 * t2 + 1][1], srcl + 16);
      union { short8 s8; int u[4]; } pa;
      pa.u[0] = hi ? b0 : a0;
      pa.u[1] = hi ? b1 : a1;
      pa.u[2] = hi ? b2 : a2;
      pa.u[3] = hi ? b3 : a3;
#pragma unroll
      for (int u = 0; u < 4; ++u)
        acc[u] = __builtin_amdgcn_mfma_f32_16x16x32_bf16(pa.s8, vf[u],
                                                         acc[u], 0, 0, 0);
    }
    __syncthreads();
  }

  int h = bh - b * NHEAD;
#pragma unroll
  for (int r = 0; r < 4; ++r) {
    float inv = 1.0f / __shfl(lr, lg * 4 + r);
    int j = n0 + lg * 4 + r;  // compacted row
#pragma unroll
    for (int u = 0; u < 4; ++u) {
      ao[((size_t)b * NTOK + j) * EMBED + h * HDIM + u * 16 + lb] =
          f2bf(acc[u][r] * inv);
    }
  }
}

// ---------------------------------------------------------------------------
// Proj gather-GEMM + ZERO-SCATTER: kept rows (jrow < kc) get A@W^T + bias
// scattered to their token; complement rows (jrow >= kc, kidx holds the
// complement list) get exact zeros. Covers every (b, token, col) once ->
// the d_out memset is eliminated.
// ---------------------------------------------------------------------------
__global__ __launch_bounds__(256) void proj_gather_kernel(
    const short* __restrict__ A, const short* __restrict__ W,
    const float* __restrict__ bias, const int* __restrict__ kidx,
    const int* __restrict__ kc, float* __restrict__ out) {
  __shared__ short sA[128][72];
  __shared__ short sW[128][72];
  __shared__ int s_idx[128];
  int bx = blockIdx.x;
  int b = bx & 7, bt = bx >> 3;
  int kcb = kc[b];
  int tid = threadIdx.x;
  if (tid < 128) s_idx[tid] = kidx[b * NTOK + bt * 128 + tid];
  int col0 = blockIdx.y * 128;
  if (bt * 128 >= kcb) {
    // pure zero-tile: scatter zeros to complement tokens, cols [col0,col0+128)
    __syncthreads();
#pragma unroll
    for (int t = 0; t < 16; ++t) {
      int c = tid + t * 256;     // 0..4095
      int rowl = c >> 5;         // 0..127
      int c4 = c & 31;           // float4 index within 128 cols
      int n = s_idx[rowl];
      ((float4*)(out + ((size_t)b * NTOK + n) * EMBED + col0))[c4] =
          make_float4(0.f, 0.f, 0.f, 0.f);
    }
    return;
  }
  int w = tid >> 6, l = tid & 63, lg = l >> 4, lb = l & 15;
  int wr = (w >> 1) * 64, wc = (w & 1) * 64;
  int r_ = tid >> 3, kq = (tid & 7) * 8;
  const short* Ab = A + ((size_t)b * NTOK + bt * 128) * EMBED;
  f32x4 acc[4][4] = {};
  short8 pa[4], pw[4];
  __syncthreads();  // s_idx ready before any use below
#pragma unroll
  for (int t = 0; t < 4; ++t) {
    pa[t] = *(const short8*)(Ab + (size_t)(t * 32 + r_) * EMBED + kq);
    pw[t] = *(const short8*)(W + (size_t)(col0 + t * 32 + r_) * EMBED + kq);
  }
  for (int k0 = 0; k0 < EMBED; k0 += 64) {
    __syncthreads();
#pragma unroll
    for (int t = 0; t < 4; ++t) {
      *(short8*)&sA[t * 32 + r_][kq] = pa[t];
      *(short8*)&sW[t * 32 + r_][kq] = pw[t];
    }
    __syncthreads();
    if (k0 + 64 < EMBED) {
#pragma unroll
      for (int t = 0; t < 4; ++t) {
        pa[t] = *(const short8*)(Ab + (size_t)(t * 32 + r_) * EMBED + k0 + 64 + kq);
        pw[t] = *(const short8*)(W + (size_t)(col0 + t * 32 + r_) * EMBED + k0 + 64 + kq);
      }
    }
#pragma unroll
    for (int half = 0; half < 2; ++half) {
      short8 af[4], bfr[4];
#pragma unroll
      for (int i = 0; i < 4; ++i)
        af[i] = *(short8*)&sA[wr + i * 16 + lb][half * 32 + lg * 8];
#pragma unroll
      for (int j = 0; j < 4; ++j)
        bfr[j] = *(short8*)&sW[wc + j * 16 + lb][half * 32 + lg * 8];
#pragma unroll
      for (int i = 0; i < 4; ++i)
#pragma unroll
        for (int j = 0; j < 4; ++j)
          acc[i][j] = __builtin_amdgcn_mfma_f32_16x16x32_bf16(af[i], bfr[j],
                                                              acc[i][j], 0, 0, 0);
    }
  }
#pragma unroll
  for (int i = 0; i < 4; ++i) {
#pragma unroll
    for (int j = 0; j < 4; ++j) {
#pragma unroll
      for (int r = 0; r < 4; ++r) {
        int jloc = wr + i * 16 + lg * 4 + r;
        int jrow = bt * 128 + jloc;
        int gcol = col0 + wc + j * 16 + lb;
        int n = s_idx[jloc];
        out[((size_t)b * NTOK + n) * EMBED + gcol] =
            (jrow < kcb) ? (acc[i][j][r] + bias[gcol]) : 0.f;
      }
    }
  }
}

// ---------------------------------------------------------------------------
extern "C" void kernel_launch(void* const* d_in, const int* in_sizes, int n_in,
                              void* d_out, int out_size, void* d_ws, size_t ws_size,
                              hipStream_t stream) {
  const float* tokens   = (const float*)d_in[0];
  const int*   lidx     = (const int*)d_in[1];
  const float* layer_emb= (const float*)d_in[2];
  const float* ln_g     = (const float*)d_in[3];
  const float* ln_b     = (const float*)d_in[4];
  const float* w1       = (const float*)d_in[5];
  const float* b1       = (const float*)d_in[6];
  const float* w2       = (const float*)d_in[7];
  const float* b2       = (const float*)d_in[8];
  const float* w3       = (const float*)d_in[9];
  const float* b3       = (const float*)d_in[10];
  const float* qkv_w    = (const float*)d_in[11];
  const float* qkv_b    = (const float*)d_in[12];
  const float* proj_w   = (const float*)d_in[13];
  const float* proj_b   = (const float*)d_in[14];
  float* out = (float*)d_out;
  float* ws = (float*)d_ws;

  float* colsum = ws;                  // [6144]
  float* lgt    = ws + 6144;           // raw logits [8192]
  int*   kidx   = (int*)(ws + 14336);
  float* biasc  = ws + 22528;
  int*   kc     = (int*)(ws + 30720);
  short* tok_bf = (short*)(ws + 30736);
  short* wq_bf  = (short*)(ws + 3176464);
  short* wp_bf  = (short*)(ws + 4061200);
  short* w1h = (short*)(ws + 4356112);
  short* w1m = (short*)(ws + 4503568);
  short* w2h = (short*)(ws + 4798480);
  short* w2m = (short*)(ws + 4872208);
  const size_t X0 = 5019664;
  short* xh  = (short*)(ws + X0);
  short* xm  = (short*)(ws + X0 + 3145728);
  short* h1h = (short*)(ws + X0 + 9437184);
  short* h1m = (short*)(ws + X0 + 11010048);
  short* Qc   = (short*)(ws + X0);
  short* Kc   = (short*)(ws + X0 + 3145728);
  short* VTc  = (short*)(ws + X0 + 9437184);
  short* aoc  = (short*)(ws + X0 + 12582912);

  // colsum accumulated via atomicAdd in prep -> pre-zero (lgt zeroed by prep;
  // d_out fully written by proj's kept+complement scatter -> no memset).
  hipMemsetAsync(colsum, 0, BATCH * EMBED * sizeof(float), stream);

  // weight conversions + lgt zero + colmean partials, one dispatch
  prep_kernel<<<dim3(2872), dim3(256), 0, stream>>>(
      qkv_w, wq_bf, proj_w, wp_bf, w1, w1h, w1m, w2, w2h, w2m,
      tokens, colsum, lgt);

  // mask path (~2^-22-exact fp16-split MFMA; logits fused into gemm<1>)
  ln_split_kernel<<<dim3(BATCH * NTOK), dim3(256), 0, stream>>>(
      tokens, colsum, layer_emb, lidx, ln_g, ln_b, xh, xm, tok_bf);
  gemm_split_kernel<0><<<dim3(128, 6), dim3(256), 0, stream>>>(
      xh, xm, w1h, w1m, b1, h1h, h1m, nullptr, nullptr,
      BATCH * NTOK, HID, EMBED);
  gemm_split_kernel<1><<<dim3(128, 6), dim3(256), 0, stream>>>(
      h1h, h1m, w2h, w2m, b2, nullptr, nullptr, w3, lgt,
      BATCH * NTOK, HID, HID);
  mask_kernel<<<dim3(BATCH), dim3(1024), 0, stream>>>(lgt, b3, kidx, kc, biasc);

  // attention path, compacted token space (V transposed in-kernel)
  qkv_gather_kernel<<<dim3(64, 18), dim3(256), 0, stream>>>(
      tok_bf, wq_bf, qkv_b, kidx, kc, Qc, Kc, VTc);
  attn_mfma3_kernel<<<dim3(1536), dim3(256), 0, stream>>>(
      Qc, Kc, VTc, biasc, kc, aoc);
  proj_gather_kernel<<<dim3(64, 6), dim3(256), 0, stream>>>(
      aoc, wp_bf, proj_b, kidx, kc, out);
}

// Round 12
// 150.447 us; speedup vs baseline: 1.6370x; 1.0206x over previous
//
#include <hip/hip_runtime.h>
#include <cstdint>
#include <cmath>

#define EMBED 768
#define HID 384
#define NHEAD 12
#define HDIM 64
#define BATCH 8
#define NTOK 1024
#define MINKEEP 102

using f32x4  = __attribute__((ext_vector_type(4))) float;
using short8 = __attribute__((ext_vector_type(8))) short;
using short4v = __attribute__((ext_vector_type(4))) short;
using half8  = __attribute__((ext_vector_type(8))) _Float16;

__device__ inline short f2bf(float f) {
  unsigned u = __float_as_uint(f);
  u += 0x7fffu + ((u >> 16) & 1u);
  return (short)(u >> 16);
}
__device__ inline float bf2f(short s) {
  return __uint_as_float(((unsigned)(unsigned short)s) << 16);
}
__device__ inline unsigned pack_bf2(float lo, float hi) {
  unsigned ul = __float_as_uint(lo);
  ul += 0x7fffu + ((ul >> 16) & 1u);
  unsigned uh = __float_as_uint(hi);
  uh += 0x7fffu + ((uh >> 16) & 1u);
  return (ul >> 16) | (uh & 0xffff0000u);
}
// fp16 2-way split: v = h + m + O(2^-22 v).
__device__ inline void split2h(float v, short& h, short& m) {
  _Float16 h0 = (_Float16)v;
  float r = v - (float)h0;
  _Float16 m0 = (_Float16)r;
  h = __builtin_bit_cast(short, h0);
  m = __builtin_bit_cast(short, m0);
}

// ---------------------------------------------------------------------------
// prep: weight conversions + lgt zero + colmean partials, ONE dispatch.
// ---------------------------------------------------------------------------
__global__ __launch_bounds__(256) void prep_kernel(
    const float* __restrict__ qkv_w, short* __restrict__ wq_bf,
    const float* __restrict__ proj_w, short* __restrict__ wp_bf,
    const float* __restrict__ w1, short* __restrict__ w1h, short* __restrict__ w1m,
    const float* __restrict__ w2, short* __restrict__ w2h, short* __restrict__ w2m,
    const float* __restrict__ tokens, float* __restrict__ colsum,
    float* __restrict__ lgt) {
  int blk = blockIdx.x, tid = threadIdx.x;
  if (blk < 2304) {
    const float* in = (blk < 1728) ? qkv_w : proj_w;
    short* out = (blk < 1728) ? wq_bf : wp_bf;
    int i = (blk < 1728 ? blk : blk - 1728) * 256 + tid;
    float4 f = ((const float4*)in)[i];
    short4v s;
    s[0] = f2bf(f.x); s[1] = f2bf(f.y); s[2] = f2bf(f.z); s[3] = f2bf(f.w);
    ((short4v*)out)[i] = s;
  } else if (blk < 2736) {
    const float* in = (blk < 2592) ? w1 : w2;
    short* oh = (blk < 2592) ? w1h : w2h;
    short* om = (blk < 2592) ? w1m : w2m;
    int i = (blk < 2592 ? blk - 2304 : blk - 2592) * 256 + tid;
    float4 f = ((const float4*)in)[i];
    short4v h, m;
    short th, tm;
    split2h(f.x, th, tm); h[0] = th; m[0] = tm;
    split2h(f.y, th, tm); h[1] = th; m[1] = tm;
    split2h(f.z, th, tm); h[2] = th; m[2] = tm;
    split2h(f.w, th, tm); h[3] = th; m[3] = tm;
    ((short4v*)oh)[i] = h;
    ((short4v*)om)[i] = m;
  } else if (blk < 2744) {
    int i = (blk - 2736) * 256 + tid;
    ((float4*)lgt)[i] = make_float4(0.f, 0.f, 0.f, 0.f);
  } else {
    int idx = blk - 2744;  // 0..127
    int b = idx >> 4, chunk = idx & 15;
    const float* tb = tokens + ((size_t)b * NTOK + chunk * 64) * EMBED;
    float s0 = 0.f, s1 = 0.f, s2 = 0.f;
#pragma unroll 8
    for (int n = 0; n < 64; ++n) {
      const float* r = tb + (size_t)n * EMBED;
      s0 += r[tid]; s1 += r[tid + 256]; s2 += r[tid + 512];
    }
    atomicAdd(&colsum[b * EMBED + tid], s0);
    atomicAdd(&colsum[b * EMBED + tid + 256], s1);
    atomicAdd(&colsum[b * EMBED + tid + 512], s2);
  }
}

// ---------------------------------------------------------------------------
// K2: layernorm per row (768) -> 2 fp16 planes (xh, xm) + tok_bf.
// ---------------------------------------------------------------------------
__global__ __launch_bounds__(256) void ln_split_kernel(
    const float* __restrict__ tokens, const float* __restrict__ colsum,
    const float* __restrict__ layer_emb, const int* __restrict__ lidx,
    const float* __restrict__ gamma, const float* __restrict__ beta,
    short* __restrict__ xh, short* __restrict__ xm,
    short* __restrict__ tok_bf) {
  int row = blockIdx.x;
  int b = row >> 10;
  __shared__ float s_row[EMBED];
  __shared__ float s_red[4];
  const float* tr = tokens + (size_t)row * EMBED;
  const float* cs = colsum + b * EMBED;
  const float* eb = layer_emb + lidx[0] * EMBED;
  float lsum = 0.f;
  for (int c = threadIdx.x; c < EMBED; c += 256) {
    float t = tr[c];
    tok_bf[(size_t)row * EMBED + c] = f2bf(t);
    float v = t + 2.0f * eb[c] + cs[c] * (1.0f / NTOK);
    s_row[c] = v;
    lsum += v;
  }
  for (int o = 32; o; o >>= 1) lsum += __shfl_down(lsum, o, 64);
  int wid = threadIdx.x >> 6;
  if ((threadIdx.x & 63) == 0) s_red[wid] = lsum;
  __syncthreads();
  float mu = (s_red[0] + s_red[1] + s_red[2] + s_red[3]) * (1.f / EMBED);
  float lss = 0.f;
  for (int c = threadIdx.x; c < EMBED; c += 256) {
    float d = s_row[c] - mu;
    lss += d * d;
  }
  for (int o = 32; o; o >>= 1) lss += __shfl_down(lss, o, 64);
  __syncthreads();
  if ((threadIdx.x & 63) == 0) s_red[wid] = lss;
  __syncthreads();
  float var = (s_red[0] + s_red[1] + s_red[2] + s_red[3]) * (1.f / EMBED);
  float rinv = 1.0f / sqrtf(var + 1e-5f);
  for (int c = threadIdx.x; c < EMBED; c += 256) {
    float v = (s_row[c] - mu) * rinv * gamma[c] + beta[c];
    short h, m;
    split2h(v, h, m);
    size_t idx = (size_t)row * EMBED + c;
    xh[idx] = h; xm[idx] = m;
  }
}

// ---------------------------------------------------------------------------
// Split-fp16 MFMA GEMM (~2^-22 exact): C = A@W^T + bias, gelu.
// OUT==0: write fp16 h/m planes. OUT==1: fused logits via atomicAdd.
// ---------------------------------------------------------------------------
__device__ inline float gelu_exact(float x) {
  return 0.5f * x * (1.0f + erff(x * 0.70710678118654752f));
}

template <int OUT>
__global__ __launch_bounds__(256) void gemm_split_kernel(
    const short* __restrict__ Ah, const short* __restrict__ Am,
    const short* __restrict__ Wh, const short* __restrict__ Wm,
    const float* __restrict__ bias, short* __restrict__ Ch,
    short* __restrict__ Cm, const float* __restrict__ w3,
    float* __restrict__ lgt, int M, int N, int K) {
  __shared__ short sA[2][64][40];
  __shared__ short sW[2][64][40];
  int tid = threadIdx.x;
  int w = tid >> 6, l = tid & 63, lg = l >> 4, lb = l & 15;
  int wr = (w >> 1) * 32, wc = (w & 1) * 32;
  int row0 = blockIdx.x * 64, col0 = blockIdx.y * 64;
  int srow = tid >> 2;
  int skk = (tid & 3) * 8;
  f32x4 acc0[2][2] = {}, acc1[2][2] = {};
  short8 ra0, ra1, rw0, rw1;
  {
    size_t aoff = (size_t)(row0 + srow) * K + skk;
    size_t woff = (size_t)(col0 + srow) * K + skk;
    ra0 = *(const short8*)(Ah + aoff);
    ra1 = *(const short8*)(Am + aoff);
    rw0 = *(const short8*)(Wh + woff);
    rw1 = *(const short8*)(Wm + woff);
  }
  for (int k0 = 0; k0 < K; k0 += 32) {
    __syncthreads();
    *(short8*)&sA[0][srow][skk] = ra0;
    *(short8*)&sA[1][srow][skk] = ra1;
    *(short8*)&sW[0][srow][skk] = rw0;
    *(short8*)&sW[1][srow][skk] = rw1;
    __syncthreads();
    if (k0 + 32 < K) {
      size_t aoff = (size_t)(row0 + srow) * K + k0 + 32 + skk;
      size_t woff = (size_t)(col0 + srow) * K + k0 + 32 + skk;
      ra0 = *(const short8*)(Ah + aoff);
      ra1 = *(const short8*)(Am + aoff);
      rw0 = *(const short8*)(Wh + woff);
      rw1 = *(const short8*)(Wm + woff);
    }
    half8 ah[2], am[2], bh[2], bm[2];
#pragma unroll
    for (int i = 0; i < 2; ++i) {
      ah[i] = *(half8*)&sA[0][wr + i * 16 + lb][lg * 8];
      am[i] = *(half8*)&sA[1][wr + i * 16 + lb][lg * 8];
      bh[i] = *(half8*)&sW[0][wc + i * 16 + lb][lg * 8];
      bm[i] = *(half8*)&sW[1][wc + i * 16 + lb][lg * 8];
    }
#pragma unroll
    for (int i = 0; i < 2; ++i)
#pragma unroll
      for (int j = 0; j < 2; ++j) {
        f32x4 c0 = acc0[i][j];
        f32x4 c1 = acc1[i][j];
        c0 = __builtin_amdgcn_mfma_f32_16x16x32_f16(ah[i], bh[j], c0, 0, 0, 0);
        c1 = __builtin_amdgcn_mfma_f32_16x16x32_f16(ah[i], bm[j], c1, 0, 0, 0);
        c0 = __builtin_amdgcn_mfma_f32_16x16x32_f16(am[i], bh[j], c0, 0, 0, 0);
        acc0[i][j] = c0;
        acc1[i][j] = c1;
      }
  }
  if (OUT == 0) {
#pragma unroll
    for (int i = 0; i < 2; ++i) {
#pragma unroll
      for (int j = 0; j < 2; ++j) {
#pragma unroll
        for (int r = 0; r < 4; ++r) {
          int grow = row0 + wr + i * 16 + lg * 4 + r;
          int gcol = col0 + wc + j * 16 + lb;
          float g = gelu_exact(acc0[i][j][r] + acc1[i][j][r] + bias[gcol]);
          size_t idx = (size_t)grow * N + gcol;
          short h, m;
          split2h(g, h, m);
          Ch[idx] = h; Cm[idx] = m;
        }
      }
    }
  } else {
    float part[2][4];
#pragma unroll
    for (int i = 0; i < 2; ++i)
#pragma unroll
      for (int r = 0; r < 4; ++r) part[i][r] = 0.f;
#pragma unroll
    for (int i = 0; i < 2; ++i) {
#pragma unroll
      for (int j = 0; j < 2; ++j) {
#pragma unroll
        for (int r = 0; r < 4; ++r) {
          int gcol = col0 + wc + j * 16 + lb;
          float g = gelu_exact(acc0[i][j][r] + acc1[i][j][r] + bias[gcol]);
          part[i][r] += g * w3[gcol];
        }
      }
    }
#pragma unroll
    for (int i = 0; i < 2; ++i) {
#pragma unroll
      for (int r = 0; r < 4; ++r) {
        float v = part[i][r];
        v += __shfl_xor(v, 1);
        v += __shfl_xor(v, 2);
        v += __shfl_xor(v, 4);
        v += __shfl_xor(v, 8);
        if (lb == 0) atomicAdd(&lgt[row0 + wr + i * 16 + lg * 4 + r], v);
      }
    }
  }
}

// ---------------------------------------------------------------------------
// mask v5: raw logits; kept list [0,kc) + complement list [kc,1024).
// ---------------------------------------------------------------------------
__global__ __launch_bounds__(1024) void mask_kernel(
    const float* __restrict__ lgt, const float* __restrict__ b3,
    int* __restrict__ kidx, int* __restrict__ kc, float* __restrict__ biasc) {
  int b = blockIdx.x, tid = threadIdx.x;
  __shared__ unsigned long long keys[1024];
  __shared__ int flag[1024];
  __shared__ int wsum[16];
  float v = lgt[b * NTOK + tid] + b3[0];
  bool bin = (v >= 0.0f);
  int wid = tid >> 6, lane = tid & 63;
  unsigned long long bal = __ballot(bin);
  if (lane == 0) wsum[wid] = __popcll(bal);
  __syncthreads();
  int total = 0;
  for (int q = 0; q < 16; ++q) total += wsum[q];
  int mv;
  if (total >= MINKEEP) {
    mv = bin ? 1 : 0;
  } else {
    flag[tid] = 0;
    unsigned u = __float_as_uint(v);
    u = (u & 0x80000000u) ? ~u : (u | 0x80000000u);  // order-preserving map
    keys[tid] = ((unsigned long long)u << 32) | (unsigned)(1023 - tid);
    __syncthreads();
    for (int k2 = 2; k2 <= 1024; k2 <<= 1) {
      for (int j = k2 >> 1; j > 0; j >>= 1) {
        int ixj = tid ^ j;
        if (ixj > tid) {
          unsigned long long a = keys[tid], c = keys[ixj];
          bool desc = ((tid & k2) == 0);
          if (desc ? (a < c) : (a > c)) {
            keys[tid] = c;
            keys[ixj] = a;
          }
        }
        __syncthreads();
      }
    }
    if (tid < MINKEEP) {
      int idx = 1023 - (int)(keys[tid] & 0xFFFFFFFFu);
      flag[idx] = 1;
    }
    __syncthreads();
    mv = flag[tid];
  }
  if (tid == 0) mv = 1;
  __syncthreads();  // wsum reuse
  unsigned long long fb = __ballot(mv != 0);
  if (lane == 0) wsum[wid] = __popcll(fb);
  __syncthreads();
  int base = 0, tot = 0;
  for (int q = 0; q < 16; ++q) {
    int vq = wsum[q];
    if (q < wid) base += vq;
    tot += vq;
  }
  if (mv) {
    int pre = base + __popcll(fb & ((1ull << lane) - 1ull));
    kidx[b * NTOK + pre] = tid;
    biasc[b * NTOK + pre] = 0.f;
  } else {
    int nbase = wid * 64 - base;  // non-kept threads before this wave
    int npre = nbase + __popcll(~fb & ((1ull << lane) - 1ull));
    kidx[b * NTOK + tot + npre] = tid;
    biasc[b * NTOK + tot + npre] = -3.0e38f;
  }
  if (tid == 0) kc[b] = tot;
}

// ---------------------------------------------------------------------------
// QKV gather-GEMM v3: 64-row x 128-col tiles (was 128x128) -> 2x active
// blocks (TLP; per-block A-traffic halves proportionally, W re-reads are
// L2-resident). Waves: 2x2 grid of 32x64 sub-tiles, acc[2][4]. V blocks
// (col0 >= 2*EMBED) still write VTc directly via LDS transpose.
// ---------------------------------------------------------------------------
__global__ __launch_bounds__(256) void qkv_gather_kernel(
    const short* __restrict__ tok_bf, const short* __restrict__ W,
    const float* __restrict__ bias, const int* __restrict__ kidx,
    const int* __restrict__ kc, short* __restrict__ qq,
    short* __restrict__ kk_, short* __restrict__ VTc) {
  __shared__ short smem[(64 + 128) * 72];
  short (*sA)[72] = (short(*)[72])smem;
  short (*sW)[72] = (short(*)[72])(smem + 64 * 72);
  __shared__ int s_idx[64];
  int bx = blockIdx.x;
  int b = bx & 7, bt = bx >> 3;     // bt 0..15, 64-row tiles
  int kcb = kc[b];
  if (bt * 64 >= kcb) return;
  int tid = threadIdx.x;
  if (tid < 64) s_idx[tid] = kidx[b * NTOK + bt * 64 + tid];
  int w = tid >> 6, l = tid & 63, lg = l >> 4, lb = l & 15;
  int wr = (w >> 1) * 32, wc = (w & 1) * 64;
  int col0 = blockIdx.y * 128;
  int r_ = tid >> 3, kq = (tid & 7) * 8;  // r_ 0..31
  __syncthreads();  // s_idx ready
  const short* Ab = tok_bf + (size_t)b * NTOK * EMBED;
  f32x4 acc[2][4] = {};
  short8 pa[2], pw[4];
#pragma unroll
  for (int t = 0; t < 2; ++t)
    pa[t] = *(const short8*)(Ab + (size_t)s_idx[t * 32 + r_] * EMBED + kq);
#pragma unroll
  for (int t = 0; t < 4; ++t)
    pw[t] = *(const short8*)(W + (size_t)(col0 + t * 32 + r_) * EMBED + kq);
  for (int k0 = 0; k0 < EMBED; k0 += 64) {
    __syncthreads();
#pragma unroll
    for (int t = 0; t < 2; ++t) *(short8*)&sA[t * 32 + r_][kq] = pa[t];
#pragma unroll
    for (int t = 0; t < 4; ++t) *(short8*)&sW[t * 32 + r_][kq] = pw[t];
    __syncthreads();
    if (k0 + 64 < EMBED) {
#pragma unroll
      for (int t = 0; t < 2; ++t)
        pa[t] = *(const short8*)(Ab + (size_t)s_idx[t * 32 + r_] * EMBED +
                                 k0 + 64 + kq);
#pragma unroll
      for (int t = 0; t < 4; ++t)
        pw[t] = *(const short8*)(W + (size_t)(col0 + t * 32 + r_) * EMBED +
                                 k0 + 64 + kq);
    }
#pragma unroll
    for (int half = 0; half < 2; ++half) {
      short8 af[2], bfr[4];
#pragma unroll
      for (int i = 0; i < 2; ++i)
        af[i] = *(short8*)&sA[wr + i * 16 + lb][half * 32 + lg * 8];
#pragma unroll
      for (int j = 0; j < 4; ++j)
        bfr[j] = *(short8*)&sW[wc + j * 16 + lb][half * 32 + lg * 8];
#pragma unroll
      for (int i = 0; i < 2; ++i)
#pragma unroll
        for (int j = 0; j < 4; ++j)
          acc[i][j] = __builtin_amdgcn_mfma_f32_16x16x32_bf16(af[i], bfr[j],
                                                              acc[i][j], 0, 0, 0);
    }
  }
  if (col0 >= 2 * EMBED) {
    // ---- V block: LDS-transpose epilogue, write VTc directly ----
    __syncthreads();  // all fragment reads done before smem reuse
    short (*sT)[72] = (short(*)[72])smem;  // 128 cols x 64 rows (72-padded)
#pragma unroll
    for (int i = 0; i < 2; ++i) {
#pragma unroll
      for (int j = 0; j < 4; ++j) {
        int col_local = wc + j * 16 + lb;   // 0..127
        int jr0 = wr + i * 16 + lg * 4;     // 0..63
        short4v v4;
#pragma unroll
        for (int r = 0; r < 4; ++r)
          v4[r] = f2bf(acc[i][j][r] + bias[col0 + col_local]);
        *(short4v*)&sT[col_local][jr0] = v4;
      }
    }
    __syncthreads();
    int rem = col0 - 2 * EMBED;  // 0,128,...,640
#pragma unroll
    for (int t = 0; t < 4; ++t) {
      int c = tid + t * 256;     // 0..1023
      int rowl = c >> 3;         // col_local 0..127
      int off = (c & 7) * 8;     // jrow offset 0..56
      int vcol = rem + rowl;
      int h = vcol >> 6, d = vcol & 63;
      size_t dst = ((size_t)(b * NHEAD + h) * HDIM + d) * NTOK + bt * 64 + off;
      *(short8*)(VTc + dst) = *(short8*)&sT[rowl][off];
    }
    return;
  }
#pragma unroll
  for (int i = 0; i < 2; ++i) {
#pragma unroll
    for (int j = 0; j < 4; ++j) {
#pragma unroll
      for (int r = 0; r < 4; ++r) {
        int jrow = bt * 64 + wr + i * 16 + lg * 4 + r;  // compacted position
        int gcol = col0 + wc + j * 16 + lb;
        float val = acc[i][j][r] + bias[gcol];
        int which = gcol / EMBED;  // 0 or 1 here
        int rem2 = gcol - which * EMBED;
        int h = rem2 >> 6, d = rem2 & 63;
        size_t dst = ((size_t)(b * NHEAD + h) * NTOK + jrow) * HDIM + d;
        if (which == 0)
          qq[dst] = f2bf(val * 0.125f);
        else
          kk_[dst] = f2bf(val);
      }
    }
  }
}

// ---------------------------------------------------------------------------
// MFMA flash attention v4 — 64-row Q tiles, 4 warps x 16 rows.
// ---------------------------------------------------------------------------
#define ATTN_SWZ(row, colbyte) (((row)*128) + ((colbyte) ^ (((row)&7) << 4)))

__global__ __launch_bounds__(256) void attn_mfma3_kernel(
    const short* __restrict__ Qc, const short* __restrict__ Kc,
    const short* __restrict__ VTc, const float* __restrict__ biasc,
    const int* __restrict__ kc, short* __restrict__ ao) {
  __shared__ __align__(16) short sK[64 * 64];
  __shared__ __align__(16) short sVT[64 * 64];
  int bid = blockIdx.x;
  int xcd = bid & 7, slot = bid >> 3;        // slot 0..191
  int bh = xcd * 12 + (slot >> 4);
  int qt = slot & 15;
  int b = bh / NHEAD;
  int kcb = kc[b];
  if (qt * 64 >= kcb) return;
  int nt = (kcb + 63) >> 6;
  int tid = threadIdx.x;
  int w = tid >> 6, l = tid & 63, lg = l >> 4, lb = l & 15;
  int n0 = qt * 64 + w * 16;
  const short* Qp = Qc + ((size_t)bh * NTOK + n0) * HDIM;
  const short* Kp = Kc + (size_t)bh * NTOK * HDIM;
  const short* Vp = VTc + (size_t)bh * HDIM * NTOK;
  const float* bp = biasc + b * NTOK;

  short8 qf[2];
#pragma unroll
  for (int hh = 0; hh < 2; ++hh)
    qf[hh] = *(const short8*)(Qp + lb * HDIM + hh * 32 + lg * 8);

  f32x4 acc[4] = {};
  float lr = 0.f;

  int srow = tid >> 3;
  int scol = (tid & 7) * 8;
  int scolb = scol * 2;
  short8 rk0, rk1, rv0, rv1;

#define ATTN_LOADT(m0_)                                                        \
  {                                                                            \
    rk0 = *(const short8*)(Kp + (size_t)((m0_) + srow) * HDIM + scol);         \
    rk1 = *(const short8*)(Kp + (size_t)((m0_) + srow + 32) * HDIM + scol);    \
    rv0 = *(const short8*)(Vp + (size_t)srow * NTOK + (m0_) + scol);           \
    rv1 = *(const short8*)(Vp + (size_t)(srow + 32) * NTOK + (m0_) + scol);    \
  }

  ATTN_LOADT(0);
  for (int t = 0; t < nt; ++t) {
    int m0 = t * 64;
    *(short8*)((char*)sK + ATTN_SWZ(srow, scolb)) = rk0;
    *(short8*)((char*)sK + ATTN_SWZ(srow + 32, scolb)) = rk1;
    *(short8*)((char*)sVT + ATTN_SWZ(srow, scolb)) = rv0;
    *(short8*)((char*)sVT + ATTN_SWZ(srow + 32, scolb)) = rv1;
    __syncthreads();
    if (t + 1 < nt) ATTN_LOADT(m0 + 64);

    f32x4 bias4[4];
#pragma unroll
    for (int s = 0; s < 4; ++s)
      bias4[s] = *(const f32x4*)(bp + m0 + s * 16 + lg * 4);

    f32x4 S[4];
#pragma unroll
    for (int s = 0; s < 4; ++s) {
      short8 kf0 = *(const short8*)((const char*)sK +
                                    ATTN_SWZ(s * 16 + lb, lg * 16));
      short8 kf1 = *(const short8*)((const char*)sK +
                                    ATTN_SWZ(s * 16 + lb, 64 + lg * 16));
      f32x4 c = bias4[s];
      c = __builtin_amdgcn_mfma_f32_16x16x32_bf16(kf0, qf[0], c, 0, 0, 0);
      c = __builtin_amdgcn_mfma_f32_16x16x32_bf16(kf1, qf[1], c, 0, 0, 0);
      S[s] = c;
    }

    unsigned pk[4][2];
    {
      float rs = 0.f;
#pragma unroll
      for (int s = 0; s < 4; ++s) {
        float p0 = __expf(S[s][0]);
        float p1 = __expf(S[s][1]);
        float p2 = __expf(S[s][2]);
        float p3 = __expf(S[s][3]);
        rs += (p0 + p1) + (p2 + p3);
        pk[s][0] = pack_bf2(p0, p1);
        pk[s][1] = pack_bf2(p2, p3);
      }
      rs += __shfl_xor(rs, 16);
      rs += __shfl_xor(rs, 32);
      lr += rs;
    }

    bool hi = (lg & 2) != 0;
    int srcl = ((lg & 1) * 2) * 16 + lb;
#pragma unroll
    for (int t2 = 0; t2 < 2; ++t2) {
      short8 vf[4];
#pragma unroll
      for (int u = 0; u < 4; ++u)
        vf[u] = *(const short8*)((const char*)sVT +
                                 ATTN_SWZ(u * 16 + lb, t2 * 64 + lg * 16));
      int a0 = __shfl((int)pk[2 * t2][0], srcl);
      int b0 = __shfl((int)pk[2 * t2 + 1][0], srcl);
      int a1 = __shfl((int)pk[2 * t2][1], srcl);
      int b1 = __shfl((int)pk[2 * t2 + 1][1], srcl);
      int a2 = __shfl((int)pk[2 * t2][0], srcl + 16);
      int b2 = __shfl((int)pk[2 * t2 + 1][0], srcl + 16);
      int a3 = __shfl((int)pk[2 * t2][1], srcl + 16);
      int b3 = __shfl((int)pk[2 * t2 + 1][1], srcl + 16);
      union { short8 s8; int u[4]; } pa;
      pa.u[0] = hi ? b0 : a0;
      pa.u[1] = hi ? b1 : a1;
      pa.u[2] = hi ? b2 : a2;
      pa.u[3] = hi ? b3 : a3;
#pragma unroll
      for (int u = 0; u < 4; ++u)
        acc[u] = __builtin_amdgcn_mfma_f32_16x16x32_bf16(pa.s8, vf[u],
                                                         acc[u], 0, 0, 0);
    }
    __syncthreads();
  }

  int h = bh - b * NHEAD;
#pragma unroll
  for (int r = 0; r < 4; ++r) {
    float inv = 1.0f / __shfl(lr, lg * 4 + r);
    int j = n0 + lg * 4 + r;  // compacted row
#pragma unroll
    for (int u = 0; u < 4; ++u) {
      ao[((size_t)b * NTOK + j) * EMBED + h * HDIM + u * 16 + lb] =
          f2bf(acc[u][r] * inv);
    }
  }
}

// ---------------------------------------------------------------------------
// Proj gather-GEMM v2 + ZERO-SCATTER: 64-row x 128-col tiles (2x TLP).
// Kept rows (jrow < kc) -> A@W^T + bias; complement rows -> exact zeros.
// ---------------------------------------------------------------------------
__global__ __launch_bounds__(256) void proj_gather_kernel(
    const short* __restrict__ A, const short* __restrict__ W,
    const float* __restrict__ bias, const int* __restrict__ kidx,
    const int* __restrict__ kc, float* __restrict__ out) {
  __shared__ short sA[64][72];
  __shared__ short sW[128][72];
  __shared__ int s_idx[64];
  int bx = blockIdx.x;
  int b = bx & 7, bt = bx >> 3;   // bt 0..15
  int kcb = kc[b];
  int tid = threadIdx.x;
  if (tid < 64) s_idx[tid] = kidx[b * NTOK + bt * 64 + tid];
  int col0 = blockIdx.y * 128;
  if (bt * 64 >= kcb) {
    // pure zero-tile: scatter zeros to complement tokens, cols [col0,col0+128)
    __syncthreads();
#pragma unroll
    for (int t = 0; t < 8; ++t) {
      int c = tid + t * 256;     // 0..2047
      int rowl = c >> 5;         // 0..63
      int c4 = c & 31;           // float4 index within 128 cols
      int n = s_idx[rowl];
      ((float4*)(out + ((size_t)b * NTOK + n) * EMBED + col0))[c4] =
          make_float4(0.f, 0.f, 0.f, 0.f);
    }
    return;
  }
  int w = tid >> 6, l = tid & 63, lg = l >> 4, lb = l & 15;
  int wr = (w >> 1) * 32, wc = (w & 1) * 64;
  int r_ = tid >> 3, kq = (tid & 7) * 8;
  const short* Ab = A + ((size_t)b * NTOK + bt * 64) * EMBED;
  f32x4 acc[2][4] = {};
  short8 pa[2], pw[4];
  __syncthreads();  // s_idx ready before any use below
#pragma unroll
  for (int t = 0; t < 2; ++t)
    pa[t] = *(const short8*)(Ab + (size_t)(t * 32 + r_) * EMBED + kq);
#pragma unroll
  for (int t = 0; t < 4; ++t)
    pw[t] = *(const short8*)(W + (size_t)(col0 + t * 32 + r_) * EMBED + kq);
  for (int k0 = 0; k0 < EMBED; k0 += 64) {
    __syncthreads();
#pragma unroll
    for (int t = 0; t < 2; ++t) *(short8*)&sA[t * 32 + r_][kq] = pa[t];
#pragma unroll
    for (int t = 0; t < 4; ++t) *(short8*)&sW[t * 32 + r_][kq] = pw[t];
    __syncthreads();
    if (k0 + 64 < EMBED) {
#pragma unroll
      for (int t = 0; t < 2; ++t)
        pa[t] = *(const short8*)(Ab + (size_t)(t * 32 + r_) * EMBED + k0 + 64 + kq);
#pragma unroll
      for (int t = 0; t < 4; ++t)
        pw[t] = *(const short8*)(W + (size_t)(col0 + t * 32 + r_) * EMBED + k0 + 64 + kq);
    }
#pragma unroll
    for (int half = 0; half < 2; ++half) {
      short8 af[2], bfr[4];
#pragma unroll
      for (int i = 0; i < 2; ++i)
        af[i] = *(short8*)&sA[wr + i * 16 + lb][half * 32 + lg * 8];
#pragma unroll
      for (int j = 0; j < 4; ++j)
        bfr[j] = *(short8*)&sW[wc + j * 16 + lb][half * 32 + lg * 8];
#pragma unroll
      for (int i = 0; i < 2; ++i)
#pragma unroll
        for (int j = 0; j < 4; ++j)
          acc[i][j] = __builtin_amdgcn_mfma_f32_16x16x32_bf16(af[i], bfr[j],
                                                              acc[i][j], 0, 0, 0);
    }
  }
#pragma unroll
  for (int i = 0; i < 2; ++i) {
#pragma unroll
    for (int j = 0; j < 4; ++j) {
#pragma unroll
      for (int r = 0; r < 4; ++r) {
        int jloc = wr + i * 16 + lg * 4 + r;   // 0..63
        int jrow = bt * 64 + jloc;
        int gcol = col0 + wc + j * 16 + lb;
        int n = s_idx[jloc];
        out[((size_t)b * NTOK + n) * EMBED + gcol] =
            (jrow < kcb) ? (acc[i][j][r] + bias[gcol]) : 0.f;
      }
    }
  }
}

// ---------------------------------------------------------------------------
extern "C" void kernel_launch(void* const* d_in, const int* in_sizes, int n_in,
                              void* d_out, int out_size, void* d_ws, size_t ws_size,
                              hipStream_t stream) {
  const float* tokens   = (const float*)d_in[0];
  const int*   lidx     = (const int*)d_in[1];
  const float* layer_emb= (const float*)d_in[2];
  const float* ln_g     = (const float*)d_in[3];
  const float* ln_b     = (const float*)d_in[4];
  const float* w1       = (const float*)d_in[5];
  const float* b1       = (const float*)d_in[6];
  const float* w2       = (const float*)d_in[7];
  const float* b2       = (const float*)d_in[8];
  const float* w3       = (const float*)d_in[9];
  const float* b3       = (const float*)d_in[10];
  const float* qkv_w    = (const float*)d_in[11];
  const float* qkv_b    = (const float*)d_in[12];
  const float* proj_w   = (const float*)d_in[13];
  const float* proj_b   = (const float*)d_in[14];
  float* out = (float*)d_out;
  float* ws = (float*)d_ws;

  float* colsum = ws;                  // [6144]
  float* lgt    = ws + 6144;           // raw logits [8192]
  int*   kidx   = (int*)(ws + 14336);
  float* biasc  = ws + 22528;
  int*   kc     = (int*)(ws + 30720);
  short* tok_bf = (short*)(ws + 30736);
  short* wq_bf  = (short*)(ws + 3176464);
  short* wp_bf  = (short*)(ws + 4061200);
  short* w1h = (short*)(ws + 4356112);
  short* w1m = (short*)(ws + 4503568);
  short* w2h = (short*)(ws + 4798480);
  short* w2m = (short*)(ws + 4872208);
  const size_t X0 = 5019664;
  short* xh  = (short*)(ws + X0);
  short* xm  = (short*)(ws + X0 + 3145728);
  short* h1h = (short*)(ws + X0 + 9437184);
  short* h1m = (short*)(ws + X0 + 11010048);
  short* Qc   = (short*)(ws + X0);
  short* Kc   = (short*)(ws + X0 + 3145728);
  short* VTc  = (short*)(ws + X0 + 9437184);
  short* aoc  = (short*)(ws + X0 + 12582912);

  // colsum accumulated via atomicAdd in prep -> pre-zero (lgt zeroed by prep;
  // d_out fully written by proj's kept+complement scatter -> no memset).
  hipMemsetAsync(colsum, 0, BATCH * EMBED * sizeof(float), stream);

  // weight conversions + lgt zero + colmean partials, one dispatch
  prep_kernel<<<dim3(2872), dim3(256), 0, stream>>>(
      qkv_w, wq_bf, proj_w, wp_bf, w1, w1h, w1m, w2, w2h, w2m,
      tokens, colsum, lgt);

  // mask path (~2^-22-exact fp16-split MFMA; logits fused into gemm<1>)
  ln_split_kernel<<<dim3(BATCH * NTOK), dim3(256), 0, stream>>>(
      tokens, colsum, layer_emb, lidx, ln_g, ln_b, xh, xm, tok_bf);
  gemm_split_kernel<0><<<dim3(128, 6), dim3(256), 0, stream>>>(
      xh, xm, w1h, w1m, b1, h1h, h1m, nullptr, nullptr,
      BATCH * NTOK, HID, EMBED);
  gemm_split_kernel<1><<<dim3(128, 6), dim3(256), 0, stream>>>(
      h1h, h1m, w2h, w2m, b2, nullptr, nullptr, w3, lgt,
      BATCH * NTOK, HID, HID);
  mask_kernel<<<dim3(BATCH), dim3(1024), 0, stream>>>(lgt, b3, kidx, kc, biasc);

  // attention path, compacted token space (V transposed in-kernel)
  qkv_gather_kernel<<<dim3(128, 18), dim3(256), 0, stream>>>(
      tok_bf, wq_bf, qkv_b, kidx, kc, Qc, Kc, VTc);
  attn_mfma3_kernel<<<dim3(1536), dim3(256), 0, stream>>>(
      Qc, Kc, VTc, biasc, kc, aoc);
  proj_gather_kernel<<<dim3(128, 6), dim3(256), 0, stream>>>(
      aoc, wp_bf, proj_b, kidx, kc, out);
}